// Round 3
// baseline (593.724 us; speedup 1.0000x reference)
//
#include <hip/hip_runtime.h>
#include <stdint.h>

#define LSEQ 1024
#define HDIM 1024
#define DDIM 2048
#define BL 2048
#define NST 16
#define XR 1027          // 3 halo rows (unused, zero-pad region) + 1024 tokens

typedef unsigned short u16;
typedef __attribute__((ext_vector_type(8))) short bf16x8;
typedef __attribute__((ext_vector_type(4))) float f32x4;

// silu via v_rcp (1-ulp rcp; output tolerance is bf16-dominated)
static __device__ __forceinline__ float silu_f(float v) {
  return v * __builtin_amdgcn_rcpf(1.f + __expf(-v));
}
static __device__ __forceinline__ float bf2f(u16 u) {
  union { float f; unsigned int i; } c; c.i = ((unsigned int)u) << 16; return c.f;
}
static __device__ __forceinline__ u16 f2bf(float f) {
  union { float f; unsigned int i; } c; c.f = f;
  unsigned int r = c.i + 0x7fffu + ((c.i >> 16) & 1u);
  return (u16)(r >> 16);
}

// ---------------- cast fp32 -> bf16 (weights, once per launch) ----------------
__global__ __launch_bounds__(256) void k_castw(const float* __restrict__ src,
                                               u16* __restrict__ dst) {
  int idx = blockIdx.x * 256 + threadIdx.x;
  float4 v = ((const float4*)src)[idx];
  ushort4 o;
  o.x = f2bf(v.x); o.y = f2bf(v.y); o.z = f2bf(v.z); o.w = f2bf(v.w);
  ((ushort4*)dst)[idx] = o;
}

// ---------------- per-row rmsnorm scale ----------------
__global__ __launch_bounds__(256) void k_rowscale(const float* __restrict__ inp,
                                                  float* __restrict__ rs) {
  int row = blockIdx.x;
  int t = threadIdx.x;
  float4 xv = *(const float4*)(inp + (size_t)row * HDIM + t * 4);
  float ss = xv.x * xv.x + xv.y * xv.y + xv.z * xv.z + xv.w * xv.w;
  for (int off = 32; off > 0; off >>= 1) ss += __shfl_down(ss, off);
  __shared__ float red[4];
  if ((t & 63) == 0) red[t >> 6] = ss;
  __syncthreads();
  if (t == 0) {
    float tot = red[0] + red[1] + red[2] + red[3];
    rs[row] = rsqrtf(tot * (1.f / HDIM) + 1e-6f);
  }
}

// ---------------- K1: in_proj MFMA GEMM, rmsnorm fused into A staging ----------------
// Full M=2048, N=4096, K=1024. 64x64 tile. Output bf16 xgb [2][XR][4096].
__global__ __launch_bounds__(256) void k_gemm1_mfma(const float* __restrict__ inp,
                                                    const u16* __restrict__ W,
                                                    const float* __restrict__ bias,
                                                    const float* __restrict__ rscale,
                                                    const float* __restrict__ nw,
                                                    u16* __restrict__ xgb) {
  __shared__ u16 Asm[64 * 40];
  __shared__ u16 Wsm[64 * 40];
  int t = threadIdx.x;
  int m0 = blockIdx.y * 64, n0 = blockIdx.x * 64;
  int srow = t >> 2, koff = (t & 3) * 8;
  int gin = m0 + srow;
  const float* Ag = inp + (size_t)gin * HDIM + koff;
  const u16* Wg = W + (size_t)(n0 + srow) * HDIM + koff;
  float scale = rscale[gin];
  int w = t >> 6, lane = t & 63;
  int quad = lane >> 4, mr = lane & 15;
  f32x4 z = {0.f, 0.f, 0.f, 0.f};
  f32x4 acc0 = z, acc1 = z, acc2 = z, acc3 = z;
  const u16* arp = &Asm[(16 * w + mr) * 40 + quad * 8];
  const u16* brp = &Wsm[mr * 40 + quad * 8];
  for (int k0 = 0; k0 < HDIM; k0 += 32) {
    float4 a0 = *(const float4*)(Ag + k0);
    float4 a1 = *(const float4*)(Ag + k0 + 4);
    float4 n0v = *(const float4*)(nw + k0 + koff);
    float4 n1v = *(const float4*)(nw + k0 + koff + 4);
    uint4 wv = *(const uint4*)(Wg + k0);
    ushort4 p0, p1;
    p0.x = f2bf(a0.x * scale * n0v.x); p0.y = f2bf(a0.y * scale * n0v.y);
    p0.z = f2bf(a0.z * scale * n0v.z); p0.w = f2bf(a0.w * scale * n0v.w);
    p1.x = f2bf(a1.x * scale * n1v.x); p1.y = f2bf(a1.y * scale * n1v.y);
    p1.z = f2bf(a1.z * scale * n1v.z); p1.w = f2bf(a1.w * scale * n1v.w);
    __syncthreads();
    *(ushort4*)(&Asm[srow * 40 + koff]) = p0;
    *(ushort4*)(&Asm[srow * 40 + koff + 4]) = p1;
    *(uint4*)(&Wsm[srow * 40 + koff]) = wv;
    __syncthreads();
    bf16x8 af = *(const bf16x8*)arp;
    bf16x8 b0 = *(const bf16x8*)(brp);
    bf16x8 b1 = *(const bf16x8*)(brp + 16 * 40);
    bf16x8 b2 = *(const bf16x8*)(brp + 32 * 40);
    bf16x8 b3 = *(const bf16x8*)(brp + 48 * 40);
    acc0 = __builtin_amdgcn_mfma_f32_16x16x32_bf16(af, b0, acc0, 0, 0, 0);
    acc1 = __builtin_amdgcn_mfma_f32_16x16x32_bf16(af, b1, acc1, 0, 0, 0);
    acc2 = __builtin_amdgcn_mfma_f32_16x16x32_bf16(af, b2, acc2, 0, 0, 0);
    acc3 = __builtin_amdgcn_mfma_f32_16x16x32_bf16(af, b3, acc3, 0, 0, 0);
  }
  f32x4 accs[4] = {acc0, acc1, acc2, acc3};
#pragma unroll
  for (int i = 0; i < 4; i++) {
    int col = n0 + 16 * i + mr;
    float bv = bias[col];
#pragma unroll
    for (int rr2 = 0; rr2 < 4; rr2++) {
      int rr = m0 + 16 * w + quad * 4 + rr2;
      int row = (rr >> 10) * XR + 3 + (rr & 1023);
      xgb[(size_t)row * 4096 + col] = f2bf(accs[i][rr2] + bv);
    }
  }
}

// ---------------- K4: out_proj MFMA GEMM + bias + residual (fp32 out) ----------------
__global__ __launch_bounds__(256) void k_gemm2_mfma(const u16* __restrict__ A,   // yb [2048][2048] bf16
                                                    const u16* __restrict__ W,   // wob [1024][2048] bf16
                                                    const float* __restrict__ bias,
                                                    const float* __restrict__ resid,
                                                    float* __restrict__ out) {
  __shared__ u16 Asm[64 * 40];
  __shared__ u16 Wsm[64 * 40];
  int t = threadIdx.x;
  int m0 = blockIdx.y * 64, n0 = blockIdx.x * 64;
  int srow = t >> 2, koff = (t & 3) * 8;
  const u16* Ag = A + (size_t)(m0 + srow) * DDIM + koff;
  const u16* Wg = W + (size_t)(n0 + srow) * DDIM + koff;
  int w = t >> 6, lane = t & 63;
  int quad = lane >> 4, mr = lane & 15;
  f32x4 z = {0.f, 0.f, 0.f, 0.f};
  f32x4 acc0 = z, acc1 = z, acc2 = z, acc3 = z;
  const u16* arp = &Asm[(16 * w + mr) * 40 + quad * 8];
  const u16* brp = &Wsm[mr * 40 + quad * 8];
  for (int k0 = 0; k0 < DDIM; k0 += 32) {
    uint4 av = *(const uint4*)(Ag + k0);
    uint4 wv = *(const uint4*)(Wg + k0);
    __syncthreads();
    *(uint4*)(&Asm[srow * 40 + koff]) = av;
    *(uint4*)(&Wsm[srow * 40 + koff]) = wv;
    __syncthreads();
    bf16x8 af = *(const bf16x8*)arp;
    bf16x8 b0 = *(const bf16x8*)(brp);
    bf16x8 b1 = *(const bf16x8*)(brp + 16 * 40);
    bf16x8 b2 = *(const bf16x8*)(brp + 32 * 40);
    bf16x8 b3 = *(const bf16x8*)(brp + 48 * 40);
    acc0 = __builtin_amdgcn_mfma_f32_16x16x32_bf16(af, b0, acc0, 0, 0, 0);
    acc1 = __builtin_amdgcn_mfma_f32_16x16x32_bf16(af, b1, acc1, 0, 0, 0);
    acc2 = __builtin_amdgcn_mfma_f32_16x16x32_bf16(af, b2, acc2, 0, 0, 0);
    acc3 = __builtin_amdgcn_mfma_f32_16x16x32_bf16(af, b3, acc3, 0, 0, 0);
  }
  f32x4 accs[4] = {acc0, acc1, acc2, acc3};
#pragma unroll
  for (int i = 0; i < 4; i++) {
    int col = n0 + 16 * i + mr;
    float bv = bias[col];
#pragma unroll
    for (int rr2 = 0; rr2 < 4; rr2++) {
      int gout = m0 + 16 * w + quad * 4 + rr2;
      out[(size_t)gout * HDIM + col] =
          accs[i][rr2] + bv + resid[(size_t)gout * HDIM + col];
    }
  }
}

// ---------------- K2: conv+silu (LDS) then x_proj; token-major proj[BL][96] ----------------
__global__ __launch_bounds__(256) void k_xprojc(const u16* __restrict__ xgb,
                                                const float* __restrict__ cw,
                                                const float* __restrict__ cb,
                                                const float* __restrict__ w,
                                                const float* __restrict__ b,
                                                float* __restrict__ proj) {
  __shared__ float row[DDIM];
  int bb = blockIdx.x >> 10, l = blockIdx.x & 1023;
  int t = threadIdx.x;
  int d = t * 8;
  float acc[8];
#pragma unroll
  for (int i = 0; i < 8; i++) acc[i] = cb[d + i];
  float cwv[8][4];
#pragma unroll
  for (int i = 0; i < 8; i++) {
    float4 v = *(const float4*)(cw + (d + i) * 4);
    cwv[i][0] = v.x; cwv[i][1] = v.y; cwv[i][2] = v.z; cwv[i][3] = v.w;
  }
#pragma unroll
  for (int j = 0; j < 4; j++) {
    if (l - 3 + j >= 0) {
      const u16* xr = xgb + (size_t)(bb * XR + l + j) * 4096 + d;
      ushort4 v0 = *(const ushort4*)xr;
      ushort4 v1 = *(const ushort4*)(xr + 4);
      acc[0] += bf2f(v0.x) * cwv[0][j]; acc[1] += bf2f(v0.y) * cwv[1][j];
      acc[2] += bf2f(v0.z) * cwv[2][j]; acc[3] += bf2f(v0.w) * cwv[3][j];
      acc[4] += bf2f(v1.x) * cwv[4][j]; acc[5] += bf2f(v1.y) * cwv[5][j];
      acc[6] += bf2f(v1.z) * cwv[6][j]; acc[7] += bf2f(v1.w) * cwv[7][j];
    }
  }
#pragma unroll
  for (int i = 0; i < 8; i++) row[d + i] = silu_f(acc[i]);
  __syncthreads();
  int wv = t >> 6, lane = t & 63;
  const float4* row4 = (const float4*)row;
  int tk = (bb << 10) + l;
  for (int o = wv; o < 96; o += 4) {
    const float4* wr4 = (const float4*)(w + (size_t)o * DDIM);
    float s0 = 0.f, s1 = 0.f, s2 = 0.f, s3 = 0.f;
#pragma unroll
    for (int k4 = 0; k4 < 8; k4++) {
      int idx = (k4 << 6) + lane;
      float4 wv4 = wr4[idx];
      float4 rv4 = row4[idx];
      s0 += rv4.x * wv4.x; s1 += rv4.y * wv4.y;
      s2 += rv4.z * wv4.z; s3 += rv4.w * wv4.w;
    }
    float s = (s0 + s1) + (s2 + s3);
    s += __shfl_xor(s, 32); s += __shfl_xor(s, 16);
    s += __shfl_xor(s, 8);  s += __shfl_xor(s, 4);
    s += __shfl_xor(s, 2);  s += __shfl_xor(s, 1);
    if (lane == 0) proj[(size_t)tk * 96 + o] = s + b[o];
  }
}

// ---------------- K2b: transpose proj[BL][96] -> projT[96][BL] ----------------
__global__ __launch_bounds__(256) void k_transpose(const float* __restrict__ proj,
                                                   float* __restrict__ projT) {
  __shared__ float tile[64][97];
  int blk = blockIdx.x;                 // 32 blocks: b = blk>>4, 64-token segment = blk&15
  int b = blk >> 4;
  int tok0 = (b << 10) + (blk & 15) * 64;
  int t = threadIdx.x;
  const float* src = proj + (size_t)tok0 * 96;
#pragma unroll
  for (int i = 0; i < 24; i++) {
    int idx = t + i * 256;
    int row = idx / 96, col = idx - row * 96;
    tile[row][col] = src[idx];
  }
  __syncthreads();
  int wv = t >> 6, lane = t & 63;
#pragma unroll
  for (int i = 0; i < 24; i++) {
    int o = wv + i * 4;
    projT[(size_t)o * BL + tok0 + lane] = tile[lane][o];
  }
}

// ---------------- K3: full-sequence selective scan ----------------
// LDS cut 31.2KB -> ~13.3KB: {dsp, Dlp} (dead after main-loop register setup)
// alias the two cross-wave y-reduction buffers; reduction is 2-phase
// (waves 2/3 write partials, waves 0/1 fused read-add-write, final sums 2).
// __launch_bounds__(256,8) pins VGPR<=64 -> 8 blocks/CU (thread cap), up
// from 5 (LDS cap).  softplus: log1pf libcall -> __logf(1+e).
__global__ __launch_bounds__(256, 8) void k_scan(const float* __restrict__ projT,
                                              const u16* __restrict__ xgb,
                                              const float* __restrict__ cw,
                                              const float* __restrict__ cb,
                                              const float* __restrict__ dtw,
                                              const float* __restrict__ dtb,
                                              const float* __restrict__ alog,
                                              const float* __restrict__ dparam,
                                              const float* __restrict__ cs,
                                              u16* __restrict__ yb) {
  __shared__ float dtw_s[64];
  __shared__ float wtot[4];
  __shared__ float xcp[1088];    // conv+silu x, padded (tok>>4)*17 + (tok&15); persistent
  __shared__ float bufA[1088];   // dsp  -> y-partial (wave2, then wave0)
  __shared__ float bufB[1088];   // xls -> Dlp -> y-partial (wave3, then wave1)

  int t = threadIdx.x;
  // XCD-aware swizzle: XCD x owns a contiguous 512-wide d range
  int cidx = ((blockIdx.x & 7) << 9) | (blockIdx.x >> 3);   // (b,d)
  int b = cidx >> 11;
  int d = cidx & (DDIM - 1);
  int wv = t >> 6, lane = t & 63;

  if (t < 64) dtw_s[t] = dtw[(size_t)d * 64 + t];
  float4 cwv = *(const float4*)(cw + d * 4);
  float cbv = cb[d];
  float dtbv = dtb[d];
  float Dp = dparam[d];
  const u16* xcol = xgb + (size_t)(b * XR + 3) * 4096 + d;      // x half
  const u16* gcol = xcol + DDIM;                                // gate half
  u16* ycol = yb + ((size_t)(b << 10)) * DDIM + d;
  int colbase = b << 10;

  // ---- stage x column (3-halo) into bufB (linear layout) ----
  float* xls = bufB;
  if (t < 3) xls[t] = 0.f;
#pragma unroll
  for (int k = 0; k < 4; k++) {
    int tok = t + (k << 8);
    xls[3 + tok] = bf2f(xcol[(size_t)tok * 4096]);
  }
  __syncthreads();                       // B1: staging + dtw_s visible

  int tok0 = t << 2;   // this thread owns tokens 4t..4t+3 for prep phases
  // ---- conv + silu -> xcp ----
#pragma unroll
  for (int i = 0; i < 4; i++) {
    int tok = tok0 + i;
    float xc = silu_f(cbv + cwv.x * xls[tok] + cwv.y * xls[tok + 1] +
                      cwv.z * xls[tok + 2] + cwv.w * xls[tok + 3]);
    xcp[((tok >> 4) * 17) + (tok & 15)] = xc;
  }
  // ---- delta = softplus(dt-dot) -> bufA ----
  float d0, d1, d2, d3;
  {
    float4 acc = {dtbv, dtbv, dtbv, dtbv};
    const float* pr = projT + colbase + tok0;
#pragma unroll 8
    for (int kk = 0; kk < 64; kk++) {
      float4 v = *(const float4*)(pr + (size_t)kk * BL);
      float wk = dtw_s[kk];
      acc.x += v.x * wk; acc.y += v.y * wk; acc.z += v.z * wk; acc.w += v.w * wk;
    }
    d0 = (acc.x > 20.f) ? acc.x : __logf(1.f + __expf(acc.x));
    d1 = (acc.y > 20.f) ? acc.y : __logf(1.f + __expf(acc.y));
    d2 = (acc.z > 20.f) ? acc.z : __logf(1.f + __expf(acc.z));
    d3 = (acc.w > 20.f) ? acc.w : __logf(1.f + __expf(acc.w));
    bufA[((tok0 >> 4) * 17) + (tok0 & 15)]             = d0;
    bufA[(((tok0 + 1) >> 4) * 17) + ((tok0 + 1) & 15)] = d1;
    bufA[(((tok0 + 2) >> 4) * 17) + ((tok0 + 2) & 15)] = d2;
    bufA[(((tok0 + 3) >> 4) * 17) + ((tok0 + 3) & 15)] = d3;
  }
  // ---- global inclusive prefix of delta (chunk-serial + one wave scan) ----
  float c0 = d0, c1 = c0 + d1, c2 = c1 + d2, c3 = c2 + d3;
  float sc = c3;
#pragma unroll
  for (int off = 1; off < 64; off <<= 1) {
    float u = __shfl_up(sc, off);
    if (lane >= off) sc += u;
  }
  if (lane == 63) wtot[wv] = sc;
  __syncthreads();                       // B2: conv xls-reads done; wtot visible
  {
    float base = sc - c3;
#pragma unroll
    for (int i = 0; i < 3; i++) if (i < wv) base += wtot[i];
    bufB[((tok0 >> 4) * 17) + (tok0 & 15)]             = base + c0;   // Dlp
    bufB[(((tok0 + 1) >> 4) * 17) + ((tok0 + 1) & 15)] = base + c1;
    bufB[(((tok0 + 2) >> 4) * 17) + ((tok0 + 2) & 15)] = base + c2;
    bufB[(((tok0 + 3) >> 4) * 17) + ((tok0 + 3) & 15)] = base + c3;
  }
  __syncthreads();                       // B3: Dlp visible

  // ---- register setup: lane owns tokens 16*lane .. 16*lane+15 ----
  int pb = lane * 17;
  float uv[16], Dl16[16], y[16];
#pragma unroll
  for (int i = 0; i < 16; i++) {
    uv[i]   = bufA[pb + i] * xcp[pb + i];   // delta * conv_x
    Dl16[i] = bufB[pb + i];
    y[i] = 0.f;
  }
  float Dprev = (lane == 0) ? 0.f : bufB[pb - 2];   // = Dlp[(lane-1)*17 + 15]
  __syncthreads();                       // B4: bufA/bufB reads complete before reuse

#pragma unroll 1
  for (int r = 0; r < 4; r++) {
    int n = (wv << 2) + r;
    float An = -__expf(alog[d * NST + n]);
    float st = cs[(size_t)(b * DDIM + d) * NST + n];
    const float* pB = projT + (size_t)(64 + n) * BL + colbase + (lane << 4);
    float Bv[16];
    *(float4*)(Bv + 0)  = *(const float4*)(pB + 0);
    *(float4*)(Bv + 4)  = *(const float4*)(pB + 4);
    *(float4*)(Bv + 8)  = *(const float4*)(pB + 8);
    *(float4*)(Bv + 12) = *(const float4*)(pB + 12);
    float P[16], w[16];
    float Pp0 = __expf(An * Dprev);
    float Pp = Pp0;
    float wsum = 0.f;
#pragma unroll
    for (int i = 0; i < 16; i++) {
      P[i] = __expf(An * Dl16[i]);
      w[i] = uv[i] * Bv[i] * __builtin_amdgcn_rcpf(fmaxf(Pp, 1e-10f));
      wsum += w[i];
      Pp = P[i];
    }
    // one 64-lane scan of lane totals -> exclusive offset
    float s2 = wsum;
#pragma unroll
    for (int off = 1; off < 64; off <<= 1) {
      float u = __shfl_up(s2, off);
      if (lane >= off) s2 += u;
    }
    float S = s2 - wsum;   // exclusive prefix for this lane
    const float* pC = projT + (size_t)(80 + n) * BL + colbase + (lane << 4);
    float Cv[16];
    *(float4*)(Cv + 0)  = *(const float4*)(pC + 0);
    *(float4*)(Cv + 4)  = *(const float4*)(pC + 4);
    *(float4*)(Cv + 8)  = *(const float4*)(pC + 8);
    *(float4*)(Cv + 12) = *(const float4*)(pC + 12);
    Pp = Pp0;
#pragma unroll
    for (int i = 0; i < 16; i++) {
      S += w[i];
      y[i] += (S * Pp + st * P[i]) * Cv[i];
      Pp = P[i];
    }
  }
  // ---- 2-phase cross-wave y reduction in 2 buffers ----
  if (wv == 2) {
#pragma unroll
    for (int i = 0; i < 16; i++) bufA[pb + i] = y[i];
  } else if (wv == 3) {
#pragma unroll
    for (int i = 0; i < 16; i++) bufB[pb + i] = y[i];
  }
  __syncthreads();                       // B5: partials of waves 2,3 visible
  if (wv == 0) {
#pragma unroll
    for (int i = 0; i < 16; i++) { y[i] += bufA[pb + i]; bufA[pb + i] = y[i]; }
  } else if (wv == 1) {
#pragma unroll
    for (int i = 0; i < 16; i++) { y[i] += bufB[pb + i]; bufB[pb + i] = y[i]; }
  }
  __syncthreads();                       // B6: combined partials visible
  // ---- y = bufA+bufB + D-term, gate, write bf16 ----
#pragma unroll
  for (int i = 0; i < 4; i++) {
    int tok = tok0 + i;
    int p = ((tok >> 4) * 17) + (tok & 15);
    float yv = bufA[p] + bufB[p] + xcp[p] * Dp;
    float g = bf2f(gcol[(size_t)tok * 4096]);
    ycol[(size_t)tok * DDIM] = f2bf(yv * silu_f(g));
  }
}

extern "C" void kernel_launch(void* const* d_in, const int* in_sizes, int n_in,
                              void* d_out, int out_size, void* d_ws, size_t ws_size,
                              hipStream_t stream) {
  const float* inp    = (const float*)d_in[0];
  const float* cstate = (const float*)d_in[1];
  const float* norm_w = (const float*)d_in[2];
  const float* w1     = (const float*)d_in[3];
  const float* b1     = (const float*)d_in[4];
  const float* convw  = (const float*)d_in[5];
  const float* convb  = (const float*)d_in[6];
  const float* xpw    = (const float*)d_in[7];
  const float* xpb    = (const float*)d_in[8];
  const float* dtw    = (const float*)d_in[9];
  const float* dtb    = (const float*)d_in[10];
  const float* alog   = (const float*)d_in[11];
  const float* dparam = (const float*)d_in[12];
  const float* wo     = (const float*)d_in[13];
  const float* bo     = (const float*)d_in[14];
  float* out = (float*)d_out;

  // workspace layout, 39,378,944 B total
  char* wsb = (char*)d_ws;
  u16*   w1b    = (u16*)(wsb + 0);            //  8,388,608 B  [4096][1024] bf16
  u16*   wob    = (u16*)(wsb + 8388608);      //  4,194,304 B  [1024][2048] bf16
  float* rscale = (float*)(wsb + 12582912);   //      8,192 B  [2048]
  float* proj   = (float*)(wsb + 12591104);   //    786,432 B  [2048][96] token-major
  float* projT  = (float*)(wsb + 13377536);   //    786,432 B  [96][2048] transposed
  u16*   xgb    = (u16*)(wsb + 14163968);     // 16,826,368 B  [2][1027][4096] bf16
  u16*   yb     = (u16*)(wsb + 30990336);     //  8,388,608 B  [2][1024][2048] bf16

  k_castw<<<4096, 256, 0, stream>>>(w1, w1b);
  k_castw<<<2048, 256, 0, stream>>>(wo, wob);
  k_rowscale<<<BL, 256, 0, stream>>>(inp, rscale);
  k_gemm1_mfma<<<dim3(64, 32), 256, 0, stream>>>(inp, w1b, b1, rscale, norm_w, xgb);
  k_xprojc<<<BL, 256, 0, stream>>>(xgb, convw, convb, xpw, xpb, proj);
  k_transpose<<<32, 256, 0, stream>>>(proj, projT);
  k_scan<<<2 * DDIM, 256, 0, stream>>>(projT, xgb, convw, convb, dtw, dtb,
                                       alog, dparam, cstate, yb);
  k_gemm2_mfma<<<dim3(16, 32), 256, 0, stream>>>(yb, wob, bo, inp, out);
}

// Round 4
// 369.505 us; speedup vs baseline: 1.6068x; 1.6068x over previous
//
#include <hip/hip_runtime.h>
#include <stdint.h>

#define LSEQ 1024
#define HDIM 1024
#define DDIM 2048
#define BL 2048
#define NST 16
#define XR 1027          // 3 halo rows (unused, zero-pad region) + 1024 tokens

typedef unsigned short u16;
typedef __attribute__((ext_vector_type(8))) short bf16x8;
typedef __attribute__((ext_vector_type(4))) float f32x4;

// silu via v_rcp (1-ulp rcp; output tolerance is bf16-dominated)
static __device__ __forceinline__ float silu_f(float v) {
  return v * __builtin_amdgcn_rcpf(1.f + __expf(-v));
}
static __device__ __forceinline__ float bf2f(u16 u) {
  union { float f; unsigned int i; } c; c.i = ((unsigned int)u) << 16; return c.f;
}
static __device__ __forceinline__ u16 f2bf(float f) {
  union { float f; unsigned int i; } c; c.f = f;
  unsigned int r = c.i + 0x7fffu + ((c.i >> 16) & 1u);
  return (u16)(r >> 16);
}

// ---------------- cast fp32 -> bf16 (weights, once per launch) ----------------
__global__ __launch_bounds__(256) void k_castw(const float* __restrict__ src,
                                               u16* __restrict__ dst) {
  int idx = blockIdx.x * 256 + threadIdx.x;
  float4 v = ((const float4*)src)[idx];
  ushort4 o;
  o.x = f2bf(v.x); o.y = f2bf(v.y); o.z = f2bf(v.z); o.w = f2bf(v.w);
  ((ushort4*)dst)[idx] = o;
}

// ---------------- per-row rmsnorm scale ----------------
__global__ __launch_bounds__(256) void k_rowscale(const float* __restrict__ inp,
                                                  float* __restrict__ rs) {
  int row = blockIdx.x;
  int t = threadIdx.x;
  float4 xv = *(const float4*)(inp + (size_t)row * HDIM + t * 4);
  float ss = xv.x * xv.x + xv.y * xv.y + xv.z * xv.z + xv.w * xv.w;
  for (int off = 32; off > 0; off >>= 1) ss += __shfl_down(ss, off);
  __shared__ float red[4];
  if ((t & 63) == 0) red[t >> 6] = ss;
  __syncthreads();
  if (t == 0) {
    float tot = red[0] + red[1] + red[2] + red[3];
    rs[row] = rsqrtf(tot * (1.f / HDIM) + 1e-6f);
  }
}

// ---------------- K1: in_proj MFMA GEMM, rmsnorm fused into A staging ----------------
// Full M=2048, N=4096, K=1024. 64x64 tile. Output bf16 xgb [2][XR][4096].
__global__ __launch_bounds__(256) void k_gemm1_mfma(const float* __restrict__ inp,
                                                    const u16* __restrict__ W,
                                                    const float* __restrict__ bias,
                                                    const float* __restrict__ rscale,
                                                    const float* __restrict__ nw,
                                                    u16* __restrict__ xgb) {
  __shared__ u16 Asm[64 * 40];
  __shared__ u16 Wsm[64 * 40];
  int t = threadIdx.x;
  int m0 = blockIdx.y * 64, n0 = blockIdx.x * 64;
  int srow = t >> 2, koff = (t & 3) * 8;
  int gin = m0 + srow;
  const float* Ag = inp + (size_t)gin * HDIM + koff;
  const u16* Wg = W + (size_t)(n0 + srow) * HDIM + koff;
  float scale = rscale[gin];
  int w = t >> 6, lane = t & 63;
  int quad = lane >> 4, mr = lane & 15;
  f32x4 z = {0.f, 0.f, 0.f, 0.f};
  f32x4 acc0 = z, acc1 = z, acc2 = z, acc3 = z;
  const u16* arp = &Asm[(16 * w + mr) * 40 + quad * 8];
  const u16* brp = &Wsm[mr * 40 + quad * 8];
  for (int k0 = 0; k0 < HDIM; k0 += 32) {
    float4 a0 = *(const float4*)(Ag + k0);
    float4 a1 = *(const float4*)(Ag + k0 + 4);
    float4 n0v = *(const float4*)(nw + k0 + koff);
    float4 n1v = *(const float4*)(nw + k0 + koff + 4);
    uint4 wv = *(const uint4*)(Wg + k0);
    ushort4 p0, p1;
    p0.x = f2bf(a0.x * scale * n0v.x); p0.y = f2bf(a0.y * scale * n0v.y);
    p0.z = f2bf(a0.z * scale * n0v.z); p0.w = f2bf(a0.w * scale * n0v.w);
    p1.x = f2bf(a1.x * scale * n1v.x); p1.y = f2bf(a1.y * scale * n1v.y);
    p1.z = f2bf(a1.z * scale * n1v.z); p1.w = f2bf(a1.w * scale * n1v.w);
    __syncthreads();
    *(ushort4*)(&Asm[srow * 40 + koff]) = p0;
    *(ushort4*)(&Asm[srow * 40 + koff + 4]) = p1;
    *(uint4*)(&Wsm[srow * 40 + koff]) = wv;
    __syncthreads();
    bf16x8 af = *(const bf16x8*)arp;
    bf16x8 b0 = *(const bf16x8*)(brp);
    bf16x8 b1 = *(const bf16x8*)(brp + 16 * 40);
    bf16x8 b2 = *(const bf16x8*)(brp + 32 * 40);
    bf16x8 b3 = *(const bf16x8*)(brp + 48 * 40);
    acc0 = __builtin_amdgcn_mfma_f32_16x16x32_bf16(af, b0, acc0, 0, 0, 0);
    acc1 = __builtin_amdgcn_mfma_f32_16x16x32_bf16(af, b1, acc1, 0, 0, 0);
    acc2 = __builtin_amdgcn_mfma_f32_16x16x32_bf16(af, b2, acc2, 0, 0, 0);
    acc3 = __builtin_amdgcn_mfma_f32_16x16x32_bf16(af, b3, acc3, 0, 0, 0);
  }
  f32x4 accs[4] = {acc0, acc1, acc2, acc3};
#pragma unroll
  for (int i = 0; i < 4; i++) {
    int col = n0 + 16 * i + mr;
    float bv = bias[col];
#pragma unroll
    for (int rr2 = 0; rr2 < 4; rr2++) {
      int rr = m0 + 16 * w + quad * 4 + rr2;
      int row = (rr >> 10) * XR + 3 + (rr & 1023);
      xgb[(size_t)row * 4096 + col] = f2bf(accs[i][rr2] + bv);
    }
  }
}

// ---------------- K4: out_proj MFMA GEMM + bias + residual (fp32 out) ----------------
__global__ __launch_bounds__(256) void k_gemm2_mfma(const u16* __restrict__ A,   // yb [2048][2048] bf16
                                                    const u16* __restrict__ W,   // wob [1024][2048] bf16
                                                    const float* __restrict__ bias,
                                                    const float* __restrict__ resid,
                                                    float* __restrict__ out) {
  __shared__ u16 Asm[64 * 40];
  __shared__ u16 Wsm[64 * 40];
  int t = threadIdx.x;
  int m0 = blockIdx.y * 64, n0 = blockIdx.x * 64;
  int srow = t >> 2, koff = (t & 3) * 8;
  const u16* Ag = A + (size_t)(m0 + srow) * DDIM + koff;
  const u16* Wg = W + (size_t)(n0 + srow) * DDIM + koff;
  int w = t >> 6, lane = t & 63;
  int quad = lane >> 4, mr = lane & 15;
  f32x4 z = {0.f, 0.f, 0.f, 0.f};
  f32x4 acc0 = z, acc1 = z, acc2 = z, acc3 = z;
  const u16* arp = &Asm[(16 * w + mr) * 40 + quad * 8];
  const u16* brp = &Wsm[mr * 40 + quad * 8];
  for (int k0 = 0; k0 < DDIM; k0 += 32) {
    uint4 av = *(const uint4*)(Ag + k0);
    uint4 wv = *(const uint4*)(Wg + k0);
    __syncthreads();
    *(uint4*)(&Asm[srow * 40 + koff]) = av;
    *(uint4*)(&Wsm[srow * 40 + koff]) = wv;
    __syncthreads();
    bf16x8 af = *(const bf16x8*)arp;
    bf16x8 b0 = *(const bf16x8*)(brp);
    bf16x8 b1 = *(const bf16x8*)(brp + 16 * 40);
    bf16x8 b2 = *(const bf16x8*)(brp + 32 * 40);
    bf16x8 b3 = *(const bf16x8*)(brp + 48 * 40);
    acc0 = __builtin_amdgcn_mfma_f32_16x16x32_bf16(af, b0, acc0, 0, 0, 0);
    acc1 = __builtin_amdgcn_mfma_f32_16x16x32_bf16(af, b1, acc1, 0, 0, 0);
    acc2 = __builtin_amdgcn_mfma_f32_16x16x32_bf16(af, b2, acc2, 0, 0, 0);
    acc3 = __builtin_amdgcn_mfma_f32_16x16x32_bf16(af, b3, acc3, 0, 0, 0);
  }
  f32x4 accs[4] = {acc0, acc1, acc2, acc3};
#pragma unroll
  for (int i = 0; i < 4; i++) {
    int col = n0 + 16 * i + mr;
    float bv = bias[col];
#pragma unroll
    for (int rr2 = 0; rr2 < 4; rr2++) {
      int gout = m0 + 16 * w + quad * 4 + rr2;
      out[(size_t)gout * HDIM + col] =
          accs[i][rr2] + bv + resid[(size_t)gout * HDIM + col];
    }
  }
}

// ---------------- K2: conv+silu (LDS) then x_proj; token-major proj[BL][96] ----------------
__global__ __launch_bounds__(256) void k_xprojc(const u16* __restrict__ xgb,
                                                const float* __restrict__ cw,
                                                const float* __restrict__ cb,
                                                const float* __restrict__ w,
                                                const float* __restrict__ b,
                                                float* __restrict__ proj) {
  __shared__ float row[DDIM];
  int bb = blockIdx.x >> 10, l = blockIdx.x & 1023;
  int t = threadIdx.x;
  int d = t * 8;
  float acc[8];
#pragma unroll
  for (int i = 0; i < 8; i++) acc[i] = cb[d + i];
  float cwv[8][4];
#pragma unroll
  for (int i = 0; i < 8; i++) {
    float4 v = *(const float4*)(cw + (d + i) * 4);
    cwv[i][0] = v.x; cwv[i][1] = v.y; cwv[i][2] = v.z; cwv[i][3] = v.w;
  }
#pragma unroll
  for (int j = 0; j < 4; j++) {
    if (l - 3 + j >= 0) {
      const u16* xr = xgb + (size_t)(bb * XR + l + j) * 4096 + d;
      ushort4 v0 = *(const ushort4*)xr;
      ushort4 v1 = *(const ushort4*)(xr + 4);
      acc[0] += bf2f(v0.x) * cwv[0][j]; acc[1] += bf2f(v0.y) * cwv[1][j];
      acc[2] += bf2f(v0.z) * cwv[2][j]; acc[3] += bf2f(v0.w) * cwv[3][j];
      acc[4] += bf2f(v1.x) * cwv[4][j]; acc[5] += bf2f(v1.y) * cwv[5][j];
      acc[6] += bf2f(v1.z) * cwv[6][j]; acc[7] += bf2f(v1.w) * cwv[7][j];
    }
  }
#pragma unroll
  for (int i = 0; i < 8; i++) row[d + i] = silu_f(acc[i]);
  __syncthreads();
  int wv = t >> 6, lane = t & 63;
  const float4* row4 = (const float4*)row;
  int tk = (bb << 10) + l;
  for (int o = wv; o < 96; o += 4) {
    const float4* wr4 = (const float4*)(w + (size_t)o * DDIM);
    float s0 = 0.f, s1 = 0.f, s2 = 0.f, s3 = 0.f;
#pragma unroll
    for (int k4 = 0; k4 < 8; k4++) {
      int idx = (k4 << 6) + lane;
      float4 wv4 = wr4[idx];
      float4 rv4 = row4[idx];
      s0 += rv4.x * wv4.x; s1 += rv4.y * wv4.y;
      s2 += rv4.z * wv4.z; s3 += rv4.w * wv4.w;
    }
    float s = (s0 + s1) + (s2 + s3);
    s += __shfl_xor(s, 32); s += __shfl_xor(s, 16);
    s += __shfl_xor(s, 8);  s += __shfl_xor(s, 4);
    s += __shfl_xor(s, 2);  s += __shfl_xor(s, 1);
    if (lane == 0) proj[(size_t)tk * 96 + o] = s + b[o];
  }
}

// ---------------- K2b: transpose proj[BL][96] -> projT[96][BL] ----------------
__global__ __launch_bounds__(256) void k_transpose(const float* __restrict__ proj,
                                                   float* __restrict__ projT) {
  __shared__ float tile[64][97];
  int blk = blockIdx.x;                 // 32 blocks: b = blk>>4, 64-token segment = blk&15
  int b = blk >> 4;
  int tok0 = (b << 10) + (blk & 15) * 64;
  int t = threadIdx.x;
  const float* src = proj + (size_t)tok0 * 96;
#pragma unroll
  for (int i = 0; i < 24; i++) {
    int idx = t + i * 256;
    int row = idx / 96, col = idx - row * 96;
    tile[row][col] = src[idx];
  }
  __syncthreads();
  int wv = t >> 6, lane = t & 63;
#pragma unroll
  for (int i = 0; i < 24; i++) {
    int o = wv + i * 4;
    projT[(size_t)o * BL + tok0 + lane] = tile[lane][o];
  }
}

// ---------------- K3: full-sequence selective scan ----------------
// LDS ~13.3KB (dsp/Dlp alias the 2-buffer cross-wave y reduction).
// NO min-waves clause: R3's (256,8) squeezed VGPR to 32 -> 1.1GB of scratch
// spill traffic (FETCH 533MB/WRITE 542MB), dur 337us.  Natural allocation
// is ~60 VGPR (R2) -> no spill; LDS no longer the occupancy limiter.
__global__ __launch_bounds__(256) void k_scan(const float* __restrict__ projT,
                                              const u16* __restrict__ xgb,
                                              const float* __restrict__ cw,
                                              const float* __restrict__ cb,
                                              const float* __restrict__ dtw,
                                              const float* __restrict__ dtb,
                                              const float* __restrict__ alog,
                                              const float* __restrict__ dparam,
                                              const float* __restrict__ cs,
                                              u16* __restrict__ yb) {
  __shared__ float dtw_s[64];
  __shared__ float wtot[4];
  __shared__ float xcp[1088];    // conv+silu x, padded (tok>>4)*17 + (tok&15); persistent
  __shared__ float bufA[1088];   // dsp  -> y-partial (wave2, then wave0)
  __shared__ float bufB[1088];   // xls -> Dlp -> y-partial (wave3, then wave1)

  int t = threadIdx.x;
  // XCD-aware swizzle: XCD x owns a contiguous 512-wide d range
  int cidx = ((blockIdx.x & 7) << 9) | (blockIdx.x >> 3);   // (b,d)
  int b = cidx >> 11;
  int d = cidx & (DDIM - 1);
  int wv = t >> 6, lane = t & 63;

  if (t < 64) dtw_s[t] = dtw[(size_t)d * 64 + t];
  float4 cwv = *(const float4*)(cw + d * 4);
  float cbv = cb[d];
  float dtbv = dtb[d];
  float Dp = dparam[d];
  const u16* xcol = xgb + (size_t)(b * XR + 3) * 4096 + d;      // x half
  const u16* gcol = xcol + DDIM;                                // gate half
  u16* ycol = yb + ((size_t)(b << 10)) * DDIM + d;
  int colbase = b << 10;

  // ---- stage x column (3-halo) into bufB (linear layout) ----
  float* xls = bufB;
  if (t < 3) xls[t] = 0.f;
#pragma unroll
  for (int k = 0; k < 4; k++) {
    int tok = t + (k << 8);
    xls[3 + tok] = bf2f(xcol[(size_t)tok * 4096]);
  }
  __syncthreads();                       // B1: staging + dtw_s visible

  int tok0 = t << 2;   // this thread owns tokens 4t..4t+3 for prep phases
  // ---- conv + silu -> xcp ----
#pragma unroll
  for (int i = 0; i < 4; i++) {
    int tok = tok0 + i;
    float xc = silu_f(cbv + cwv.x * xls[tok] + cwv.y * xls[tok + 1] +
                      cwv.z * xls[tok + 2] + cwv.w * xls[tok + 3]);
    xcp[((tok >> 4) * 17) + (tok & 15)] = xc;
  }
  // ---- delta = softplus(dt-dot) -> bufA ----
  float d0, d1, d2, d3;
  {
    float4 acc = {dtbv, dtbv, dtbv, dtbv};
    const float* pr = projT + colbase + tok0;
#pragma unroll 8
    for (int kk = 0; kk < 64; kk++) {
      float4 v = *(const float4*)(pr + (size_t)kk * BL);
      float wk = dtw_s[kk];
      acc.x += v.x * wk; acc.y += v.y * wk; acc.z += v.z * wk; acc.w += v.w * wk;
    }
    d0 = (acc.x > 20.f) ? acc.x : __logf(1.f + __expf(acc.x));
    d1 = (acc.y > 20.f) ? acc.y : __logf(1.f + __expf(acc.y));
    d2 = (acc.z > 20.f) ? acc.z : __logf(1.f + __expf(acc.z));
    d3 = (acc.w > 20.f) ? acc.w : __logf(1.f + __expf(acc.w));
    bufA[((tok0 >> 4) * 17) + (tok0 & 15)]             = d0;
    bufA[(((tok0 + 1) >> 4) * 17) + ((tok0 + 1) & 15)] = d1;
    bufA[(((tok0 + 2) >> 4) * 17) + ((tok0 + 2) & 15)] = d2;
    bufA[(((tok0 + 3) >> 4) * 17) + ((tok0 + 3) & 15)] = d3;
  }
  // ---- global inclusive prefix of delta (chunk-serial + one wave scan) ----
  float c0 = d0, c1 = c0 + d1, c2 = c1 + d2, c3 = c2 + d3;
  float sc = c3;
#pragma unroll
  for (int off = 1; off < 64; off <<= 1) {
    float u = __shfl_up(sc, off);
    if (lane >= off) sc += u;
  }
  if (lane == 63) wtot[wv] = sc;
  __syncthreads();                       // B2: conv xls-reads done; wtot visible
  {
    float base = sc - c3;
#pragma unroll
    for (int i = 0; i < 3; i++) if (i < wv) base += wtot[i];
    bufB[((tok0 >> 4) * 17) + (tok0 & 15)]             = base + c0;   // Dlp
    bufB[(((tok0 + 1) >> 4) * 17) + ((tok0 + 1) & 15)] = base + c1;
    bufB[(((tok0 + 2) >> 4) * 17) + ((tok0 + 2) & 15)] = base + c2;
    bufB[(((tok0 + 3) >> 4) * 17) + ((tok0 + 3) & 15)] = base + c3;
  }
  __syncthreads();                       // B3: Dlp visible

  // ---- register setup: lane owns tokens 16*lane .. 16*lane+15 ----
  int pb = lane * 17;
  float uv[16], Dl16[16], y[16];
#pragma unroll
  for (int i = 0; i < 16; i++) {
    uv[i]   = bufA[pb + i] * xcp[pb + i];   // delta * conv_x
    Dl16[i] = bufB[pb + i];
    y[i] = 0.f;
  }
  float Dprev = (lane == 0) ? 0.f : bufB[pb - 2];   // = Dlp[(lane-1)*17 + 15]
  __syncthreads();                       // B4: bufA/bufB reads complete before reuse

#pragma unroll 1
  for (int r = 0; r < 4; r++) {
    int n = (wv << 2) + r;
    float An = -__expf(alog[d * NST + n]);
    float st = cs[(size_t)(b * DDIM + d) * NST + n];
    const float* pB = projT + (size_t)(64 + n) * BL + colbase + (lane << 4);
    float Bv[16];
    *(float4*)(Bv + 0)  = *(const float4*)(pB + 0);
    *(float4*)(Bv + 4)  = *(const float4*)(pB + 4);
    *(float4*)(Bv + 8)  = *(const float4*)(pB + 8);
    *(float4*)(Bv + 12) = *(const float4*)(pB + 12);
    float P[16], w[16];
    float Pp0 = __expf(An * Dprev);
    float Pp = Pp0;
    float wsum = 0.f;
#pragma unroll
    for (int i = 0; i < 16; i++) {
      P[i] = __expf(An * Dl16[i]);
      w[i] = uv[i] * Bv[i] * __builtin_amdgcn_rcpf(fmaxf(Pp, 1e-10f));
      wsum += w[i];
      Pp = P[i];
    }
    // one 64-lane scan of lane totals -> exclusive offset
    float s2 = wsum;
#pragma unroll
    for (int off = 1; off < 64; off <<= 1) {
      float u = __shfl_up(s2, off);
      if (lane >= off) s2 += u;
    }
    float S = s2 - wsum;   // exclusive prefix for this lane
    const float* pC = projT + (size_t)(80 + n) * BL + colbase + (lane << 4);
    float Cv[16];
    *(float4*)(Cv + 0)  = *(const float4*)(pC + 0);
    *(float4*)(Cv + 4)  = *(const float4*)(pC + 4);
    *(float4*)(Cv + 8)  = *(const float4*)(pC + 8);
    *(float4*)(Cv + 12) = *(const float4*)(pC + 12);
    Pp = Pp0;
#pragma unroll
    for (int i = 0; i < 16; i++) {
      S += w[i];
      y[i] += (S * Pp + st * P[i]) * Cv[i];
      Pp = P[i];
    }
  }
  // ---- 2-phase cross-wave y reduction in 2 buffers ----
  if (wv == 2) {
#pragma unroll
    for (int i = 0; i < 16; i++) bufA[pb + i] = y[i];
  } else if (wv == 3) {
#pragma unroll
    for (int i = 0; i < 16; i++) bufB[pb + i] = y[i];
  }
  __syncthreads();                       // B5: partials of waves 2,3 visible
  if (wv == 0) {
#pragma unroll
    for (int i = 0; i < 16; i++) { y[i] += bufA[pb + i]; bufA[pb + i] = y[i]; }
  } else if (wv == 1) {
#pragma unroll
    for (int i = 0; i < 16; i++) { y[i] += bufB[pb + i]; bufB[pb + i] = y[i]; }
  }
  __syncthreads();                       // B6: combined partials visible
  // ---- y = bufA+bufB + D-term, gate, write bf16 ----
#pragma unroll
  for (int i = 0; i < 4; i++) {
    int tok = tok0 + i;
    int p = ((tok >> 4) * 17) + (tok & 15);
    float yv = bufA[p] + bufB[p] + xcp[p] * Dp;
    float g = bf2f(gcol[(size_t)tok * 4096]);
    ycol[(size_t)tok * DDIM] = f2bf(yv * silu_f(g));
  }
}

extern "C" void kernel_launch(void* const* d_in, const int* in_sizes, int n_in,
                              void* d_out, int out_size, void* d_ws, size_t ws_size,
                              hipStream_t stream) {
  const float* inp    = (const float*)d_in[0];
  const float* cstate = (const float*)d_in[1];
  const float* norm_w = (const float*)d_in[2];
  const float* w1     = (const float*)d_in[3];
  const float* b1     = (const float*)d_in[4];
  const float* convw  = (const float*)d_in[5];
  const float* convb  = (const float*)d_in[6];
  const float* xpw    = (const float*)d_in[7];
  const float* xpb    = (const float*)d_in[8];
  const float* dtw    = (const float*)d_in[9];
  const float* dtb    = (const float*)d_in[10];
  const float* alog   = (const float*)d_in[11];
  const float* dparam = (const float*)d_in[12];
  const float* wo     = (const float*)d_in[13];
  const float* bo     = (const float*)d_in[14];
  float* out = (float*)d_out;

  // workspace layout, 39,378,944 B total
  char* wsb = (char*)d_ws;
  u16*   w1b    = (u16*)(wsb + 0);            //  8,388,608 B  [4096][1024] bf16
  u16*   wob    = (u16*)(wsb + 8388608);      //  4,194,304 B  [1024][2048] bf16
  float* rscale = (float*)(wsb + 12582912);   //      8,192 B  [2048]
  float* proj   = (float*)(wsb + 12591104);   //    786,432 B  [2048][96] token-major
  float* projT  = (float*)(wsb + 13377536);   //    786,432 B  [96][2048] transposed
  u16*   xgb    = (u16*)(wsb + 14163968);     // 16,826,368 B  [2][1027][4096] bf16
  u16*   yb     = (u16*)(wsb + 30990336);     //  8,388,608 B  [2][1024][2048] bf16

  k_castw<<<4096, 256, 0, stream>>>(w1, w1b);
  k_castw<<<2048, 256, 0, stream>>>(wo, wob);
  k_rowscale<<<BL, 256, 0, stream>>>(inp, rscale);
  k_gemm1_mfma<<<dim3(64, 32), 256, 0, stream>>>(inp, w1b, b1, rscale, norm_w, xgb);
  k_xprojc<<<BL, 256, 0, stream>>>(xgb, convw, convb, xpw, xpb, proj);
  k_transpose<<<32, 256, 0, stream>>>(proj, projT);
  k_scan<<<2 * DDIM, 256, 0, stream>>>(projT, xgb, convw, convb, dtw, dtb,
                                       alog, dparam, cstate, yb);
  k_gemm2_mfma<<<dim3(16, 32), 256, 0, stream>>>(yb, wob, bo, inp, out);
}

// Round 5
// 365.539 us; speedup vs baseline: 1.6242x; 1.0108x over previous
//
#include <hip/hip_runtime.h>
#include <stdint.h>

#define LSEQ 1024
#define HDIM 1024
#define DDIM 2048
#define BL 2048
#define NST 16
#define XR 1027          // 3 halo rows (unused, zero-pad region) + 1024 tokens

typedef unsigned short u16;
typedef __attribute__((ext_vector_type(8))) short bf16x8;
typedef __attribute__((ext_vector_type(4))) float f32x4;

// silu via v_rcp (1-ulp rcp; output tolerance is bf16-dominated)
static __device__ __forceinline__ float silu_f(float v) {
  return v * __builtin_amdgcn_rcpf(1.f + __expf(-v));
}
static __device__ __forceinline__ float bf2f(u16 u) {
  union { float f; unsigned int i; } c; c.i = ((unsigned int)u) << 16; return c.f;
}
static __device__ __forceinline__ u16 f2bf(float f) {
  union { float f; unsigned int i; } c; c.f = f;
  unsigned int r = c.i + 0x7fffu + ((c.i >> 16) & 1u);
  return (u16)(r >> 16);
}

// ---------------- cast fp32 -> bf16 (weights, once per launch) ----------------
__global__ __launch_bounds__(256) void k_castw(const float* __restrict__ src,
                                               u16* __restrict__ dst) {
  int idx = blockIdx.x * 256 + threadIdx.x;
  float4 v = ((const float4*)src)[idx];
  ushort4 o;
  o.x = f2bf(v.x); o.y = f2bf(v.y); o.z = f2bf(v.z); o.w = f2bf(v.w);
  ((ushort4*)dst)[idx] = o;
}

// ---------------- per-row rmsnorm scale ----------------
__global__ __launch_bounds__(256) void k_rowscale(const float* __restrict__ inp,
                                                  float* __restrict__ rs) {
  int row = blockIdx.x;
  int t = threadIdx.x;
  float4 xv = *(const float4*)(inp + (size_t)row * HDIM + t * 4);
  float ss = xv.x * xv.x + xv.y * xv.y + xv.z * xv.z + xv.w * xv.w;
  for (int off = 32; off > 0; off >>= 1) ss += __shfl_down(ss, off);
  __shared__ float red[4];
  if ((t & 63) == 0) red[t >> 6] = ss;
  __syncthreads();
  if (t == 0) {
    float tot = red[0] + red[1] + red[2] + red[3];
    rs[row] = rsqrtf(tot * (1.f / HDIM) + 1e-6f);
  }
}

// ---------------- K1: in_proj MFMA GEMM, rmsnorm fused into A staging ----------------
// Full M=2048, N=4096, K=1024. 64x64 tile. Output bf16 xgb [2][XR][4096].
__global__ __launch_bounds__(256) void k_gemm1_mfma(const float* __restrict__ inp,
                                                    const u16* __restrict__ W,
                                                    const float* __restrict__ bias,
                                                    const float* __restrict__ rscale,
                                                    const float* __restrict__ nw,
                                                    u16* __restrict__ xgb) {
  __shared__ u16 Asm[64 * 40];
  __shared__ u16 Wsm[64 * 40];
  int t = threadIdx.x;
  int m0 = blockIdx.y * 64, n0 = blockIdx.x * 64;
  int srow = t >> 2, koff = (t & 3) * 8;
  int gin = m0 + srow;
  const float* Ag = inp + (size_t)gin * HDIM + koff;
  const u16* Wg = W + (size_t)(n0 + srow) * HDIM + koff;
  float scale = rscale[gin];
  int w = t >> 6, lane = t & 63;
  int quad = lane >> 4, mr = lane & 15;
  f32x4 z = {0.f, 0.f, 0.f, 0.f};
  f32x4 acc0 = z, acc1 = z, acc2 = z, acc3 = z;
  const u16* arp = &Asm[(16 * w + mr) * 40 + quad * 8];
  const u16* brp = &Wsm[mr * 40 + quad * 8];
  for (int k0 = 0; k0 < HDIM; k0 += 32) {
    float4 a0 = *(const float4*)(Ag + k0);
    float4 a1 = *(const float4*)(Ag + k0 + 4);
    float4 n0v = *(const float4*)(nw + k0 + koff);
    float4 n1v = *(const float4*)(nw + k0 + koff + 4);
    uint4 wv = *(const uint4*)(Wg + k0);
    ushort4 p0, p1;
    p0.x = f2bf(a0.x * scale * n0v.x); p0.y = f2bf(a0.y * scale * n0v.y);
    p0.z = f2bf(a0.z * scale * n0v.z); p0.w = f2bf(a0.w * scale * n0v.w);
    p1.x = f2bf(a1.x * scale * n1v.x); p1.y = f2bf(a1.y * scale * n1v.y);
    p1.z = f2bf(a1.z * scale * n1v.z); p1.w = f2bf(a1.w * scale * n1v.w);
    __syncthreads();
    *(ushort4*)(&Asm[srow * 40 + koff]) = p0;
    *(ushort4*)(&Asm[srow * 40 + koff + 4]) = p1;
    *(uint4*)(&Wsm[srow * 40 + koff]) = wv;
    __syncthreads();
    bf16x8 af = *(const bf16x8*)arp;
    bf16x8 b0 = *(const bf16x8*)(brp);
    bf16x8 b1 = *(const bf16x8*)(brp + 16 * 40);
    bf16x8 b2 = *(const bf16x8*)(brp + 32 * 40);
    bf16x8 b3 = *(const bf16x8*)(brp + 48 * 40);
    acc0 = __builtin_amdgcn_mfma_f32_16x16x32_bf16(af, b0, acc0, 0, 0, 0);
    acc1 = __builtin_amdgcn_mfma_f32_16x16x32_bf16(af, b1, acc1, 0, 0, 0);
    acc2 = __builtin_amdgcn_mfma_f32_16x16x32_bf16(af, b2, acc2, 0, 0, 0);
    acc3 = __builtin_amdgcn_mfma_f32_16x16x32_bf16(af, b3, acc3, 0, 0, 0);
  }
  f32x4 accs[4] = {acc0, acc1, acc2, acc3};
#pragma unroll
  for (int i = 0; i < 4; i++) {
    int col = n0 + 16 * i + mr;
    float bv = bias[col];
#pragma unroll
    for (int rr2 = 0; rr2 < 4; rr2++) {
      int rr = m0 + 16 * w + quad * 4 + rr2;
      int row = (rr >> 10) * XR + 3 + (rr & 1023);
      xgb[(size_t)row * 4096 + col] = f2bf(accs[i][rr2] + bv);
    }
  }
}

// ---------------- K4: out_proj MFMA GEMM + bias + residual (fp32 out) ----------------
__global__ __launch_bounds__(256) void k_gemm2_mfma(const u16* __restrict__ A,   // yb [2048][2048] bf16
                                                    const u16* __restrict__ W,   // wob [1024][2048] bf16
                                                    const float* __restrict__ bias,
                                                    const float* __restrict__ resid,
                                                    float* __restrict__ out) {
  __shared__ u16 Asm[64 * 40];
  __shared__ u16 Wsm[64 * 40];
  int t = threadIdx.x;
  int m0 = blockIdx.y * 64, n0 = blockIdx.x * 64;
  int srow = t >> 2, koff = (t & 3) * 8;
  const u16* Ag = A + (size_t)(m0 + srow) * DDIM + koff;
  const u16* Wg = W + (size_t)(n0 + srow) * DDIM + koff;
  int w = t >> 6, lane = t & 63;
  int quad = lane >> 4, mr = lane & 15;
  f32x4 z = {0.f, 0.f, 0.f, 0.f};
  f32x4 acc0 = z, acc1 = z, acc2 = z, acc3 = z;
  const u16* arp = &Asm[(16 * w + mr) * 40 + quad * 8];
  const u16* brp = &Wsm[mr * 40 + quad * 8];
  for (int k0 = 0; k0 < DDIM; k0 += 32) {
    uint4 av = *(const uint4*)(Ag + k0);
    uint4 wv = *(const uint4*)(Wg + k0);
    __syncthreads();
    *(uint4*)(&Asm[srow * 40 + koff]) = av;
    *(uint4*)(&Wsm[srow * 40 + koff]) = wv;
    __syncthreads();
    bf16x8 af = *(const bf16x8*)arp;
    bf16x8 b0 = *(const bf16x8*)(brp);
    bf16x8 b1 = *(const bf16x8*)(brp + 16 * 40);
    bf16x8 b2 = *(const bf16x8*)(brp + 32 * 40);
    bf16x8 b3 = *(const bf16x8*)(brp + 48 * 40);
    acc0 = __builtin_amdgcn_mfma_f32_16x16x32_bf16(af, b0, acc0, 0, 0, 0);
    acc1 = __builtin_amdgcn_mfma_f32_16x16x32_bf16(af, b1, acc1, 0, 0, 0);
    acc2 = __builtin_amdgcn_mfma_f32_16x16x32_bf16(af, b2, acc2, 0, 0, 0);
    acc3 = __builtin_amdgcn_mfma_f32_16x16x32_bf16(af, b3, acc3, 0, 0, 0);
  }
  f32x4 accs[4] = {acc0, acc1, acc2, acc3};
#pragma unroll
  for (int i = 0; i < 4; i++) {
    int col = n0 + 16 * i + mr;
    float bv = bias[col];
#pragma unroll
    for (int rr2 = 0; rr2 < 4; rr2++) {
      int gout = m0 + 16 * w + quad * 4 + rr2;
      out[(size_t)gout * HDIM + col] =
          accs[i][rr2] + bv + resid[(size_t)gout * HDIM + col];
    }
  }
}

// ---------------- K2: conv+silu (LDS) then x_proj; token-major proj[BL][96] ----------------
__global__ __launch_bounds__(256) void k_xprojc(const u16* __restrict__ xgb,
                                                const float* __restrict__ cw,
                                                const float* __restrict__ cb,
                                                const float* __restrict__ w,
                                                const float* __restrict__ b,
                                                float* __restrict__ proj) {
  __shared__ float row[DDIM];
  int bb = blockIdx.x >> 10, l = blockIdx.x & 1023;
  int t = threadIdx.x;
  int d = t * 8;
  float acc[8];
#pragma unroll
  for (int i = 0; i < 8; i++) acc[i] = cb[d + i];
  float cwv[8][4];
#pragma unroll
  for (int i = 0; i < 8; i++) {
    float4 v = *(const float4*)(cw + (d + i) * 4);
    cwv[i][0] = v.x; cwv[i][1] = v.y; cwv[i][2] = v.z; cwv[i][3] = v.w;
  }
#pragma unroll
  for (int j = 0; j < 4; j++) {
    if (l - 3 + j >= 0) {
      const u16* xr = xgb + (size_t)(bb * XR + l + j) * 4096 + d;
      ushort4 v0 = *(const ushort4*)xr;
      ushort4 v1 = *(const ushort4*)(xr + 4);
      acc[0] += bf2f(v0.x) * cwv[0][j]; acc[1] += bf2f(v0.y) * cwv[1][j];
      acc[2] += bf2f(v0.z) * cwv[2][j]; acc[3] += bf2f(v0.w) * cwv[3][j];
      acc[4] += bf2f(v1.x) * cwv[4][j]; acc[5] += bf2f(v1.y) * cwv[5][j];
      acc[6] += bf2f(v1.z) * cwv[6][j]; acc[7] += bf2f(v1.w) * cwv[7][j];
    }
  }
#pragma unroll
  for (int i = 0; i < 8; i++) row[d + i] = silu_f(acc[i]);
  __syncthreads();
  int wv = t >> 6, lane = t & 63;
  const float4* row4 = (const float4*)row;
  int tk = (bb << 10) + l;
  for (int o = wv; o < 96; o += 4) {
    const float4* wr4 = (const float4*)(w + (size_t)o * DDIM);
    float s0 = 0.f, s1 = 0.f, s2 = 0.f, s3 = 0.f;
#pragma unroll
    for (int k4 = 0; k4 < 8; k4++) {
      int idx = (k4 << 6) + lane;
      float4 wv4 = wr4[idx];
      float4 rv4 = row4[idx];
      s0 += rv4.x * wv4.x; s1 += rv4.y * wv4.y;
      s2 += rv4.z * wv4.z; s3 += rv4.w * wv4.w;
    }
    float s = (s0 + s1) + (s2 + s3);
    s += __shfl_xor(s, 32); s += __shfl_xor(s, 16);
    s += __shfl_xor(s, 8);  s += __shfl_xor(s, 4);
    s += __shfl_xor(s, 2);  s += __shfl_xor(s, 1);
    if (lane == 0) proj[(size_t)tk * 96 + o] = s + b[o];
  }
}

// ---------------- K2b: transpose proj[BL][96] -> projT[96][BL] ----------------
__global__ __launch_bounds__(256) void k_transpose(const float* __restrict__ proj,
                                                   float* __restrict__ projT) {
  __shared__ float tile[64][97];
  int blk = blockIdx.x;                 // 32 blocks: b = blk>>4, 64-token segment = blk&15
  int b = blk >> 4;
  int tok0 = (b << 10) + (blk & 15) * 64;
  int t = threadIdx.x;
  const float* src = proj + (size_t)tok0 * 96;
#pragma unroll
  for (int i = 0; i < 24; i++) {
    int idx = t + i * 256;
    int row = idx / 96, col = idx - row * 96;
    tile[row][col] = src[idx];
  }
  __syncthreads();
  int wv = t >> 6, lane = t & 63;
#pragma unroll
  for (int i = 0; i < 24; i++) {
    int o = wv + i * 4;
    projT[(size_t)o * BL + tok0 + lane] = tile[lane][o];
  }
}

// ---------------- K3: full-sequence selective scan ----------------
// R5: register-diet main loop.  R4 evidence: VGPR=64 -> 16 waves/CU (40% occ),
// latency-bound (VALU work cut 20% with zero dur change).  Empirical rule:
// waves/CU ~= 1024/VGPR (R3: 32->81%, R2/R4: 60-64->40%).
// Changes: uv/Dl stay in LDS (scalar ds_read, 17-stride = 2 lanes/bank, free);
// uv = delta*xcp folded into the delta buffer pre-loop; phase 2 recomputes
// Pp[i]=exp(An*Dl[i-1]) (bitwise-identical input) and reloads Cv from L2 so
// only y[16] persists across the r-loop.  Target VGPR ~40 -> ~25 waves/CU.
__global__ __launch_bounds__(256) void k_scan(const float* __restrict__ projT,
                                              const u16* __restrict__ xgb,
                                              const float* __restrict__ cw,
                                              const float* __restrict__ cb,
                                              const float* __restrict__ dtw,
                                              const float* __restrict__ dtb,
                                              const float* __restrict__ alog,
                                              const float* __restrict__ dparam,
                                              const float* __restrict__ cs,
                                              u16* __restrict__ yb) {
  __shared__ float dtw_s[64];
  __shared__ float wtot[4];
  __shared__ float xcp[1088];    // conv+silu x, padded (tok>>4)*17 + (tok&15); persistent
  __shared__ float uvl[1088];    // delta -> uv = delta*xcp -> y-partial A
  __shared__ float dlp[1088];    // xls (staging) -> Dl prefix -> y-partial B

  int t = threadIdx.x;
  // XCD-aware swizzle: XCD x owns a contiguous 512-wide d range
  int cidx = ((blockIdx.x & 7) << 9) | (blockIdx.x >> 3);   // (b,d)
  int b = cidx >> 11;
  int d = cidx & (DDIM - 1);
  int wv = t >> 6, lane = t & 63;

  if (t < 64) dtw_s[t] = dtw[(size_t)d * 64 + t];
  float4 cwv = *(const float4*)(cw + d * 4);
  float cbv = cb[d];
  float dtbv = dtb[d];
  float Dp = dparam[d];
  const u16* xcol = xgb + (size_t)(b * XR + 3) * 4096 + d;      // x half
  const u16* gcol = xcol + DDIM;                                // gate half
  u16* ycol = yb + ((size_t)(b << 10)) * DDIM + d;
  int colbase = b << 10;

  // ---- stage x column (3-halo) into dlp (linear layout) ----
  float* xls = dlp;
  if (t < 3) xls[t] = 0.f;
#pragma unroll
  for (int k = 0; k < 4; k++) {
    int tok = t + (k << 8);
    xls[3 + tok] = bf2f(xcol[(size_t)tok * 4096]);
  }
  __syncthreads();                       // B1: staging + dtw_s visible

  int tok0 = t << 2;   // this thread owns tokens 4t..4t+3 for prep phases
  // ---- conv + silu -> xcp ----
#pragma unroll
  for (int i = 0; i < 4; i++) {
    int tok = tok0 + i;
    float xc = silu_f(cbv + cwv.x * xls[tok] + cwv.y * xls[tok + 1] +
                      cwv.z * xls[tok + 2] + cwv.w * xls[tok + 3]);
    xcp[((tok >> 4) * 17) + (tok & 15)] = xc;
  }
  // ---- delta = softplus(dt-dot) -> uvl ----
  float d0, d1, d2, d3;
  {
    float4 acc = {dtbv, dtbv, dtbv, dtbv};
    const float* pr = projT + colbase + tok0;
#pragma unroll 8
    for (int kk = 0; kk < 64; kk++) {
      float4 v = *(const float4*)(pr + (size_t)kk * BL);
      float wk = dtw_s[kk];
      acc.x += v.x * wk; acc.y += v.y * wk; acc.z += v.z * wk; acc.w += v.w * wk;
    }
    d0 = (acc.x > 20.f) ? acc.x : __logf(1.f + __expf(acc.x));
    d1 = (acc.y > 20.f) ? acc.y : __logf(1.f + __expf(acc.y));
    d2 = (acc.z > 20.f) ? acc.z : __logf(1.f + __expf(acc.z));
    d3 = (acc.w > 20.f) ? acc.w : __logf(1.f + __expf(acc.w));
    uvl[((tok0 >> 4) * 17) + (tok0 & 15)]             = d0;
    uvl[(((tok0 + 1) >> 4) * 17) + ((tok0 + 1) & 15)] = d1;
    uvl[(((tok0 + 2) >> 4) * 17) + ((tok0 + 2) & 15)] = d2;
    uvl[(((tok0 + 3) >> 4) * 17) + ((tok0 + 3) & 15)] = d3;
  }
  // ---- global inclusive prefix of delta (chunk-serial + one wave scan) ----
  float c0 = d0, c1 = c0 + d1, c2 = c1 + d2, c3 = c2 + d3;
  float sc = c3;
#pragma unroll
  for (int off = 1; off < 64; off <<= 1) {
    float u = __shfl_up(sc, off);
    if (lane >= off) sc += u;
  }
  if (lane == 63) wtot[wv] = sc;
  __syncthreads();                       // B2: conv xls-reads done; wtot visible
  {
    float base = sc - c3;
#pragma unroll
    for (int i = 0; i < 3; i++) if (i < wv) base += wtot[i];
    dlp[((tok0 >> 4) * 17) + (tok0 & 15)]             = base + c0;   // Dl prefix
    dlp[(((tok0 + 1) >> 4) * 17) + ((tok0 + 1) & 15)] = base + c1;
    dlp[(((tok0 + 2) >> 4) * 17) + ((tok0 + 2) & 15)] = base + c2;
    dlp[(((tok0 + 3) >> 4) * 17) + ((tok0 + 3) & 15)] = base + c3;
  }
  // ---- fold uv = delta * xcp (own positions, no cross-thread hazard) ----
#pragma unroll
  for (int i = 0; i < 4; i++) {
    int tok = tok0 + i;
    int p = ((tok >> 4) * 17) + (tok & 15);
    uvl[p] = uvl[p] * xcp[p];
  }
  __syncthreads();                       // B3: Dl + uv visible

  // ---- main scan: each wave owns 4 states over the FULL sequence;
  //      lane owns tokens 16*lane .. 16*lane+15; only y[16] persists ----
  int pb = lane * 17;
  float y[16];
#pragma unroll
  for (int i = 0; i < 16; i++) y[i] = 0.f;
  float Dprev = (lane == 0) ? 0.f : dlp[pb - 2];   // = Dl[(lane-1)*17 + 15]

#pragma unroll 1
  for (int r = 0; r < 4; r++) {
    int n = (wv << 2) + r;
    float An = -__expf(alog[d * NST + n]);
    float st = cs[(size_t)(b * DDIM + d) * NST + n];
    const float* pB = projT + (size_t)(64 + n) * BL + colbase + (lane << 4);
    const float* pC = pB + (size_t)16 * BL;
    float Pp = __expf(An * Dprev);
    float sl = 0.f;
#pragma unroll
    for (int c = 0; c < 4; c++) {
      float4 bv = *(const float4*)(pB + c * 4);
      float4 cv = *(const float4*)(pC + c * 4);
      float bvs[4] = {bv.x, bv.y, bv.z, bv.w};
      float cvs[4] = {cv.x, cv.y, cv.z, cv.w};
#pragma unroll
      for (int j = 0; j < 4; j++) {
        int i = c * 4 + j;
        float P = __expf(An * dlp[pb + i]);
        float w = uvl[pb + i] * bvs[j] * __builtin_amdgcn_rcpf(fmaxf(Pp, 1e-10f));
        sl += w;
        y[i] += (sl * Pp + st * P) * cvs[j];
        Pp = P;
      }
    }
    // one 64-lane scan of lane totals -> exclusive offset
    float s2 = sl;
#pragma unroll
    for (int off = 1; off < 64; off <<= 1) {
      float u = __shfl_up(s2, off);
      if (lane >= off) s2 += u;
    }
    float Soff = s2 - sl;
    // phase 2: y[i] += Soff * Pp[i] * Cv[i], Pp recomputed (bitwise-identical)
#pragma unroll
    for (int c = 0; c < 4; c++) {
      float4 cv = *(const float4*)(pC + c * 4);
      float cvs[4] = {cv.x, cv.y, cv.z, cv.w};
#pragma unroll
      for (int j = 0; j < 4; j++) {
        int i = c * 4 + j;
        float dlm = (i == 0) ? Dprev : dlp[pb + i - 1];
        y[i] += Soff * __expf(An * dlm) * cvs[j];
      }
    }
  }
  __syncthreads();                       // B4: all main-loop LDS reads done
  // ---- 2-phase cross-wave y reduction reusing uvl/dlp ----
  if (wv == 2) {
#pragma unroll
    for (int i = 0; i < 16; i++) uvl[pb + i] = y[i];
  } else if (wv == 3) {
#pragma unroll
    for (int i = 0; i < 16; i++) dlp[pb + i] = y[i];
  }
  __syncthreads();                       // B5: partials of waves 2,3 visible
  if (wv == 0) {
#pragma unroll
    for (int i = 0; i < 16; i++) uvl[pb + i] += y[i];
  } else if (wv == 1) {
#pragma unroll
    for (int i = 0; i < 16; i++) dlp[pb + i] += y[i];
  }
  __syncthreads();                       // B6: combined partials visible
  // ---- y = uvl+dlp + D-term, gate, write bf16 ----
#pragma unroll
  for (int i = 0; i < 4; i++) {
    int tok = tok0 + i;
    int p = ((tok >> 4) * 17) + (tok & 15);
    float yv = uvl[p] + dlp[p] + xcp[p] * Dp;
    float g = bf2f(gcol[(size_t)tok * 4096]);
    ycol[(size_t)tok * DDIM] = f2bf(yv * silu_f(g));
  }
}

extern "C" void kernel_launch(void* const* d_in, const int* in_sizes, int n_in,
                              void* d_out, int out_size, void* d_ws, size_t ws_size,
                              hipStream_t stream) {
  const float* inp    = (const float*)d_in[0];
  const float* cstate = (const float*)d_in[1];
  const float* norm_w = (const float*)d_in[2];
  const float* w1     = (const float*)d_in[3];
  const float* b1     = (const float*)d_in[4];
  const float* convw  = (const float*)d_in[5];
  const float* convb  = (const float*)d_in[6];
  const float* xpw    = (const float*)d_in[7];
  const float* xpb    = (const float*)d_in[8];
  const float* dtw    = (const float*)d_in[9];
  const float* dtb    = (const float*)d_in[10];
  const float* alog   = (const float*)d_in[11];
  const float* dparam = (const float*)d_in[12];
  const float* wo     = (const float*)d_in[13];
  const float* bo     = (const float*)d_in[14];
  float* out = (float*)d_out;

  // workspace layout, 39,378,944 B total
  char* wsb = (char*)d_ws;
  u16*   w1b    = (u16*)(wsb + 0);            //  8,388,608 B  [4096][1024] bf16
  u16*   wob    = (u16*)(wsb + 8388608);      //  4,194,304 B  [1024][2048] bf16
  float* rscale = (float*)(wsb + 12582912);   //      8,192 B  [2048]
  float* proj   = (float*)(wsb + 12591104);   //    786,432 B  [2048][96] token-major
  float* projT  = (float*)(wsb + 13377536);   //    786,432 B  [96][2048] transposed
  u16*   xgb    = (u16*)(wsb + 14163968);     // 16,826,368 B  [2][1027][4096] bf16
  u16*   yb     = (u16*)(wsb + 30990336);     //  8,388,608 B  [2][1024][2048] bf16

  k_castw<<<4096, 256, 0, stream>>>(w1, w1b);
  k_castw<<<2048, 256, 0, stream>>>(wo, wob);
  k_rowscale<<<BL, 256, 0, stream>>>(inp, rscale);
  k_gemm1_mfma<<<dim3(64, 32), 256, 0, stream>>>(inp, w1b, b1, rscale, norm_w, xgb);
  k_xprojc<<<BL, 256, 0, stream>>>(xgb, convw, convb, xpw, xpb, proj);
  k_transpose<<<32, 256, 0, stream>>>(proj, projT);
  k_scan<<<2 * DDIM, 256, 0, stream>>>(projT, xgb, convw, convb, dtw, dtb,
                                       alog, dparam, cstate, yb);
  k_gemm2_mfma<<<dim3(16, 32), 256, 0, stream>>>(yb, wob, bo, inp, out);
}

// Round 6
// 352.063 us; speedup vs baseline: 1.6864x; 1.0383x over previous
//
#include <hip/hip_runtime.h>
#include <stdint.h>

#define LSEQ 1024
#define HDIM 1024
#define DDIM 2048
#define BL 2048
#define NST 16
#define XR 1027          // 3 halo rows (unused, zero-pad region) + 1024 tokens

typedef unsigned short u16;
typedef __attribute__((ext_vector_type(8))) short bf16x8;
typedef __attribute__((ext_vector_type(4))) float f32x4;

// silu via v_rcp (1-ulp rcp; output tolerance is bf16-dominated)
static __device__ __forceinline__ float silu_f(float v) {
  return v * __builtin_amdgcn_rcpf(1.f + __expf(-v));
}
static __device__ __forceinline__ float bf2f(u16 u) {
  union { float f; unsigned int i; } c; c.i = ((unsigned int)u) << 16; return c.f;
}
static __device__ __forceinline__ u16 f2bf(float f) {
  union { float f; unsigned int i; } c; c.f = f;
  unsigned int r = c.i + 0x7fffu + ((c.i >> 16) & 1u);
  return (u16)(r >> 16);
}
static __device__ __forceinline__ float softplus_f(float v) {
  return (v > 20.f) ? v : __logf(1.f + __expf(v));
}

// ---------------- cast fp32 -> bf16 (weights, once per launch) ----------------
__global__ __launch_bounds__(256) void k_castw(const float* __restrict__ src,
                                               u16* __restrict__ dst) {
  int idx = blockIdx.x * 256 + threadIdx.x;
  float4 v = ((const float4*)src)[idx];
  ushort4 o;
  o.x = f2bf(v.x); o.y = f2bf(v.y); o.z = f2bf(v.z); o.w = f2bf(v.w);
  ((ushort4*)dst)[idx] = o;
}

// ---------------- per-row rmsnorm scale ----------------
__global__ __launch_bounds__(256) void k_rowscale(const float* __restrict__ inp,
                                                  float* __restrict__ rs) {
  int row = blockIdx.x;
  int t = threadIdx.x;
  float4 xv = *(const float4*)(inp + (size_t)row * HDIM + t * 4);
  float ss = xv.x * xv.x + xv.y * xv.y + xv.z * xv.z + xv.w * xv.w;
  for (int off = 32; off > 0; off >>= 1) ss += __shfl_down(ss, off);
  __shared__ float red[4];
  if ((t & 63) == 0) red[t >> 6] = ss;
  __syncthreads();
  if (t == 0) {
    float tot = red[0] + red[1] + red[2] + red[3];
    rs[row] = rsqrtf(tot * (1.f / HDIM) + 1e-6f);
  }
}

// ---------------- K1: in_proj MFMA GEMM, rmsnorm fused into A staging ----------------
// Full M=2048, N=4096, K=1024. 64x64 tile. Output bf16 xgb [2][XR][4096].
__global__ __launch_bounds__(256) void k_gemm1_mfma(const float* __restrict__ inp,
                                                    const u16* __restrict__ W,
                                                    const float* __restrict__ bias,
                                                    const float* __restrict__ rscale,
                                                    const float* __restrict__ nw,
                                                    u16* __restrict__ xgb) {
  __shared__ u16 Asm[64 * 40];
  __shared__ u16 Wsm[64 * 40];
  int t = threadIdx.x;
  int m0 = blockIdx.y * 64, n0 = blockIdx.x * 64;
  int srow = t >> 2, koff = (t & 3) * 8;
  int gin = m0 + srow;
  const float* Ag = inp + (size_t)gin * HDIM + koff;
  const u16* Wg = W + (size_t)(n0 + srow) * HDIM + koff;
  float scale = rscale[gin];
  int w = t >> 6, lane = t & 63;
  int quad = lane >> 4, mr = lane & 15;
  f32x4 z = {0.f, 0.f, 0.f, 0.f};
  f32x4 acc0 = z, acc1 = z, acc2 = z, acc3 = z;
  const u16* arp = &Asm[(16 * w + mr) * 40 + quad * 8];
  const u16* brp = &Wsm[mr * 40 + quad * 8];
  for (int k0 = 0; k0 < HDIM; k0 += 32) {
    float4 a0 = *(const float4*)(Ag + k0);
    float4 a1 = *(const float4*)(Ag + k0 + 4);
    float4 n0v = *(const float4*)(nw + k0 + koff);
    float4 n1v = *(const float4*)(nw + k0 + koff + 4);
    uint4 wv = *(const uint4*)(Wg + k0);
    ushort4 p0, p1;
    p0.x = f2bf(a0.x * scale * n0v.x); p0.y = f2bf(a0.y * scale * n0v.y);
    p0.z = f2bf(a0.z * scale * n0v.z); p0.w = f2bf(a0.w * scale * n0v.w);
    p1.x = f2bf(a1.x * scale * n1v.x); p1.y = f2bf(a1.y * scale * n1v.y);
    p1.z = f2bf(a1.z * scale * n1v.z); p1.w = f2bf(a1.w * scale * n1v.w);
    __syncthreads();
    *(ushort4*)(&Asm[srow * 40 + koff]) = p0;
    *(ushort4*)(&Asm[srow * 40 + koff + 4]) = p1;
    *(uint4*)(&Wsm[srow * 40 + koff]) = wv;
    __syncthreads();
    bf16x8 af = *(const bf16x8*)arp;
    bf16x8 b0 = *(const bf16x8*)(brp);
    bf16x8 b1 = *(const bf16x8*)(brp + 16 * 40);
    bf16x8 b2 = *(const bf16x8*)(brp + 32 * 40);
    bf16x8 b3 = *(const bf16x8*)(brp + 48 * 40);
    acc0 = __builtin_amdgcn_mfma_f32_16x16x32_bf16(af, b0, acc0, 0, 0, 0);
    acc1 = __builtin_amdgcn_mfma_f32_16x16x32_bf16(af, b1, acc1, 0, 0, 0);
    acc2 = __builtin_amdgcn_mfma_f32_16x16x32_bf16(af, b2, acc2, 0, 0, 0);
    acc3 = __builtin_amdgcn_mfma_f32_16x16x32_bf16(af, b3, acc3, 0, 0, 0);
  }
  f32x4 accs[4] = {acc0, acc1, acc2, acc3};
#pragma unroll
  for (int i = 0; i < 4; i++) {
    int col = n0 + 16 * i + mr;
    float bv = bias[col];
#pragma unroll
    for (int rr2 = 0; rr2 < 4; rr2++) {
      int rr = m0 + 16 * w + quad * 4 + rr2;
      int row = (rr >> 10) * XR + 3 + (rr & 1023);
      xgb[(size_t)row * 4096 + col] = f2bf(accs[i][rr2] + bv);
    }
  }
}

// ---------------- K4: out_proj MFMA GEMM + bias + residual (fp32 out) ----------------
__global__ __launch_bounds__(256) void k_gemm2_mfma(const u16* __restrict__ A,   // yb [2048][2048] bf16
                                                    const u16* __restrict__ W,   // wob [1024][2048] bf16
                                                    const float* __restrict__ bias,
                                                    const float* __restrict__ resid,
                                                    float* __restrict__ out) {
  __shared__ u16 Asm[64 * 40];
  __shared__ u16 Wsm[64 * 40];
  int t = threadIdx.x;
  int m0 = blockIdx.y * 64, n0 = blockIdx.x * 64;
  int srow = t >> 2, koff = (t & 3) * 8;
  const u16* Ag = A + (size_t)(m0 + srow) * DDIM + koff;
  const u16* Wg = W + (size_t)(n0 + srow) * DDIM + koff;
  int w = t >> 6, lane = t & 63;
  int quad = lane >> 4, mr = lane & 15;
  f32x4 z = {0.f, 0.f, 0.f, 0.f};
  f32x4 acc0 = z, acc1 = z, acc2 = z, acc3 = z;
  const u16* arp = &Asm[(16 * w + mr) * 40 + quad * 8];
  const u16* brp = &Wsm[mr * 40 + quad * 8];
  for (int k0 = 0; k0 < DDIM; k0 += 32) {
    uint4 av = *(const uint4*)(Ag + k0);
    uint4 wv = *(const uint4*)(Wg + k0);
    __syncthreads();
    *(uint4*)(&Asm[srow * 40 + koff]) = av;
    *(uint4*)(&Wsm[srow * 40 + koff]) = wv;
    __syncthreads();
    bf16x8 af = *(const bf16x8*)arp;
    bf16x8 b0 = *(const bf16x8*)(brp);
    bf16x8 b1 = *(const bf16x8*)(brp + 16 * 40);
    bf16x8 b2 = *(const bf16x8*)(brp + 32 * 40);
    bf16x8 b3 = *(const bf16x8*)(brp + 48 * 40);
    acc0 = __builtin_amdgcn_mfma_f32_16x16x32_bf16(af, b0, acc0, 0, 0, 0);
    acc1 = __builtin_amdgcn_mfma_f32_16x16x32_bf16(af, b1, acc1, 0, 0, 0);
    acc2 = __builtin_amdgcn_mfma_f32_16x16x32_bf16(af, b2, acc2, 0, 0, 0);
    acc3 = __builtin_amdgcn_mfma_f32_16x16x32_bf16(af, b3, acc3, 0, 0, 0);
  }
  f32x4 accs[4] = {acc0, acc1, acc2, acc3};
#pragma unroll
  for (int i = 0; i < 4; i++) {
    int col = n0 + 16 * i + mr;
    float bv = bias[col];
#pragma unroll
    for (int rr2 = 0; rr2 < 4; rr2++) {
      int gout = m0 + 16 * w + quad * 4 + rr2;
      out[(size_t)gout * HDIM + col] =
          accs[i][rr2] + bv + resid[(size_t)gout * HDIM + col];
    }
  }
}

// ---------------- K2: conv+silu (LDS) then x_proj; token-major proj[BL][96] ----------------
__global__ __launch_bounds__(256) void k_xprojc(const u16* __restrict__ xgb,
                                                const float* __restrict__ cw,
                                                const float* __restrict__ cb,
                                                const float* __restrict__ w,
                                                const float* __restrict__ b,
                                                float* __restrict__ proj) {
  __shared__ float row[DDIM];
  int bb = blockIdx.x >> 10, l = blockIdx.x & 1023;
  int t = threadIdx.x;
  int d = t * 8;
  float acc[8];
#pragma unroll
  for (int i = 0; i < 8; i++) acc[i] = cb[d + i];
  float cwv[8][4];
#pragma unroll
  for (int i = 0; i < 8; i++) {
    float4 v = *(const float4*)(cw + (d + i) * 4);
    cwv[i][0] = v.x; cwv[i][1] = v.y; cwv[i][2] = v.z; cwv[i][3] = v.w;
  }
#pragma unroll
  for (int j = 0; j < 4; j++) {
    if (l - 3 + j >= 0) {
      const u16* xr = xgb + (size_t)(bb * XR + l + j) * 4096 + d;
      ushort4 v0 = *(const ushort4*)xr;
      ushort4 v1 = *(const ushort4*)(xr + 4);
      acc[0] += bf2f(v0.x) * cwv[0][j]; acc[1] += bf2f(v0.y) * cwv[1][j];
      acc[2] += bf2f(v0.z) * cwv[2][j]; acc[3] += bf2f(v0.w) * cwv[3][j];
      acc[4] += bf2f(v1.x) * cwv[4][j]; acc[5] += bf2f(v1.y) * cwv[5][j];
      acc[6] += bf2f(v1.z) * cwv[6][j]; acc[7] += bf2f(v1.w) * cwv[7][j];
    }
  }
#pragma unroll
  for (int i = 0; i < 8; i++) row[d + i] = silu_f(acc[i]);
  __syncthreads();
  int wv = t >> 6, lane = t & 63;
  const float4* row4 = (const float4*)row;
  int tk = (bb << 10) + l;
  for (int o = wv; o < 96; o += 4) {
    const float4* wr4 = (const float4*)(w + (size_t)o * DDIM);
    float s0 = 0.f, s1 = 0.f, s2 = 0.f, s3 = 0.f;
#pragma unroll
    for (int k4 = 0; k4 < 8; k4++) {
      int idx = (k4 << 6) + lane;
      float4 wv4 = wr4[idx];
      float4 rv4 = row4[idx];
      s0 += rv4.x * wv4.x; s1 += rv4.y * wv4.y;
      s2 += rv4.z * wv4.z; s3 += rv4.w * wv4.w;
    }
    float s = (s0 + s1) + (s2 + s3);
    s += __shfl_xor(s, 32); s += __shfl_xor(s, 16);
    s += __shfl_xor(s, 8);  s += __shfl_xor(s, 4);
    s += __shfl_xor(s, 2);  s += __shfl_xor(s, 1);
    if (lane == 0) proj[(size_t)tk * 96 + o] = s + b[o];
  }
}

// ---------------- K2b: transpose proj[BL][96] -> projT[96][BL] ----------------
__global__ __launch_bounds__(256) void k_transpose(const float* __restrict__ proj,
                                                   float* __restrict__ projT) {
  __shared__ float tile[64][97];
  int blk = blockIdx.x;                 // 32 blocks: b = blk>>4, 64-token segment = blk&15
  int b = blk >> 4;
  int tok0 = (b << 10) + (blk & 15) * 64;
  int t = threadIdx.x;
  const float* src = proj + (size_t)tok0 * 96;
#pragma unroll
  for (int i = 0; i < 24; i++) {
    int idx = t + i * 256;
    int row = idx / 96, col = idx - row * 96;
    tile[row][col] = src[idx];
  }
  __syncthreads();
  int wv = t >> 6, lane = t & 63;
#pragma unroll
  for (int i = 0; i < 24; i++) {
    int o = wv + i * 4;
    projT[(size_t)o * BL + tok0 + lane] = tile[lane][o];
  }
}

// ---------------- K2c: delta GEMM: deltaT[2048 d][2048 tok] = softplus(dtw.projT + dtb) ----
// Hoists the dt-dot out of k_scan: was 256KB/block x 4096 blocks = 1GB of
// redundant L2 reads (every d-block re-read the same 64x1024 projT slice).
// Now 64MB read + 16MB write here, and k_scan reads 4KB/block coalesced.
// Same accumulation order as the old in-scan dot (r ascending, acc init dtb)
// -> bitwise-identical delta.
__global__ __launch_bounds__(256) void k_delta(const float* __restrict__ projT,
                                               const float* __restrict__ dtw,
                                               const float* __restrict__ dtb,
                                               float* __restrict__ deltaT) {
  __shared__ float dw_s[16][64];
  int t = threadIdx.x;
  int d0 = (blockIdx.x >> 3) * 16;        // 128 d-tiles of 16
  int tokbase = (blockIdx.x & 7) * 256;   // 8 token-tiles of 256
  {
    const float* src = dtw + (size_t)d0 * 64;
#pragma unroll
    for (int i = 0; i < 4; i++) {
      int idx = t + i * 256;
      dw_s[idx >> 6][idx & 63] = src[idx];
    }
  }
  __syncthreads();
  int tq = t & 63, dq = t >> 6;           // thread: 4 tokens x 4 d
  const float* pr = projT + tokbase + tq * 4;
  int dbase = d0 + dq * 4;
  float acc[4][4];
#pragma unroll
  for (int di = 0; di < 4; di++) {
    float bv = dtb[dbase + di];
    acc[di][0] = bv; acc[di][1] = bv; acc[di][2] = bv; acc[di][3] = bv;
  }
#pragma unroll 8
  for (int r = 0; r < 64; r++) {
    float4 pv = *(const float4*)(pr + (size_t)r * BL);
#pragma unroll
    for (int di = 0; di < 4; di++) {
      float wk = dw_s[dq * 4 + di][r];
      acc[di][0] += pv.x * wk; acc[di][1] += pv.y * wk;
      acc[di][2] += pv.z * wk; acc[di][3] += pv.w * wk;
    }
  }
#pragma unroll
  for (int di = 0; di < 4; di++) {
    float4 o;
    o.x = softplus_f(acc[di][0]); o.y = softplus_f(acc[di][1]);
    o.z = softplus_f(acc[di][2]); o.w = softplus_f(acc[di][3]);
    *(float4*)(deltaT + (size_t)(dbase + di) * BL + tokbase + tq * 4) = o;
  }
}

// ---------------- K3 v2: selective scan, delta precomputed by k_delta ----------------
__global__ __launch_bounds__(256) void k_scan2(const float* __restrict__ projT,
                                               const float* __restrict__ deltaT,
                                               const u16* __restrict__ xgb,
                                               const float* __restrict__ cw,
                                               const float* __restrict__ cb,
                                               const float* __restrict__ alog,
                                               const float* __restrict__ dparam,
                                               const float* __restrict__ cs,
                                               u16* __restrict__ yb) {
  __shared__ float wtot[4];
  __shared__ float xcp[1088];    // conv+silu x, padded (tok>>4)*17 + (tok&15)
  __shared__ float uvl[1088];    // delta -> uv = delta*xcp -> y-partial A
  __shared__ float dlp[1088];    // xls (staging) -> Dl prefix -> y-partial B

  int t = threadIdx.x;
  int cidx = ((blockIdx.x & 7) << 9) | (blockIdx.x >> 3);   // (b,d)
  int b = cidx >> 11;
  int d = cidx & (DDIM - 1);
  int wv = t >> 6, lane = t & 63;

  float4 cwv = *(const float4*)(cw + d * 4);
  float cbv = cb[d];
  float Dp = dparam[d];
  const u16* xcol = xgb + (size_t)(b * XR + 3) * 4096 + d;
  const u16* gcol = xcol + DDIM;
  u16* ycol = yb + ((size_t)(b << 10)) * DDIM + d;
  int colbase = b << 10;
  int tok0 = t << 2;

  // delta row: coalesced float4 (softplus pre-applied)
  float4 dv = *(const float4*)(deltaT + (size_t)d * BL + colbase + tok0);

  // ---- stage x column (3-halo) into dlp (linear layout) ----
  float* xls = dlp;
  if (t < 3) xls[t] = 0.f;
#pragma unroll
  for (int k = 0; k < 4; k++) {
    int tok = t + (k << 8);
    xls[3 + tok] = bf2f(xcol[(size_t)tok * 4096]);
  }
  __syncthreads();                       // B1: staging visible

  // ---- conv + silu -> xcp ----
#pragma unroll
  for (int i = 0; i < 4; i++) {
    int tok = tok0 + i;
    float xc = silu_f(cbv + cwv.x * xls[tok] + cwv.y * xls[tok + 1] +
                      cwv.z * xls[tok + 2] + cwv.w * xls[tok + 3]);
    xcp[((tok >> 4) * 17) + (tok & 15)] = xc;
  }
  float d0 = dv.x, d1 = dv.y, d2 = dv.z, d3 = dv.w;
  uvl[((tok0 >> 4) * 17) + (tok0 & 15)]             = d0;
  uvl[(((tok0 + 1) >> 4) * 17) + ((tok0 + 1) & 15)] = d1;
  uvl[(((tok0 + 2) >> 4) * 17) + ((tok0 + 2) & 15)] = d2;
  uvl[(((tok0 + 3) >> 4) * 17) + ((tok0 + 3) & 15)] = d3;
  // ---- global inclusive prefix of delta ----
  float c0 = d0, c1 = c0 + d1, c2 = c1 + d2, c3 = c2 + d3;
  float sc = c3;
#pragma unroll
  for (int off = 1; off < 64; off <<= 1) {
    float u = __shfl_up(sc, off);
    if (lane >= off) sc += u;
  }
  if (lane == 63) wtot[wv] = sc;
  __syncthreads();                       // B2: conv xls-reads done; wtot visible
  {
    float base = sc - c3;
#pragma unroll
    for (int i = 0; i < 3; i++) if (i < wv) base += wtot[i];
    dlp[((tok0 >> 4) * 17) + (tok0 & 15)]             = base + c0;
    dlp[(((tok0 + 1) >> 4) * 17) + ((tok0 + 1) & 15)] = base + c1;
    dlp[(((tok0 + 2) >> 4) * 17) + ((tok0 + 2) & 15)] = base + c2;
    dlp[(((tok0 + 3) >> 4) * 17) + ((tok0 + 3) & 15)] = base + c3;
  }
#pragma unroll
  for (int i = 0; i < 4; i++) {
    int tok = tok0 + i;
    int p = ((tok >> 4) * 17) + (tok & 15);
    uvl[p] = uvl[p] * xcp[p];            // uv = delta * conv_x
  }
  __syncthreads();                       // B3: Dl + uv visible

  int pb = lane * 17;
  float y[16];
#pragma unroll
  for (int i = 0; i < 16; i++) y[i] = 0.f;
  float Dprev = (lane == 0) ? 0.f : dlp[pb - 2];

#pragma unroll 1
  for (int r = 0; r < 4; r++) {
    int n = (wv << 2) + r;
    float An = -__expf(alog[d * NST + n]);
    float st = cs[(size_t)(b * DDIM + d) * NST + n];
    const float* pB = projT + (size_t)(64 + n) * BL + colbase + (lane << 4);
    const float* pC = pB + (size_t)16 * BL;
    float Pp = __expf(An * Dprev);
    float sl = 0.f;
#pragma unroll
    for (int c = 0; c < 4; c++) {
      float4 bv = *(const float4*)(pB + c * 4);
      float4 cv = *(const float4*)(pC + c * 4);
      float bvs[4] = {bv.x, bv.y, bv.z, bv.w};
      float cvs[4] = {cv.x, cv.y, cv.z, cv.w};
#pragma unroll
      for (int j = 0; j < 4; j++) {
        int i = c * 4 + j;
        float P = __expf(An * dlp[pb + i]);
        float w = uvl[pb + i] * bvs[j] * __builtin_amdgcn_rcpf(fmaxf(Pp, 1e-10f));
        sl += w;
        y[i] += (sl * Pp + st * P) * cvs[j];
        Pp = P;
      }
    }
    float s2 = sl;
#pragma unroll
    for (int off = 1; off < 64; off <<= 1) {
      float u = __shfl_up(s2, off);
      if (lane >= off) s2 += u;
    }
    float Soff = s2 - sl;
#pragma unroll
    for (int c = 0; c < 4; c++) {
      float4 cv = *(const float4*)(pC + c * 4);
      float cvs[4] = {cv.x, cv.y, cv.z, cv.w};
#pragma unroll
      for (int j = 0; j < 4; j++) {
        int i = c * 4 + j;
        float dlm = (i == 0) ? Dprev : dlp[pb + i - 1];
        y[i] += Soff * __expf(An * dlm) * cvs[j];
      }
    }
  }
  __syncthreads();                       // B4
  if (wv == 2) {
#pragma unroll
    for (int i = 0; i < 16; i++) uvl[pb + i] = y[i];
  } else if (wv == 3) {
#pragma unroll
    for (int i = 0; i < 16; i++) dlp[pb + i] = y[i];
  }
  __syncthreads();                       // B5
  if (wv == 0) {
#pragma unroll
    for (int i = 0; i < 16; i++) uvl[pb + i] += y[i];
  } else if (wv == 1) {
#pragma unroll
    for (int i = 0; i < 16; i++) dlp[pb + i] += y[i];
  }
  __syncthreads();                       // B6
#pragma unroll
  for (int i = 0; i < 4; i++) {
    int tok = tok0 + i;
    int p = ((tok >> 4) * 17) + (tok & 15);
    float yv = uvl[p] + dlp[p] + xcp[p] * Dp;
    float g = bf2f(gcol[(size_t)tok * 4096]);
    ycol[(size_t)tok * DDIM] = f2bf(yv * silu_f(g));
  }
}

// ---------------- K3 fallback (R5): in-scan dt-dot, used when ws too small ----------------
__global__ __launch_bounds__(256) void k_scan(const float* __restrict__ projT,
                                              const u16* __restrict__ xgb,
                                              const float* __restrict__ cw,
                                              const float* __restrict__ cb,
                                              const float* __restrict__ dtw,
                                              const float* __restrict__ dtb,
                                              const float* __restrict__ alog,
                                              const float* __restrict__ dparam,
                                              const float* __restrict__ cs,
                                              u16* __restrict__ yb) {
  __shared__ float dtw_s[64];
  __shared__ float wtot[4];
  __shared__ float xcp[1088];
  __shared__ float uvl[1088];
  __shared__ float dlp[1088];

  int t = threadIdx.x;
  int cidx = ((blockIdx.x & 7) << 9) | (blockIdx.x >> 3);
  int b = cidx >> 11;
  int d = cidx & (DDIM - 1);
  int wv = t >> 6, lane = t & 63;

  if (t < 64) dtw_s[t] = dtw[(size_t)d * 64 + t];
  float4 cwv = *(const float4*)(cw + d * 4);
  float cbv = cb[d];
  float dtbv = dtb[d];
  float Dp = dparam[d];
  const u16* xcol = xgb + (size_t)(b * XR + 3) * 4096 + d;
  const u16* gcol = xcol + DDIM;
  u16* ycol = yb + ((size_t)(b << 10)) * DDIM + d;
  int colbase = b << 10;

  float* xls = dlp;
  if (t < 3) xls[t] = 0.f;
#pragma unroll
  for (int k = 0; k < 4; k++) {
    int tok = t + (k << 8);
    xls[3 + tok] = bf2f(xcol[(size_t)tok * 4096]);
  }
  __syncthreads();

  int tok0 = t << 2;
#pragma unroll
  for (int i = 0; i < 4; i++) {
    int tok = tok0 + i;
    float xc = silu_f(cbv + cwv.x * xls[tok] + cwv.y * xls[tok + 1] +
                      cwv.z * xls[tok + 2] + cwv.w * xls[tok + 3]);
    xcp[((tok >> 4) * 17) + (tok & 15)] = xc;
  }
  float d0, d1, d2, d3;
  {
    float4 acc = {dtbv, dtbv, dtbv, dtbv};
    const float* pr = projT + colbase + tok0;
#pragma unroll 8
    for (int kk = 0; kk < 64; kk++) {
      float4 v = *(const float4*)(pr + (size_t)kk * BL);
      float wk = dtw_s[kk];
      acc.x += v.x * wk; acc.y += v.y * wk; acc.z += v.z * wk; acc.w += v.w * wk;
    }
    d0 = softplus_f(acc.x); d1 = softplus_f(acc.y);
    d2 = softplus_f(acc.z); d3 = softplus_f(acc.w);
    uvl[((tok0 >> 4) * 17) + (tok0 & 15)]             = d0;
    uvl[(((tok0 + 1) >> 4) * 17) + ((tok0 + 1) & 15)] = d1;
    uvl[(((tok0 + 2) >> 4) * 17) + ((tok0 + 2) & 15)] = d2;
    uvl[(((tok0 + 3) >> 4) * 17) + ((tok0 + 3) & 15)] = d3;
  }
  float c0 = d0, c1 = c0 + d1, c2 = c1 + d2, c3 = c2 + d3;
  float sc = c3;
#pragma unroll
  for (int off = 1; off < 64; off <<= 1) {
    float u = __shfl_up(sc, off);
    if (lane >= off) sc += u;
  }
  if (lane == 63) wtot[wv] = sc;
  __syncthreads();
  {
    float base = sc - c3;
#pragma unroll
    for (int i = 0; i < 3; i++) if (i < wv) base += wtot[i];
    dlp[((tok0 >> 4) * 17) + (tok0 & 15)]             = base + c0;
    dlp[(((tok0 + 1) >> 4) * 17) + ((tok0 + 1) & 15)] = base + c1;
    dlp[(((tok0 + 2) >> 4) * 17) + ((tok0 + 2) & 15)] = base + c2;
    dlp[(((tok0 + 3) >> 4) * 17) + ((tok0 + 3) & 15)] = base + c3;
  }
#pragma unroll
  for (int i = 0; i < 4; i++) {
    int tok = tok0 + i;
    int p = ((tok >> 4) * 17) + (tok & 15);
    uvl[p] = uvl[p] * xcp[p];
  }
  __syncthreads();

  int pb = lane * 17;
  float y[16];
#pragma unroll
  for (int i = 0; i < 16; i++) y[i] = 0.f;
  float Dprev = (lane == 0) ? 0.f : dlp[pb - 2];

#pragma unroll 1
  for (int r = 0; r < 4; r++) {
    int n = (wv << 2) + r;
    float An = -__expf(alog[d * NST + n]);
    float st = cs[(size_t)(b * DDIM + d) * NST + n];
    const float* pB = projT + (size_t)(64 + n) * BL + colbase + (lane << 4);
    const float* pC = pB + (size_t)16 * BL;
    float Pp = __expf(An * Dprev);
    float sl = 0.f;
#pragma unroll
    for (int c = 0; c < 4; c++) {
      float4 bv = *(const float4*)(pB + c * 4);
      float4 cv = *(const float4*)(pC + c * 4);
      float bvs[4] = {bv.x, bv.y, bv.z, bv.w};
      float cvs[4] = {cv.x, cv.y, cv.z, cv.w};
#pragma unroll
      for (int j = 0; j < 4; j++) {
        int i = c * 4 + j;
        float P = __expf(An * dlp[pb + i]);
        float w = uvl[pb + i] * bvs[j] * __builtin_amdgcn_rcpf(fmaxf(Pp, 1e-10f));
        sl += w;
        y[i] += (sl * Pp + st * P) * cvs[j];
        Pp = P;
      }
    }
    float s2 = sl;
#pragma unroll
    for (int off = 1; off < 64; off <<= 1) {
      float u = __shfl_up(s2, off);
      if (lane >= off) s2 += u;
    }
    float Soff = s2 - sl;
#pragma unroll
    for (int c = 0; c < 4; c++) {
      float4 cv = *(const float4*)(pC + c * 4);
      float cvs[4] = {cv.x, cv.y, cv.z, cv.w};
#pragma unroll
      for (int j = 0; j < 4; j++) {
        int i = c * 4 + j;
        float dlm = (i == 0) ? Dprev : dlp[pb + i - 1];
        y[i] += Soff * __expf(An * dlm) * cvs[j];
      }
    }
  }
  __syncthreads();
  if (wv == 2) {
#pragma unroll
    for (int i = 0; i < 16; i++) uvl[pb + i] = y[i];
  } else if (wv == 3) {
#pragma unroll
    for (int i = 0; i < 16; i++) dlp[pb + i] = y[i];
  }
  __syncthreads();
  if (wv == 0) {
#pragma unroll
    for (int i = 0; i < 16; i++) uvl[pb + i] += y[i];
  } else if (wv == 1) {
#pragma unroll
    for (int i = 0; i < 16; i++) dlp[pb + i] += y[i];
  }
  __syncthreads();
#pragma unroll
  for (int i = 0; i < 4; i++) {
    int tok = tok0 + i;
    int p = ((tok >> 4) * 17) + (tok & 15);
    float yv = uvl[p] + dlp[p] + xcp[p] * Dp;
    float g = bf2f(gcol[(size_t)tok * 4096]);
    ycol[(size_t)tok * DDIM] = f2bf(yv * silu_f(g));
  }
}

extern "C" void kernel_launch(void* const* d_in, const int* in_sizes, int n_in,
                              void* d_out, int out_size, void* d_ws, size_t ws_size,
                              hipStream_t stream) {
  const float* inp    = (const float*)d_in[0];
  const float* cstate = (const float*)d_in[1];
  const float* norm_w = (const float*)d_in[2];
  const float* w1     = (const float*)d_in[3];
  const float* b1     = (const float*)d_in[4];
  const float* convw  = (const float*)d_in[5];
  const float* convb  = (const float*)d_in[6];
  const float* xpw    = (const float*)d_in[7];
  const float* xpb    = (const float*)d_in[8];
  const float* dtw    = (const float*)d_in[9];
  const float* dtb    = (const float*)d_in[10];
  const float* alog   = (const float*)d_in[11];
  const float* dparam = (const float*)d_in[12];
  const float* wo     = (const float*)d_in[13];
  const float* bo     = (const float*)d_in[14];
  float* out = (float*)d_out;

  // base workspace layout, 39,378,944 B; deltaT (16 MB) appended if ws permits
  char* wsb = (char*)d_ws;
  u16*   w1b    = (u16*)(wsb + 0);            //  8,388,608 B  [4096][1024] bf16
  u16*   wob    = (u16*)(wsb + 8388608);      //  4,194,304 B  [1024][2048] bf16
  float* rscale = (float*)(wsb + 12582912);   //      8,192 B  [2048]
  float* proj   = (float*)(wsb + 12591104);   //    786,432 B  [2048][96] token-major
  float* projT  = (float*)(wsb + 13377536);   //    786,432 B  [96][2048] transposed
  u16*   xgb    = (u16*)(wsb + 14163968);     // 16,826,368 B  [2][1027][4096] bf16
  u16*   yb     = (u16*)(wsb + 30990336);     //  8,388,608 B  [2][1024][2048] bf16
  float* deltaT = (float*)(wsb + 39378944);   // 16,777,216 B  [2048 d][2048 tok] f32

  const size_t WS_NEED_DELTA = 39378944u + 16777216u;

  k_castw<<<4096, 256, 0, stream>>>(w1, w1b);
  k_castw<<<2048, 256, 0, stream>>>(wo, wob);
  k_rowscale<<<BL, 256, 0, stream>>>(inp, rscale);
  k_gemm1_mfma<<<dim3(64, 32), 256, 0, stream>>>(inp, w1b, b1, rscale, norm_w, xgb);
  k_xprojc<<<BL, 256, 0, stream>>>(xgb, convw, convb, xpw, xpb, proj);
  k_transpose<<<32, 256, 0, stream>>>(proj, projT);
  if (ws_size >= WS_NEED_DELTA) {
    k_delta<<<1024, 256, 0, stream>>>(projT, dtw, dtb, deltaT);
    k_scan2<<<2 * DDIM, 256, 0, stream>>>(projT, deltaT, xgb, convw, convb,
                                          alog, dparam, cstate, yb);
  } else {
    k_scan<<<2 * DDIM, 256, 0, stream>>>(projT, xgb, convw, convb, dtw, dtb,
                                         alog, dparam, cstate, yb);
  }
  k_gemm2_mfma<<<dim3(16, 32), 256, 0, stream>>>(yb, wob, bo, inp, out);
}

// Round 8
// 341.199 us; speedup vs baseline: 1.7401x; 1.0318x over previous
//
#include <hip/hip_runtime.h>
#include <stdint.h>

#define LSEQ 1024
#define HDIM 1024
#define DDIM 2048
#define BL 2048
#define NST 16
#define XR 1027          // 3 halo rows (unused, zero-pad region) + 1024 tokens

typedef unsigned short u16;
typedef __attribute__((ext_vector_type(8))) short bf16x8;
typedef __attribute__((ext_vector_type(4))) float f32x4;

// silu via v_rcp (1-ulp rcp; output tolerance is bf16-dominated)
static __device__ __forceinline__ float silu_f(float v) {
  return v * __builtin_amdgcn_rcpf(1.f + __expf(-v));
}
static __device__ __forceinline__ float bf2f(u16 u) {
  union { float f; unsigned int i; } c; c.i = ((unsigned int)u) << 16; return c.f;
}
static __device__ __forceinline__ u16 f2bf(float f) {
  union { float f; unsigned int i; } c; c.f = f;
  unsigned int r = c.i + 0x7fffu + ((c.i >> 16) & 1u);
  return (u16)(r >> 16);
}
static __device__ __forceinline__ float softplus_f(float v) {
  return (v > 20.f) ? v : __logf(1.f + __expf(v));
}

// ---------------- cast fp32 -> bf16 (weights, once per launch) ----------------
__global__ __launch_bounds__(256) void k_castw(const float* __restrict__ src,
                                               u16* __restrict__ dst) {
  int idx = blockIdx.x * 256 + threadIdx.x;
  float4 v = ((const float4*)src)[idx];
  ushort4 o;
  o.x = f2bf(v.x); o.y = f2bf(v.y); o.z = f2bf(v.z); o.w = f2bf(v.w);
  ((ushort4*)dst)[idx] = o;
}

// ---------------- per-row rmsnorm + normalize -> xnb bf16 [2048][1024] ----------------
// Same expression as the old in-gemm normalize: f2bf(x * scale * nw) -> bitwise-
// identical A operand; gemm1 becomes a pure bf16 GEMM (uint4 staging, no VALU).
__global__ __launch_bounds__(256) void k_rowscale2(const float* __restrict__ inp,
                                                   const float* __restrict__ nw,
                                                   u16* __restrict__ xnb) {
  int row = blockIdx.x;
  int t = threadIdx.x;
  float4 xv = *(const float4*)(inp + (size_t)row * HDIM + t * 4);
  float ss = xv.x * xv.x + xv.y * xv.y + xv.z * xv.z + xv.w * xv.w;
  for (int off = 32; off > 0; off >>= 1) ss += __shfl_down(ss, off);
  __shared__ float red[4];
  if ((t & 63) == 0) red[t >> 6] = ss;
  __syncthreads();
  float tot = red[0] + red[1] + red[2] + red[3];
  float scale = rsqrtf(tot * (1.f / HDIM) + 1e-6f);
  float4 nv = *(const float4*)(nw + t * 4);
  ushort4 o;
  o.x = f2bf(xv.x * scale * nv.x); o.y = f2bf(xv.y * scale * nv.y);
  o.z = f2bf(xv.z * scale * nv.z); o.w = f2bf(xv.w * scale * nv.w);
  ((ushort4*)xnb)[row * 256 + t] = o;
}

// ---------------- K1: in_proj GEMM, 128x128 tile, pure bf16 ----------------
// A = xnb [2048][1024], W = w1b [4096][1024] (both row-major, K contiguous).
// 4 waves in 2x2; each wave 64x64 out = 4x4 MFMA frags; 16 MFMA / K-step.
__global__ __launch_bounds__(256) void k_gemm1b(const u16* __restrict__ A,
                                                const u16* __restrict__ W,
                                                const float* __restrict__ bias,
                                                u16* __restrict__ xgb) {
  __shared__ u16 Asm[128 * 40];
  __shared__ u16 Wsm[128 * 40];
  int t = threadIdx.x;
  int m0 = blockIdx.y * 128, n0 = blockIdx.x * 128;
  int srow = t >> 1, koff = (t & 1) * 16;
  const u16* Ag = A + (size_t)(m0 + srow) * HDIM + koff;
  const u16* Wg = W + (size_t)(n0 + srow) * HDIM + koff;
  int w = t >> 6, lane = t & 63;
  int wr = w >> 1, wc = w & 1;
  int quad = lane >> 4, mr = lane & 15;
  f32x4 z = {0.f, 0.f, 0.f, 0.f};
  f32x4 acc[4][4] = {{z, z, z, z}, {z, z, z, z}, {z, z, z, z}, {z, z, z, z}};
  const u16* arp = &Asm[(wr * 64 + mr) * 40 + quad * 8];
  const u16* brp = &Wsm[(wc * 64 + mr) * 40 + quad * 8];
  for (int k0 = 0; k0 < HDIM; k0 += 32) {
    uint4 a0 = *(const uint4*)(Ag + k0);
    uint4 a1 = *(const uint4*)(Ag + k0 + 8);
    uint4 w0 = *(const uint4*)(Wg + k0);
    uint4 w1 = *(const uint4*)(Wg + k0 + 8);
    __syncthreads();
    *(uint4*)(&Asm[srow * 40 + koff]) = a0;
    *(uint4*)(&Asm[srow * 40 + koff + 8]) = a1;
    *(uint4*)(&Wsm[srow * 40 + koff]) = w0;
    *(uint4*)(&Wsm[srow * 40 + koff + 8]) = w1;
    __syncthreads();
    bf16x8 af[4], bf[4];
#pragma unroll
    for (int i = 0; i < 4; i++) {
      af[i] = *(const bf16x8*)(arp + i * 16 * 40);
      bf[i] = *(const bf16x8*)(brp + i * 16 * 40);
    }
#pragma unroll
    for (int mi = 0; mi < 4; mi++)
#pragma unroll
      for (int ni = 0; ni < 4; ni++)
        acc[mi][ni] = __builtin_amdgcn_mfma_f32_16x16x32_bf16(af[mi], bf[ni],
                                                              acc[mi][ni], 0, 0, 0);
  }
#pragma unroll
  for (int ni = 0; ni < 4; ni++) {
    int col = n0 + wc * 64 + ni * 16 + mr;
    float bv = bias[col];
#pragma unroll
    for (int mi = 0; mi < 4; mi++) {
#pragma unroll
      for (int rr2 = 0; rr2 < 4; rr2++) {
        int rr = m0 + wr * 64 + mi * 16 + quad * 4 + rr2;
        int row = (rr >> 10) * XR + 3 + (rr & 1023);
        xgb[(size_t)row * 4096 + col] = f2bf(acc[mi][ni][rr2] + bv);
      }
    }
  }
}

// ---------------- K4: out_proj GEMM, 128x64 tile + bias + residual ----------------
// A = yb [2048][2048] bf16, W = wob [1024][2048] bf16.  256 blocks (1/CU).
__global__ __launch_bounds__(256) void k_gemm2b(const u16* __restrict__ A,
                                                const u16* __restrict__ W,
                                                const float* __restrict__ bias,
                                                const float* __restrict__ resid,
                                                float* __restrict__ out) {
  __shared__ u16 Asm[128 * 40];
  __shared__ u16 Wsm[64 * 40];
  int t = threadIdx.x;
  int m0 = blockIdx.y * 128, n0 = blockIdx.x * 64;
  int srow = t >> 1, koff = (t & 1) * 16;
  const u16* Ag = A + (size_t)(m0 + srow) * DDIM + koff;
  const u16* Wg = W + (size_t)(n0 + (srow & 63)) * DDIM + koff;
  int w = t >> 6, lane = t & 63;
  int wr = w >> 1, wc = w & 1;
  int quad = lane >> 4, mr = lane & 15;
  f32x4 z = {0.f, 0.f, 0.f, 0.f};
  f32x4 acc[4][2] = {{z, z}, {z, z}, {z, z}, {z, z}};
  const u16* arp = &Asm[(wr * 64 + mr) * 40 + quad * 8];
  const u16* brp = &Wsm[(wc * 32 + mr) * 40 + quad * 8];
  for (int k0 = 0; k0 < DDIM; k0 += 32) {
    uint4 a0 = *(const uint4*)(Ag + k0);
    uint4 a1 = *(const uint4*)(Ag + k0 + 8);
    uint4 w0, w1;
    if (t < 128) {
      w0 = *(const uint4*)(Wg + k0);
      w1 = *(const uint4*)(Wg + k0 + 8);
    }
    __syncthreads();
    *(uint4*)(&Asm[srow * 40 + koff]) = a0;
    *(uint4*)(&Asm[srow * 40 + koff + 8]) = a1;
    if (t < 128) {
      *(uint4*)(&Wsm[srow * 40 + koff]) = w0;
      *(uint4*)(&Wsm[srow * 40 + koff + 8]) = w1;
    }
    __syncthreads();
    bf16x8 af[4], bf[2];
#pragma unroll
    for (int i = 0; i < 4; i++) af[i] = *(const bf16x8*)(arp + i * 16 * 40);
#pragma unroll
    for (int i = 0; i < 2; i++) bf[i] = *(const bf16x8*)(brp + i * 16 * 40);
#pragma unroll
    for (int mi = 0; mi < 4; mi++)
#pragma unroll
      for (int ni = 0; ni < 2; ni++)
        acc[mi][ni] = __builtin_amdgcn_mfma_f32_16x16x32_bf16(af[mi], bf[ni],
                                                              acc[mi][ni], 0, 0, 0);
  }
#pragma unroll
  for (int ni = 0; ni < 2; ni++) {
    int col = n0 + wc * 32 + ni * 16 + mr;
    float bv = bias[col];
#pragma unroll
    for (int mi = 0; mi < 4; mi++) {
#pragma unroll
      for (int rr2 = 0; rr2 < 4; rr2++) {
        int row = m0 + wr * 64 + mi * 16 + quad * 4 + rr2;
        out[(size_t)row * HDIM + col] =
            acc[mi][ni][rr2] + bv + resid[(size_t)row * HDIM + col];
      }
    }
  }
}

// ---------------- K2: conv+silu (LDS) then x_proj; token-major proj[BL][96] ----------------
__global__ __launch_bounds__(256) void k_xprojc(const u16* __restrict__ xgb,
                                                const float* __restrict__ cw,
                                                const float* __restrict__ cb,
                                                const float* __restrict__ w,
                                                const float* __restrict__ b,
                                                float* __restrict__ proj) {
  __shared__ float row[DDIM];
  int bb = blockIdx.x >> 10, l = blockIdx.x & 1023;
  int t = threadIdx.x;
  int d = t * 8;
  float acc[8];
#pragma unroll
  for (int i = 0; i < 8; i++) acc[i] = cb[d + i];
  float cwv[8][4];
#pragma unroll
  for (int i = 0; i < 8; i++) {
    float4 v = *(const float4*)(cw + (d + i) * 4);
    cwv[i][0] = v.x; cwv[i][1] = v.y; cwv[i][2] = v.z; cwv[i][3] = v.w;
  }
#pragma unroll
  for (int j = 0; j < 4; j++) {
    if (l - 3 + j >= 0) {
      const u16* xr = xgb + (size_t)(bb * XR + l + j) * 4096 + d;
      ushort4 v0 = *(const ushort4*)xr;
      ushort4 v1 = *(const ushort4*)(xr + 4);
      acc[0] += bf2f(v0.x) * cwv[0][j]; acc[1] += bf2f(v0.y) * cwv[1][j];
      acc[2] += bf2f(v0.z) * cwv[2][j]; acc[3] += bf2f(v0.w) * cwv[3][j];
      acc[4] += bf2f(v1.x) * cwv[4][j]; acc[5] += bf2f(v1.y) * cwv[5][j];
      acc[6] += bf2f(v1.z) * cwv[6][j]; acc[7] += bf2f(v1.w) * cwv[7][j];
    }
  }
#pragma unroll
  for (int i = 0; i < 8; i++) row[d + i] = silu_f(acc[i]);
  __syncthreads();
  int wv = t >> 6, lane = t & 63;
  const float4* row4 = (const float4*)row;
  int tk = (bb << 10) + l;
  for (int o = wv; o < 96; o += 4) {
    const float4* wr4 = (const float4*)(w + (size_t)o * DDIM);
    float s0 = 0.f, s1 = 0.f, s2 = 0.f, s3 = 0.f;
#pragma unroll
    for (int k4 = 0; k4 < 8; k4++) {
      int idx = (k4 << 6) + lane;
      float4 wv4 = wr4[idx];
      float4 rv4 = row4[idx];
      s0 += rv4.x * wv4.x; s1 += rv4.y * wv4.y;
      s2 += rv4.z * wv4.z; s3 += rv4.w * wv4.w;
    }
    float s = (s0 + s1) + (s2 + s3);
    s += __shfl_xor(s, 32); s += __shfl_xor(s, 16);
    s += __shfl_xor(s, 8);  s += __shfl_xor(s, 4);
    s += __shfl_xor(s, 2);  s += __shfl_xor(s, 1);
    if (lane == 0) proj[(size_t)tk * 96 + o] = s + b[o];
  }
}

// ---------------- K2b: transpose proj[BL][96] -> projT[96][BL] ----------------
__global__ __launch_bounds__(256) void k_transpose(const float* __restrict__ proj,
                                                   float* __restrict__ projT) {
  __shared__ float tile[64][97];
  int blk = blockIdx.x;                 // 32 blocks: b = blk>>4, 64-token segment = blk&15
  int b = blk >> 4;
  int tok0 = (b << 10) + (blk & 15) * 64;
  int t = threadIdx.x;
  const float* src = proj + (size_t)tok0 * 96;
#pragma unroll
  for (int i = 0; i < 24; i++) {
    int idx = t + i * 256;
    int row = idx / 96, col = idx - row * 96;
    tile[row][col] = src[idx];
  }
  __syncthreads();
  int wv = t >> 6, lane = t & 63;
#pragma unroll
  for (int i = 0; i < 24; i++) {
    int o = wv + i * 4;
    projT[(size_t)o * BL + tok0 + lane] = tile[lane][o];
  }
}

// ---------------- K2c: delta GEMM: deltaT[2048 d][2048 tok] = softplus(dtw.projT + dtb) ----
__global__ __launch_bounds__(256) void k_delta(const float* __restrict__ projT,
                                               const float* __restrict__ dtw,
                                               const float* __restrict__ dtb,
                                               float* __restrict__ deltaT) {
  __shared__ float dw_s[16][64];
  int t = threadIdx.x;
  int d0 = (blockIdx.x >> 3) * 16;        // 128 d-tiles of 16
  int tokbase = (blockIdx.x & 7) * 256;   // 8 token-tiles of 256
  {
    const float* src = dtw + (size_t)d0 * 64;
#pragma unroll
    for (int i = 0; i < 4; i++) {
      int idx = t + i * 256;
      dw_s[idx >> 6][idx & 63] = src[idx];
    }
  }
  __syncthreads();
  int tq = t & 63, dq = t >> 6;           // thread: 4 tokens x 4 d
  const float* pr = projT + tokbase + tq * 4;
  int dbase = d0 + dq * 4;
  float acc[4][4];
#pragma unroll
  for (int di = 0; di < 4; di++) {
    float bv = dtb[dbase + di];
    acc[di][0] = bv; acc[di][1] = bv; acc[di][2] = bv; acc[di][3] = bv;
  }
#pragma unroll 8
  for (int r = 0; r < 64; r++) {
    float4 pv = *(const float4*)(pr + (size_t)r * BL);
#pragma unroll
    for (int di = 0; di < 4; di++) {
      float wk = dw_s[dq * 4 + di][r];
      acc[di][0] += pv.x * wk; acc[di][1] += pv.y * wk;
      acc[di][2] += pv.z * wk; acc[di][3] += pv.w * wk;
    }
  }
#pragma unroll
  for (int di = 0; di < 4; di++) {
    float4 o;
    o.x = softplus_f(acc[di][0]); o.y = softplus_f(acc[di][1]);
    o.z = softplus_f(acc[di][2]); o.w = softplus_f(acc[di][3]);
    *(float4*)(deltaT + (size_t)(dbase + di) * BL + tokbase + tq * 4) = o;
  }
}

// ---------------- K3 v2: selective scan, delta precomputed by k_delta ----------------
__global__ __launch_bounds__(256) void k_scan2(const float* __restrict__ projT,
                                               const float* __restrict__ deltaT,
                                               const u16* __restrict__ xgb,
                                               const float* __restrict__ cw,
                                               const float* __restrict__ cb,
                                               const float* __restrict__ alog,
                                               const float* __restrict__ dparam,
                                               const float* __restrict__ cs,
                                               u16* __restrict__ yb) {
  __shared__ float wtot[4];
  __shared__ float xcp[1088];    // conv+silu x, padded (tok>>4)*17 + (tok&15)
  __shared__ float uvl[1088];    // delta -> uv = delta*xcp -> y-partial A
  __shared__ float dlp[1088];    // xls (staging) -> Dl prefix -> y-partial B

  int t = threadIdx.x;
  int cidx = ((blockIdx.x & 7) << 9) | (blockIdx.x >> 3);   // (b,d)
  int b = cidx >> 11;
  int d = cidx & (DDIM - 1);
  int wv = t >> 6, lane = t & 63;

  float4 cwv = *(const float4*)(cw + d * 4);
  float cbv = cb[d];
  float Dp = dparam[d];
  const u16* xcol = xgb + (size_t)(b * XR + 3) * 4096 + d;
  const u16* gcol = xcol + DDIM;
  u16* ycol = yb + ((size_t)(b << 10)) * DDIM + d;
  int colbase = b << 10;
  int tok0 = t << 2;

  // delta row: coalesced float4 (softplus pre-applied)
  float4 dv = *(const float4*)(deltaT + (size_t)d * BL + colbase + tok0);

  // ---- stage x column (3-halo) into dlp (linear layout) ----
  float* xls = dlp;
  if (t < 3) xls[t] = 0.f;
#pragma unroll
  for (int k = 0; k < 4; k++) {
    int tok = t + (k << 8);
    xls[3 + tok] = bf2f(xcol[(size_t)tok * 4096]);
  }
  __syncthreads();                       // B1: staging visible

  // ---- conv + silu -> xcp ----
#pragma unroll
  for (int i = 0; i < 4; i++) {
    int tok = tok0 + i;
    float xc = silu_f(cbv + cwv.x * xls[tok] + cwv.y * xls[tok + 1] +
                      cwv.z * xls[tok + 2] + cwv.w * xls[tok + 3]);
    xcp[((tok >> 4) * 17) + (tok & 15)] = xc;
  }
  float d0 = dv.x, d1 = dv.y, d2 = dv.z, d3 = dv.w;
  uvl[((tok0 >> 4) * 17) + (tok0 & 15)]             = d0;
  uvl[(((tok0 + 1) >> 4) * 17) + ((tok0 + 1) & 15)] = d1;
  uvl[(((tok0 + 2) >> 4) * 17) + ((tok0 + 2) & 15)] = d2;
  uvl[(((tok0 + 3) >> 4) * 17) + ((tok0 + 3) & 15)] = d3;
  // ---- global inclusive prefix of delta ----
  float c0 = d0, c1 = c0 + d1, c2 = c1 + d2, c3 = c2 + d3;
  float sc = c3;
#pragma unroll
  for (int off = 1; off < 64; off <<= 1) {
    float u = __shfl_up(sc, off);
    if (lane >= off) sc += u;
  }
  if (lane == 63) wtot[wv] = sc;
  __syncthreads();                       // B2: conv xls-reads done; wtot visible
  {
    float base = sc - c3;
#pragma unroll
    for (int i = 0; i < 3; i++) if (i < wv) base += wtot[i];
    dlp[((tok0 >> 4) * 17) + (tok0 & 15)]             = base + c0;
    dlp[(((tok0 + 1) >> 4) * 17) + ((tok0 + 1) & 15)] = base + c1;
    dlp[(((tok0 + 2) >> 4) * 17) + ((tok0 + 2) & 15)] = base + c2;
    dlp[(((tok0 + 3) >> 4) * 17) + ((tok0 + 3) & 15)] = base + c3;
  }
#pragma unroll
  for (int i = 0; i < 4; i++) {
    int tok = tok0 + i;
    int p = ((tok >> 4) * 17) + (tok & 15);
    uvl[p] = uvl[p] * xcp[p];            // uv = delta * conv_x
  }
  __syncthreads();                       // B3: Dl + uv visible

  int pb = lane * 17;
  float y[16];
#pragma unroll
  for (int i = 0; i < 16; i++) y[i] = 0.f;
  float Dprev = (lane == 0) ? 0.f : dlp[pb - 2];

#pragma unroll 1
  for (int r = 0; r < 4; r++) {
    int n = (wv << 2) + r;
    float An = -__expf(alog[d * NST + n]);
    float st = cs[(size_t)(b * DDIM + d) * NST + n];
    const float* pB = projT + (size_t)(64 + n) * BL + colbase + (lane << 4);
    const float* pC = pB + (size_t)16 * BL;
    float Pp = __expf(An * Dprev);
    float sl = 0.f;
#pragma unroll
    for (int c = 0; c < 4; c++) {
      float4 bv = *(const float4*)(pB + c * 4);
      float4 cv = *(const float4*)(pC + c * 4);
      float bvs[4] = {bv.x, bv.y, bv.z, bv.w};
      float cvs[4] = {cv.x, cv.y, cv.z, cv.w};
#pragma unroll
      for (int j = 0; j < 4; j++) {
        int i = c * 4 + j;
        float P = __expf(An * dlp[pb + i]);
        float w = uvl[pb + i] * bvs[j] * __builtin_amdgcn_rcpf(fmaxf(Pp, 1e-10f));
        sl += w;
        y[i] += (sl * Pp + st * P) * cvs[j];
        Pp = P;
      }
    }
    float s2 = sl;
#pragma unroll
    for (int off = 1; off < 64; off <<= 1) {
      float u = __shfl_up(s2, off);
      if (lane >= off) s2 += u;
    }
    float Soff = s2 - sl;
#pragma unroll
    for (int c = 0; c < 4; c++) {
      float4 cv = *(const float4*)(pC + c * 4);
      float cvs[4] = {cv.x, cv.y, cv.z, cv.w};
#pragma unroll
      for (int j = 0; j < 4; j++) {
        int i = c * 4 + j;
        float dlm = (i == 0) ? Dprev : dlp[pb + i - 1];
        y[i] += Soff * __expf(An * dlm) * cvs[j];
      }
    }
  }
  __syncthreads();                       // B4
  if (wv == 2) {
#pragma unroll
    for (int i = 0; i < 16; i++) uvl[pb + i] = y[i];
  } else if (wv == 3) {
#pragma unroll
    for (int i = 0; i < 16; i++) dlp[pb + i] = y[i];
  }
  __syncthreads();                       // B5
  if (wv == 0) {
#pragma unroll
    for (int i = 0; i < 16; i++) uvl[pb + i] += y[i];
  } else if (wv == 1) {
#pragma unroll
    for (int i = 0; i < 16; i++) dlp[pb + i] += y[i];
  }
  __syncthreads();                       // B6
#pragma unroll
  for (int i = 0; i < 4; i++) {
    int tok = tok0 + i;
    int p = ((tok >> 4) * 17) + (tok & 15);
    float yv = uvl[p] + dlp[p] + xcp[p] * Dp;
    float g = bf2f(gcol[(size_t)tok * 4096]);
    ycol[(size_t)tok * DDIM] = f2bf(yv * silu_f(g));
  }
}

// ---------------- K3 fallback (R5): in-scan dt-dot, used when ws too small ----------------
__global__ __launch_bounds__(256) void k_scan(const float* __restrict__ projT,
                                              const u16* __restrict__ xgb,
                                              const float* __restrict__ cw,
                                              const float* __restrict__ cb,
                                              const float* __restrict__ dtw,
                                              const float* __restrict__ dtb,
                                              const float* __restrict__ alog,
                                              const float* __restrict__ dparam,
                                              const float* __restrict__ cs,
                                              u16* __restrict__ yb) {
  __shared__ float dtw_s[64];
  __shared__ float wtot[4];
  __shared__ float xcp[1088];
  __shared__ float uvl[1088];
  __shared__ float dlp[1088];

  int t = threadIdx.x;
  int cidx = ((blockIdx.x & 7) << 9) | (blockIdx.x >> 3);
  int b = cidx >> 11;
  int d = cidx & (DDIM - 1);
  int wv = t >> 6, lane = t & 63;

  if (t < 64) dtw_s[t] = dtw[(size_t)d * 64 + t];
  float4 cwv = *(const float4*)(cw + d * 4);
  float cbv = cb[d];
  float dtbv = dtb[d];
  float Dp = dparam[d];
  const u16* xcol = xgb + (size_t)(b * XR + 3) * 4096 + d;
  const u16* gcol = xcol + DDIM;
  u16* ycol = yb + ((size_t)(b << 10)) * DDIM + d;
  int colbase = b << 10;

  float* xls = dlp;
  if (t < 3) xls[t] = 0.f;
#pragma unroll
  for (int k = 0; k < 4; k++) {
    int tok = t + (k << 8);
    xls[3 + tok] = bf2f(xcol[(size_t)tok * 4096]);
  }
  __syncthreads();

  int tok0 = t << 2;
#pragma unroll
  for (int i = 0; i < 4; i++) {
    int tok = tok0 + i;
    float xc = silu_f(cbv + cwv.x * xls[tok] + cwv.y * xls[tok + 1] +
                      cwv.z * xls[tok + 2] + cwv.w * xls[tok + 3]);
    xcp[((tok >> 4) * 17) + (tok & 15)] = xc;
  }
  float d0, d1, d2, d3;
  {
    float4 acc = {dtbv, dtbv, dtbv, dtbv};
    const float* pr = projT + colbase + tok0;
#pragma unroll 8
    for (int kk = 0; kk < 64; kk++) {
      float4 v = *(const float4*)(pr + (size_t)kk * BL);
      float wk = dtw_s[kk];
      acc.x += v.x * wk; acc.y += v.y * wk; acc.z += v.z * wk; acc.w += v.w * wk;
    }
    d0 = softplus_f(acc.x); d1 = softplus_f(acc.y);
    d2 = softplus_f(acc.z); d3 = softplus_f(acc.w);
    uvl[((tok0 >> 4) * 17) + (tok0 & 15)]             = d0;
    uvl[(((tok0 + 1) >> 4) * 17) + ((tok0 + 1) & 15)] = d1;
    uvl[(((tok0 + 2) >> 4) * 17) + ((tok0 + 2) & 15)] = d2;
    uvl[(((tok0 + 3) >> 4) * 17) + ((tok0 + 3) & 15)] = d3;
  }
  float c0 = d0, c1 = c0 + d1, c2 = c1 + d2, c3 = c2 + d3;
  float sc = c3;
#pragma unroll
  for (int off = 1; off < 64; off <<= 1) {
    float u = __shfl_up(sc, off);
    if (lane >= off) sc += u;
  }
  if (lane == 63) wtot[wv] = sc;
  __syncthreads();
  {
    float base = sc - c3;
#pragma unroll
    for (int i = 0; i < 3; i++) if (i < wv) base += wtot[i];
    dlp[((tok0 >> 4) * 17) + (tok0 & 15)]             = base + c0;
    dlp[(((tok0 + 1) >> 4) * 17) + ((tok0 + 1) & 15)] = base + c1;
    dlp[(((tok0 + 2) >> 4) * 17) + ((tok0 + 2) & 15)] = base + c2;
    dlp[(((tok0 + 3) >> 4) * 17) + ((tok0 + 3) & 15)] = base + c3;
  }
#pragma unroll
  for (int i = 0; i < 4; i++) {
    int tok = tok0 + i;
    int p = ((tok >> 4) * 17) + (tok & 15);
    uvl[p] = uvl[p] * xcp[p];
  }
  __syncthreads();

  int pb = lane * 17;
  float y[16];
#pragma unroll
  for (int i = 0; i < 16; i++) y[i] = 0.f;
  float Dprev = (lane == 0) ? 0.f : dlp[pb - 2];

#pragma unroll 1
  for (int r = 0; r < 4; r++) {
    int n = (wv << 2) + r;
    float An = -__expf(alog[d * NST + n]);
    float st = cs[(size_t)(b * DDIM + d) * NST + n];
    const float* pB = projT + (size_t)(64 + n) * BL + colbase + (lane << 4);
    const float* pC = pB + (size_t)16 * BL;
    float Pp = __expf(An * Dprev);
    float sl = 0.f;
#pragma unroll
    for (int c = 0; c < 4; c++) {
      float4 bv = *(const float4*)(pB + c * 4);
      float4 cv = *(const float4*)(pC + c * 4);
      float bvs[4] = {bv.x, bv.y, bv.z, bv.w};
      float cvs[4] = {cv.x, cv.y, cv.z, cv.w};
#pragma unroll
      for (int j = 0; j < 4; j++) {
        int i = c * 4 + j;
        float P = __expf(An * dlp[pb + i]);
        float w = uvl[pb + i] * bvs[j] * __builtin_amdgcn_rcpf(fmaxf(Pp, 1e-10f));
        sl += w;
        y[i] += (sl * Pp + st * P) * cvs[j];
        Pp = P;
      }
    }
    float s2 = sl;
#pragma unroll
    for (int off = 1; off < 64; off <<= 1) {
      float u = __shfl_up(s2, off);
      if (lane >= off) s2 += u;
    }
    float Soff = s2 - sl;
#pragma unroll
    for (int c = 0; c < 4; c++) {
      float4 cv = *(const float4*)(pC + c * 4);
      float cvs[4] = {cv.x, cv.y, cv.z, cv.w};
#pragma unroll
      for (int j = 0; j < 4; j++) {
        int i = c * 4 + j;
        float dlm = (i == 0) ? Dprev : dlp[pb + i - 1];
        y[i] += Soff * __expf(An * dlm) * cvs[j];
      }
    }
  }
  __syncthreads();
  if (wv == 2) {
#pragma unroll
    for (int i = 0; i < 16; i++) uvl[pb + i] = y[i];
  } else if (wv == 3) {
#pragma unroll
    for (int i = 0; i < 16; i++) dlp[pb + i] = y[i];
  }
  __syncthreads();
  if (wv == 0) {
#pragma unroll
    for (int i = 0; i < 16; i++) uvl[pb + i] += y[i];
  } else if (wv == 1) {
#pragma unroll
    for (int i = 0; i < 16; i++) dlp[pb + i] += y[i];
  }
  __syncthreads();
#pragma unroll
  for (int i = 0; i < 4; i++) {
    int tok = tok0 + i;
    int p = ((tok >> 4) * 17) + (tok & 15);
    float yv = uvl[p] + dlp[p] + xcp[p] * Dp;
    float g = bf2f(gcol[(size_t)tok * 4096]);
    ycol[(size_t)tok * DDIM] = f2bf(yv * silu_f(g));
  }
}

extern "C" void kernel_launch(void* const* d_in, const int* in_sizes, int n_in,
                              void* d_out, int out_size, void* d_ws, size_t ws_size,
                              hipStream_t stream) {
  const float* inp    = (const float*)d_in[0];
  const float* cstate = (const float*)d_in[1];
  const float* norm_w = (const float*)d_in[2];
  const float* w1     = (const float*)d_in[3];
  const float* b1     = (const float*)d_in[4];
  const float* convw  = (const float*)d_in[5];
  const float* convb  = (const float*)d_in[6];
  const float* xpw    = (const float*)d_in[7];
  const float* xpb    = (const float*)d_in[8];
  const float* dtw    = (const float*)d_in[9];
  const float* dtb    = (const float*)d_in[10];
  const float* alog   = (const float*)d_in[11];
  const float* dparam = (const float*)d_in[12];
  const float* wo     = (const float*)d_in[13];
  const float* bo     = (const float*)d_in[14];
  float* out = (float*)d_out;

  // base workspace layout, 39,378,944 B; deltaT (16 MB) appended (ws confirmed >= 56 MB)
  char* wsb = (char*)d_ws;
  u16*   w1b    = (u16*)(wsb + 0);            //  8,388,608 B  [4096][1024] bf16
  u16*   wob    = (u16*)(wsb + 8388608);      //  4,194,304 B  [1024][2048] bf16
  float* proj   = (float*)(wsb + 12591104);   //    786,432 B  [2048][96] token-major
  float* projT  = (float*)(wsb + 13377536);   //    786,432 B  [96][2048] transposed
  u16*   xgb    = (u16*)(wsb + 14163968);     // 16,826,368 B  [2][1027][4096] bf16
  u16*   yb     = (u16*)(wsb + 30990336);     //  8,388,608 B  [2][1024][2048] bf16
  u16*   xnb    = yb;                         //  4,194,304 B  [2048][1024] bf16 (aliases yb;
                                              //  consumed by gemm1 before scan writes yb)
  float* deltaT = (float*)(wsb + 39378944);   // 16,777,216 B  [2048 d][2048 tok] f32

  const size_t WS_NEED_DELTA = 39378944u + 16777216u;

  k_castw<<<4096, 256, 0, stream>>>(w1, w1b);
  k_castw<<<2048, 256, 0, stream>>>(wo, wob);
  k_rowscale2<<<BL, 256, 0, stream>>>(inp, norm_w, xnb);
  k_gemm1b<<<dim3(32, 16), 256, 0, stream>>>(xnb, w1b, b1, xgb);
  k_xprojc<<<BL, 256, 0, stream>>>(xgb, convw, convb, xpw, xpb, proj);
  k_transpose<<<32, 256, 0, stream>>>(proj, projT);
  if (ws_size >= WS_NEED_DELTA) {
    k_delta<<<1024, 256, 0, stream>>>(projT, dtw, dtb, deltaT);
    k_scan2<<<2 * DDIM, 256, 0, stream>>>(projT, deltaT, xgb, convw, convb,
                                          alog, dparam, cstate, yb);
  } else {
    k_scan<<<2 * DDIM, 256, 0, stream>>>(projT, xgb, convw, convb, dtw, dtb,
                                         alog, dparam, cstate, yb);
  }
  k_gemm2b<<<dim3(16, 16), 256, 0, stream>>>(yb, wob, bo, inp, out);
}

// Round 9
// 335.645 us; speedup vs baseline: 1.7689x; 1.0165x over previous
//
#include <hip/hip_runtime.h>
#include <stdint.h>

#define LSEQ 1024
#define HDIM 1024
#define DDIM 2048
#define BL 2048
#define NST 16
#define XR 1027          // 3 halo rows (zeroed by k_zerohalo) + 1024 tokens

typedef unsigned short u16;
typedef __attribute__((ext_vector_type(8))) short bf16x8;
typedef __attribute__((ext_vector_type(4))) float f32x4;

// silu via v_rcp (1-ulp rcp; output tolerance is bf16-dominated)
static __device__ __forceinline__ float silu_f(float v) {
  return v * __builtin_amdgcn_rcpf(1.f + __expf(-v));
}
static __device__ __forceinline__ float bf2f(u16 u) {
  union { float f; unsigned int i; } c; c.i = ((unsigned int)u) << 16; return c.f;
}
static __device__ __forceinline__ u16 f2bf(float f) {
  union { float f; unsigned int i; } c; c.f = f;
  unsigned int r = c.i + 0x7fffu + ((c.i >> 16) & 1u);
  return (u16)(r >> 16);
}
static __device__ __forceinline__ float softplus_f(float v) {
  return (v > 20.f) ? v : __logf(1.f + __expf(v));
}

// ---------------- cast fp32 -> bf16 (weights, once per launch) ----------------
__global__ __launch_bounds__(256) void k_castw(const float* __restrict__ src,
                                               u16* __restrict__ dst) {
  int idx = blockIdx.x * 256 + threadIdx.x;
  float4 v = ((const float4*)src)[idx];
  ushort4 o;
  o.x = f2bf(v.x); o.y = f2bf(v.y); o.z = f2bf(v.z); o.w = f2bf(v.w);
  ((ushort4*)dst)[idx] = o;
}

// ---------------- cast fp32 -> split bf16 hi/lo (xpw) ----------------
// hi = bf16(v), lo = bf16(v - hi): 3-MFMA split product gives ~f32 precision.
__global__ __launch_bounds__(256) void k_castsplit(const float* __restrict__ src,
                                                   u16* __restrict__ hi,
                                                   u16* __restrict__ lo) {
  int idx = blockIdx.x * 256 + threadIdx.x;
  float4 v = ((const float4*)src)[idx];
  ushort4 h, l;
  h.x = f2bf(v.x); l.x = f2bf(v.x - bf2f(h.x));
  h.y = f2bf(v.y); l.y = f2bf(v.y - bf2f(h.y));
  h.z = f2bf(v.z); l.z = f2bf(v.z - bf2f(h.z));
  h.w = f2bf(v.w); l.w = f2bf(v.w - bf2f(h.w));
  ((ushort4*)hi)[idx] = h;
  ((ushort4*)lo)[idx] = l;
}

// ---------------- zero the 3 halo rows of each batch stripe in xgb ----------------
__global__ __launch_bounds__(256) void k_zerohalo(u16* __restrict__ xgb) {
  int idx = blockIdx.x * 256 + threadIdx.x;       // 6144 ushort4 total (24 blocks)
  int b = idx / 3072;                             // batch
  int r = idx - b * 3072;                         // 3 rows x 1024 ushort4
  ushort4 z4 = {0, 0, 0, 0};
  ((ushort4*)(xgb + (size_t)b * XR * 4096))[r] = z4;
}

// ---------------- per-row rmsnorm + normalize -> xnb bf16 [2048][1024] ----------------
__global__ __launch_bounds__(256) void k_rowscale2(const float* __restrict__ inp,
                                                   const float* __restrict__ nw,
                                                   u16* __restrict__ xnb) {
  int row = blockIdx.x;
  int t = threadIdx.x;
  float4 xv = *(const float4*)(inp + (size_t)row * HDIM + t * 4);
  float ss = xv.x * xv.x + xv.y * xv.y + xv.z * xv.z + xv.w * xv.w;
  for (int off = 32; off > 0; off >>= 1) ss += __shfl_down(ss, off);
  __shared__ float red[4];
  if ((t & 63) == 0) red[t >> 6] = ss;
  __syncthreads();
  float tot = red[0] + red[1] + red[2] + red[3];
  float scale = rsqrtf(tot * (1.f / HDIM) + 1e-6f);
  float4 nv = *(const float4*)(nw + t * 4);
  ushort4 o;
  o.x = f2bf(xv.x * scale * nv.x); o.y = f2bf(xv.y * scale * nv.y);
  o.z = f2bf(xv.z * scale * nv.z); o.w = f2bf(xv.w * scale * nv.w);
  ((ushort4*)xnb)[row * 256 + t] = o;
}

// ---------------- K1: in_proj GEMM, 128x128 tile, pure bf16 ----------------
__global__ __launch_bounds__(256) void k_gemm1b(const u16* __restrict__ A,
                                                const u16* __restrict__ W,
                                                const float* __restrict__ bias,
                                                u16* __restrict__ xgb) {
  __shared__ u16 Asm[128 * 40];
  __shared__ u16 Wsm[128 * 40];
  int t = threadIdx.x;
  int m0 = blockIdx.y * 128, n0 = blockIdx.x * 128;
  int srow = t >> 1, koff = (t & 1) * 16;
  const u16* Ag = A + (size_t)(m0 + srow) * HDIM + koff;
  const u16* Wg = W + (size_t)(n0 + srow) * HDIM + koff;
  int w = t >> 6, lane = t & 63;
  int wr = w >> 1, wc = w & 1;
  int quad = lane >> 4, mr = lane & 15;
  f32x4 z = {0.f, 0.f, 0.f, 0.f};
  f32x4 acc[4][4] = {{z, z, z, z}, {z, z, z, z}, {z, z, z, z}, {z, z, z, z}};
  const u16* arp = &Asm[(wr * 64 + mr) * 40 + quad * 8];
  const u16* brp = &Wsm[(wc * 64 + mr) * 40 + quad * 8];
  for (int k0 = 0; k0 < HDIM; k0 += 32) {
    uint4 a0 = *(const uint4*)(Ag + k0);
    uint4 a1 = *(const uint4*)(Ag + k0 + 8);
    uint4 w0 = *(const uint4*)(Wg + k0);
    uint4 w1 = *(const uint4*)(Wg + k0 + 8);
    __syncthreads();
    *(uint4*)(&Asm[srow * 40 + koff]) = a0;
    *(uint4*)(&Asm[srow * 40 + koff + 8]) = a1;
    *(uint4*)(&Wsm[srow * 40 + koff]) = w0;
    *(uint4*)(&Wsm[srow * 40 + koff + 8]) = w1;
    __syncthreads();
    bf16x8 af[4], bf[4];
#pragma unroll
    for (int i = 0; i < 4; i++) {
      af[i] = *(const bf16x8*)(arp + i * 16 * 40);
      bf[i] = *(const bf16x8*)(brp + i * 16 * 40);
    }
#pragma unroll
    for (int mi = 0; mi < 4; mi++)
#pragma unroll
      for (int ni = 0; ni < 4; ni++)
        acc[mi][ni] = __builtin_amdgcn_mfma_f32_16x16x32_bf16(af[mi], bf[ni],
                                                              acc[mi][ni], 0, 0, 0);
  }
#pragma unroll
  for (int ni = 0; ni < 4; ni++) {
    int col = n0 + wc * 64 + ni * 16 + mr;
    float bv = bias[col];
#pragma unroll
    for (int mi = 0; mi < 4; mi++) {
#pragma unroll
      for (int rr2 = 0; rr2 < 4; rr2++) {
        int rr = m0 + wr * 64 + mi * 16 + quad * 4 + rr2;
        int row = (rr >> 10) * XR + 3 + (rr & 1023);
        xgb[(size_t)row * 4096 + col] = f2bf(acc[mi][ni][rr2] + bv);
      }
    }
  }
}

// ---------------- K4: out_proj GEMM, 128x64 tile + bias + residual ----------------
__global__ __launch_bounds__(256) void k_gemm2b(const u16* __restrict__ A,
                                                const u16* __restrict__ W,
                                                const float* __restrict__ bias,
                                                const float* __restrict__ resid,
                                                float* __restrict__ out) {
  __shared__ u16 Asm[128 * 40];
  __shared__ u16 Wsm[64 * 40];
  int t = threadIdx.x;
  int m0 = blockIdx.y * 128, n0 = blockIdx.x * 64;
  int srow = t >> 1, koff = (t & 1) * 16;
  const u16* Ag = A + (size_t)(m0 + srow) * DDIM + koff;
  const u16* Wg = W + (size_t)(n0 + (srow & 63)) * DDIM + koff;
  int w = t >> 6, lane = t & 63;
  int wr = w >> 1, wc = w & 1;
  int quad = lane >> 4, mr = lane & 15;
  f32x4 z = {0.f, 0.f, 0.f, 0.f};
  f32x4 acc[4][2] = {{z, z}, {z, z}, {z, z}, {z, z}};
  const u16* arp = &Asm[(wr * 64 + mr) * 40 + quad * 8];
  const u16* brp = &Wsm[(wc * 32 + mr) * 40 + quad * 8];
  for (int k0 = 0; k0 < DDIM; k0 += 32) {
    uint4 a0 = *(const uint4*)(Ag + k0);
    uint4 a1 = *(const uint4*)(Ag + k0 + 8);
    uint4 w0, w1;
    if (t < 128) {
      w0 = *(const uint4*)(Wg + k0);
      w1 = *(const uint4*)(Wg + k0 + 8);
    }
    __syncthreads();
    *(uint4*)(&Asm[srow * 40 + koff]) = a0;
    *(uint4*)(&Asm[srow * 40 + koff + 8]) = a1;
    if (t < 128) {
      *(uint4*)(&Wsm[srow * 40 + koff]) = w0;
      *(uint4*)(&Wsm[srow * 40 + koff + 8]) = w1;
    }
    __syncthreads();
    bf16x8 af[4], bf[2];
#pragma unroll
    for (int i = 0; i < 4; i++) af[i] = *(const bf16x8*)(arp + i * 16 * 40);
#pragma unroll
    for (int i = 0; i < 2; i++) bf[i] = *(const bf16x8*)(brp + i * 16 * 40);
#pragma unroll
    for (int mi = 0; mi < 4; mi++)
#pragma unroll
      for (int ni = 0; ni < 2; ni++)
        acc[mi][ni] = __builtin_amdgcn_mfma_f32_16x16x32_bf16(af[mi], bf[ni],
                                                              acc[mi][ni], 0, 0, 0);
  }
#pragma unroll
  for (int ni = 0; ni < 2; ni++) {
    int col = n0 + wc * 32 + ni * 16 + mr;
    float bv = bias[col];
#pragma unroll
    for (int mi = 0; mi < 4; mi++) {
#pragma unroll
      for (int rr2 = 0; rr2 < 4; rr2++) {
        int row = m0 + wr * 64 + mi * 16 + quad * 4 + rr2;
        out[(size_t)row * HDIM + col] =
            acc[mi][ni][rr2] + bv + resid[(size_t)row * HDIM + col];
      }
    }
  }
}

// ---------------- K2 v2: fused conv+silu + x_proj GEMM -> projT directly ----------------
// projT[o][tok] = sum_d w[o][d] * silu(conv(x))[tok][d]   (bias added in k_xcomb)
// Grid 64 = 32 token-tiles (64 tok) x 2 K-partitions (1024 each).
// Split-bf16 (hi/lo) on BOTH w and xc; 3 MFMAs per product -> ~f32 precision.
// ks=0 writes projT, ks=1 writes scratch; k_xcomb sums + bias.
__global__ __launch_bounds__(256) void k_xprojT(const u16* __restrict__ xgb,
                                                const u16* __restrict__ whb,
                                                const u16* __restrict__ wlb,
                                                const float* __restrict__ cw,
                                                const float* __restrict__ cb,
                                                float* __restrict__ outA,
                                                float* __restrict__ outB) {
  __shared__ u16 Xst[67 * 40];     // raw x rows tok-3 .. tok+63
  __shared__ u16 XH[64 * 40];      // xc hi
  __shared__ u16 XL[64 * 40];      // xc lo
  __shared__ u16 WH[96 * 40];      // w hi
  __shared__ u16 WL[96 * 40];      // w lo
  int t = threadIdx.x;
  int tt = blockIdx.x & 31, ks = blockIdx.x >> 5;
  int tokbase = tt << 6;
  int b = tokbase >> 10, l0 = tokbase & 1023;
  int kbase = ks << 10;
  const u16* xbase = xgb + (size_t)(b * XR + l0) * 4096;   // raw row i <-> tok tokbase-3+i
  float* outp = (ks == 0) ? outA : outB;
  int dlane = t & 31, tokg = t >> 5;                       // conv mapping: 8 tok x 32 d
  int wvq = t >> 6, lane = t & 63;
  int quad = lane >> 4, mr = lane & 15;
  f32x4 z = {0.f, 0.f, 0.f, 0.f};
  f32x4 acc[6] = {z, z, z, z, z, z};

  for (int it = 0; it < 32; it++) {
    int kc = kbase + (it << 5);
    // stage raw x tile [67][32] (64B rows, uint4 parts)
    for (int idx = t; idx < 268; idx += 256) {
      int r = idx >> 2, p = idx & 3;
      uint4 v = *(const uint4*)(xbase + (size_t)r * 4096 + kc + p * 8);
      *(uint4*)(&Xst[r * 40 + p * 8]) = v;
    }
    // stage w hi/lo tiles [96][32]
    for (int idx = t; idx < 384; idx += 256) {
      int r = idx >> 2, p = idx & 3;
      *(uint4*)(&WH[r * 40 + p * 8]) = *(const uint4*)(whb + (size_t)r * 2048 + kc + p * 8);
      *(uint4*)(&WL[r * 40 + p * 8]) = *(const uint4*)(wlb + (size_t)r * 2048 + kc + p * 8);
    }
    __syncthreads();
    // conv + silu + bf16-split; thread owns 8 consecutive tokens at one d
    {
      int d = kc + dlane;
      float4 cwv = *(const float4*)(cw + d * 4);
      float cbv = cb[d];
      float xr[11];
#pragma unroll
      for (int j = 0; j < 11; j++) xr[j] = bf2f(Xst[(tokg * 8 + j) * 40 + dlane]);
#pragma unroll
      for (int jj = 0; jj < 8; jj++) {
        float xc = silu_f(cbv + cwv.x * xr[jj] + cwv.y * xr[jj + 1] +
                          cwv.z * xr[jj + 2] + cwv.w * xr[jj + 3]);
        u16 h = f2bf(xc);
        u16 l = f2bf(xc - bf2f(h));
        XH[(tokg * 8 + jj) * 40 + dlane] = h;
        XL[(tokg * 8 + jj) * 40 + dlane] = l;
      }
    }
    __syncthreads();
    // MFMA: C[o][tok], af = w rows, bf = xc rows; wave wvq owns 16 tokens
    bf16x8 xh = *(const bf16x8*)(&XH[(wvq * 16 + mr) * 40 + quad * 8]);
    bf16x8 xl = *(const bf16x8*)(&XL[(wvq * 16 + mr) * 40 + quad * 8]);
#pragma unroll
    for (int mi = 0; mi < 6; mi++) {
      bf16x8 wh = *(const bf16x8*)(&WH[(mi * 16 + mr) * 40 + quad * 8]);
      bf16x8 wl = *(const bf16x8*)(&WL[(mi * 16 + mr) * 40 + quad * 8]);
      acc[mi] = __builtin_amdgcn_mfma_f32_16x16x32_bf16(wh, xh, acc[mi], 0, 0, 0);
      acc[mi] = __builtin_amdgcn_mfma_f32_16x16x32_bf16(wh, xl, acc[mi], 0, 0, 0);
      acc[mi] = __builtin_amdgcn_mfma_f32_16x16x32_bf16(wl, xh, acc[mi], 0, 0, 0);
    }
    __syncthreads();
  }
  // epilogue: row = o (af-side: quad*4+rr), col = tok (bf-side: mr)
#pragma unroll
  for (int mi = 0; mi < 6; mi++) {
#pragma unroll
    for (int rr = 0; rr < 4; rr++) {
      int o = mi * 16 + quad * 4 + rr;
      outp[(size_t)o * BL + tokbase + wvq * 16 + mr] = acc[mi][rr];
    }
  }
}

// ---------------- K2d: combine K-partials + bias into projT ----------------
__global__ __launch_bounds__(256) void k_xcomb(float* __restrict__ projT,
                                               const float* __restrict__ scr,
                                               const float* __restrict__ xpb) {
  int idx = blockIdx.x * 256 + threadIdx.x;   // float4 over [96][2048]
  int o = idx >> 9;                            // 512 float4 per o-row
  float4 a = ((const float4*)projT)[idx];
  float4 s = ((const float4*)scr)[idx];
  float bv = xpb[o];
  a.x += s.x + bv; a.y += s.y + bv; a.z += s.z + bv; a.w += s.w + bv;
  ((float4*)projT)[idx] = a;
}

// ---------------- K2c: delta GEMM: deltaT[2048 d][2048 tok] = softplus(dtw.projT + dtb) ----
__global__ __launch_bounds__(256) void k_delta(const float* __restrict__ projT,
                                               const float* __restrict__ dtw,
                                               const float* __restrict__ dtb,
                                               float* __restrict__ deltaT) {
  __shared__ float dw_s[16][64];
  int t = threadIdx.x;
  int d0 = (blockIdx.x >> 3) * 16;        // 128 d-tiles of 16
  int tokbase = (blockIdx.x & 7) * 256;   // 8 token-tiles of 256
  {
    const float* src = dtw + (size_t)d0 * 64;
#pragma unroll
    for (int i = 0; i < 4; i++) {
      int idx = t + i * 256;
      dw_s[idx >> 6][idx & 63] = src[idx];
    }
  }
  __syncthreads();
  int tq = t & 63, dq = t >> 6;           // thread: 4 tokens x 4 d
  const float* pr = projT + tokbase + tq * 4;
  int dbase = d0 + dq * 4;
  float acc[4][4];
#pragma unroll
  for (int di = 0; di < 4; di++) {
    float bv = dtb[dbase + di];
    acc[di][0] = bv; acc[di][1] = bv; acc[di][2] = bv; acc[di][3] = bv;
  }
#pragma unroll 8
  for (int r = 0; r < 64; r++) {
    float4 pv = *(const float4*)(pr + (size_t)r * BL);
#pragma unroll
    for (int di = 0; di < 4; di++) {
      float wk = dw_s[dq * 4 + di][r];
      acc[di][0] += pv.x * wk; acc[di][1] += pv.y * wk;
      acc[di][2] += pv.z * wk; acc[di][3] += pv.w * wk;
    }
  }
#pragma unroll
  for (int di = 0; di < 4; di++) {
    float4 o;
    o.x = softplus_f(acc[di][0]); o.y = softplus_f(acc[di][1]);
    o.z = softplus_f(acc[di][2]); o.w = softplus_f(acc[di][3]);
    *(float4*)(deltaT + (size_t)(dbase + di) * BL + tokbase + tq * 4) = o;
  }
}

// ---------------- K3 v2: selective scan, delta precomputed by k_delta ----------------
__global__ __launch_bounds__(256) void k_scan2(const float* __restrict__ projT,
                                               const float* __restrict__ deltaT,
                                               const u16* __restrict__ xgb,
                                               const float* __restrict__ cw,
                                               const float* __restrict__ cb,
                                               const float* __restrict__ alog,
                                               const float* __restrict__ dparam,
                                               const float* __restrict__ cs,
                                               u16* __restrict__ yb) {
  __shared__ float wtot[4];
  __shared__ float xcp[1088];    // conv+silu x, padded (tok>>4)*17 + (tok&15)
  __shared__ float uvl[1088];    // delta -> uv = delta*xcp -> y-partial A
  __shared__ float dlp[1088];    // xls (staging) -> Dl prefix -> y-partial B

  int t = threadIdx.x;
  int cidx = ((blockIdx.x & 7) << 9) | (blockIdx.x >> 3);   // (b,d)
  int b = cidx >> 11;
  int d = cidx & (DDIM - 1);
  int wv = t >> 6, lane = t & 63;

  float4 cwv = *(const float4*)(cw + d * 4);
  float cbv = cb[d];
  float Dp = dparam[d];
  const u16* xcol = xgb + (size_t)(b * XR + 3) * 4096 + d;
  const u16* gcol = xcol + DDIM;
  u16* ycol = yb + ((size_t)(b << 10)) * DDIM + d;
  int colbase = b << 10;
  int tok0 = t << 2;

  // delta row: coalesced float4 (softplus pre-applied)
  float4 dv = *(const float4*)(deltaT + (size_t)d * BL + colbase + tok0);

  // ---- stage x column (3-halo) into dlp (linear layout) ----
  float* xls = dlp;
  if (t < 3) xls[t] = 0.f;
#pragma unroll
  for (int k = 0; k < 4; k++) {
    int tok = t + (k << 8);
    xls[3 + tok] = bf2f(xcol[(size_t)tok * 4096]);
  }
  __syncthreads();                       // B1: staging visible

  // ---- conv + silu -> xcp ----
#pragma unroll
  for (int i = 0; i < 4; i++) {
    int tok = tok0 + i;
    float xc = silu_f(cbv + cwv.x * xls[tok] + cwv.y * xls[tok + 1] +
                      cwv.z * xls[tok + 2] + cwv.w * xls[tok + 3]);
    xcp[((tok >> 4) * 17) + (tok & 15)] = xc;
  }
  float d0 = dv.x, d1 = dv.y, d2 = dv.z, d3 = dv.w;
  uvl[((tok0 >> 4) * 17) + (tok0 & 15)]             = d0;
  uvl[(((tok0 + 1) >> 4) * 17) + ((tok0 + 1) & 15)] = d1;
  uvl[(((tok0 + 2) >> 4) * 17) + ((tok0 + 2) & 15)] = d2;
  uvl[(((tok0 + 3) >> 4) * 17) + ((tok0 + 3) & 15)] = d3;
  // ---- global inclusive prefix of delta ----
  float c0 = d0, c1 = c0 + d1, c2 = c1 + d2, c3 = c2 + d3;
  float sc = c3;
#pragma unroll
  for (int off = 1; off < 64; off <<= 1) {
    float u = __shfl_up(sc, off);
    if (lane >= off) sc += u;
  }
  if (lane == 63) wtot[wv] = sc;
  __syncthreads();                       // B2: conv xls-reads done; wtot visible
  {
    float base = sc - c3;
#pragma unroll
    for (int i = 0; i < 3; i++) if (i < wv) base += wtot[i];
    dlp[((tok0 >> 4) * 17) + (tok0 & 15)]             = base + c0;
    dlp[(((tok0 + 1) >> 4) * 17) + ((tok0 + 1) & 15)] = base + c1;
    dlp[(((tok0 + 2) >> 4) * 17) + ((tok0 + 2) & 15)] = base + c2;
    dlp[(((tok0 + 3) >> 4) * 17) + ((tok0 + 3) & 15)] = base + c3;
  }
#pragma unroll
  for (int i = 0; i < 4; i++) {
    int tok = tok0 + i;
    int p = ((tok >> 4) * 17) + (tok & 15);
    uvl[p] = uvl[p] * xcp[p];            // uv = delta * conv_x
  }
  __syncthreads();                       // B3: Dl + uv visible

  int pb = lane * 17;
  float y[16];
#pragma unroll
  for (int i = 0; i < 16; i++) y[i] = 0.f;
  float Dprev = (lane == 0) ? 0.f : dlp[pb - 2];

#pragma unroll 1
  for (int r = 0; r < 4; r++) {
    int n = (wv << 2) + r;
    float An = -__expf(alog[d * NST + n]);
    float st = cs[(size_t)(b * DDIM + d) * NST + n];
    const float* pB = projT + (size_t)(64 + n) * BL + colbase + (lane << 4);
    const float* pC = pB + (size_t)16 * BL;
    float Pp = __expf(An * Dprev);
    float sl = 0.f;
#pragma unroll
    for (int c = 0; c < 4; c++) {
      float4 bv = *(const float4*)(pB + c * 4);
      float4 cv = *(const float4*)(pC + c * 4);
      float bvs[4] = {bv.x, bv.y, bv.z, bv.w};
      float cvs[4] = {cv.x, cv.y, cv.z, cv.w};
#pragma unroll
      for (int j = 0; j < 4; j++) {
        int i = c * 4 + j;
        float P = __expf(An * dlp[pb + i]);
        float w = uvl[pb + i] * bvs[j] * __builtin_amdgcn_rcpf(fmaxf(Pp, 1e-10f));
        sl += w;
        y[i] += (sl * Pp + st * P) * cvs[j];
        Pp = P;
      }
    }
    float s2 = sl;
#pragma unroll
    for (int off = 1; off < 64; off <<= 1) {
      float u = __shfl_up(s2, off);
      if (lane >= off) s2 += u;
    }
    float Soff = s2 - sl;
#pragma unroll
    for (int c = 0; c < 4; c++) {
      float4 cv = *(const float4*)(pC + c * 4);
      float cvs[4] = {cv.x, cv.y, cv.z, cv.w};
#pragma unroll
      for (int j = 0; j < 4; j++) {
        int i = c * 4 + j;
        float dlm = (i == 0) ? Dprev : dlp[pb + i - 1];
        y[i] += Soff * __expf(An * dlm) * cvs[j];
      }
    }
  }
  __syncthreads();                       // B4
  if (wv == 2) {
#pragma unroll
    for (int i = 0; i < 16; i++) uvl[pb + i] = y[i];
  } else if (wv == 3) {
#pragma unroll
    for (int i = 0; i < 16; i++) dlp[pb + i] = y[i];
  }
  __syncthreads();                       // B5
  if (wv == 0) {
#pragma unroll
    for (int i = 0; i < 16; i++) uvl[pb + i] += y[i];
  } else if (wv == 1) {
#pragma unroll
    for (int i = 0; i < 16; i++) dlp[pb + i] += y[i];
  }
  __syncthreads();                       // B6
#pragma unroll
  for (int i = 0; i < 4; i++) {
    int tok = tok0 + i;
    int p = ((tok >> 4) * 17) + (tok & 15);
    float yv = uvl[p] + dlp[p] + xcp[p] * Dp;
    float g = bf2f(gcol[(size_t)tok * 4096]);
    ycol[(size_t)tok * DDIM] = f2bf(yv * silu_f(g));
  }
}

extern "C" void kernel_launch(void* const* d_in, const int* in_sizes, int n_in,
                              void* d_out, int out_size, void* d_ws, size_t ws_size,
                              hipStream_t stream) {
  const float* inp    = (const float*)d_in[0];
  const float* cstate = (const float*)d_in[1];
  const float* norm_w = (const float*)d_in[2];
  const float* w1     = (const float*)d_in[3];
  const float* b1     = (const float*)d_in[4];
  const float* convw  = (const float*)d_in[5];
  const float* convb  = (const float*)d_in[6];
  const float* xpw    = (const float*)d_in[7];
  const float* xpb    = (const float*)d_in[8];
  const float* dtw    = (const float*)d_in[9];
  const float* dtb    = (const float*)d_in[10];
  const float* alog   = (const float*)d_in[11];
  const float* dparam = (const float*)d_in[12];
  const float* wo     = (const float*)d_in[13];
  const float* bo     = (const float*)d_in[14];
  float* out = (float*)d_out;

  // workspace layout (ws >= 56,156,160 B confirmed by R6/R8 runs)
  char* wsb = (char*)d_ws;
  u16*   w1b    = (u16*)(wsb + 0);            //  8,388,608 B  [4096][1024] bf16
  u16*   wob    = (u16*)(wsb + 8388608);      //  4,194,304 B  [1024][2048] bf16
  u16*   whb    = (u16*)(wsb + 12591104);     //    393,216 B  xpw hi bf16 [96][2048]
  u16*   wlb    = (u16*)(wsb + 12984320);     //    393,216 B  xpw lo bf16 [96][2048]
  float* projT  = (float*)(wsb + 13377536);   //    786,432 B  [96][2048] f32
  u16*   xgb    = (u16*)(wsb + 14163968);     // 16,826,368 B  [2][1027][4096] bf16
  u16*   yb     = (u16*)(wsb + 30990336);     //  8,388,608 B  [2][1024][2048] bf16
  u16*   xnb    = yb;                         //  aliases yb (consumed before scan writes)
  float* deltaT = (float*)(wsb + 39378944);   // 16,777,216 B  [2048 d][2048 tok] f32
  float* pscr   = deltaT;                     //  first 786,432 B reused as K-partial scratch
                                              //  (read by k_xcomb BEFORE k_delta writes)

  k_castw<<<4096, 256, 0, stream>>>(w1, w1b);
  k_castw<<<2048, 256, 0, stream>>>(wo, wob);
  k_castsplit<<<192, 256, 0, stream>>>(xpw, whb, wlb);
  k_rowscale2<<<BL, 256, 0, stream>>>(inp, norm_w, xnb);
  k_gemm1b<<<dim3(32, 16), 256, 0, stream>>>(xnb, w1b, b1, xgb);
  k_zerohalo<<<24, 256, 0, stream>>>(xgb);
  k_xprojT<<<64, 256, 0, stream>>>(xgb, whb, wlb, convw, convb, projT, pscr);
  k_xcomb<<<192, 256, 0, stream>>>(projT, pscr, xpb);
  k_delta<<<1024, 256, 0, stream>>>(projT, dtw, dtb, deltaT);
  k_scan2<<<2 * DDIM, 256, 0, stream>>>(projT, deltaT, xgb, convw, convb,
                                        alog, dparam, cstate, yb);
  k_gemm2b<<<dim3(16, 16), 256, 0, stream>>>(yb, wob, bo, inp, out);
}

// Round 10
// 290.596 us; speedup vs baseline: 2.0431x; 1.1550x over previous
//
#include <hip/hip_runtime.h>
#include <stdint.h>

#define LSEQ 1024
#define HDIM 1024
#define DDIM 2048
#define BL 2048
#define NST 16
#define XR 1027          // 3 halo rows (zeroed by k_zerohalo) + 1024 tokens

typedef unsigned short u16;
typedef __attribute__((ext_vector_type(8))) short bf16x8;
typedef __attribute__((ext_vector_type(4))) float f32x4;

// silu via v_rcp (1-ulp rcp; output tolerance is bf16-dominated)
static __device__ __forceinline__ float silu_f(float v) {
  return v * __builtin_amdgcn_rcpf(1.f + __expf(-v));
}
static __device__ __forceinline__ float bf2f(u16 u) {
  union { float f; unsigned int i; } c; c.i = ((unsigned int)u) << 16; return c.f;
}
static __device__ __forceinline__ u16 f2bf(float f) {
  union { float f; unsigned int i; } c; c.f = f;
  unsigned int r = c.i + 0x7fffu + ((c.i >> 16) & 1u);
  return (u16)(r >> 16);
}
static __device__ __forceinline__ float softplus_f(float v) {
  return (v > 20.f) ? v : __logf(1.f + __expf(v));
}

// ---------------- cast fp32 -> bf16 (weights, once per launch) ----------------
__global__ __launch_bounds__(256) void k_castw(const float* __restrict__ src,
                                               u16* __restrict__ dst) {
  int idx = blockIdx.x * 256 + threadIdx.x;
  float4 v = ((const float4*)src)[idx];
  ushort4 o;
  o.x = f2bf(v.x); o.y = f2bf(v.y); o.z = f2bf(v.z); o.w = f2bf(v.w);
  ((ushort4*)dst)[idx] = o;
}

// ---------------- cast fp32 -> split bf16 hi/lo (xpw) ----------------
__global__ __launch_bounds__(256) void k_castsplit(const float* __restrict__ src,
                                                   u16* __restrict__ hi,
                                                   u16* __restrict__ lo) {
  int idx = blockIdx.x * 256 + threadIdx.x;
  float4 v = ((const float4*)src)[idx];
  ushort4 h, l;
  h.x = f2bf(v.x); l.x = f2bf(v.x - bf2f(h.x));
  h.y = f2bf(v.y); l.y = f2bf(v.y - bf2f(h.y));
  h.z = f2bf(v.z); l.z = f2bf(v.z - bf2f(h.z));
  h.w = f2bf(v.w); l.w = f2bf(v.w - bf2f(h.w));
  ((ushort4*)hi)[idx] = h;
  ((ushort4*)lo)[idx] = l;
}

// ---------------- zero the 3 halo rows of each batch stripe in xgb ----------------
__global__ __launch_bounds__(256) void k_zerohalo(u16* __restrict__ xgb) {
  int idx = blockIdx.x * 256 + threadIdx.x;       // 6144 ushort4 total (24 blocks)
  int b = idx / 3072;
  int r = idx - b * 3072;
  ushort4 z4 = {0, 0, 0, 0};
  ((ushort4*)(xgb + (size_t)b * XR * 4096))[r] = z4;
}

// ---------------- per-row rmsnorm + normalize -> xnb bf16 [2048][1024] ----------------
__global__ __launch_bounds__(256) void k_rowscale2(const float* __restrict__ inp,
                                                   const float* __restrict__ nw,
                                                   u16* __restrict__ xnb) {
  int row = blockIdx.x;
  int t = threadIdx.x;
  float4 xv = *(const float4*)(inp + (size_t)row * HDIM + t * 4);
  float ss = xv.x * xv.x + xv.y * xv.y + xv.z * xv.z + xv.w * xv.w;
  for (int off = 32; off > 0; off >>= 1) ss += __shfl_down(ss, off);
  __shared__ float red[4];
  if ((t & 63) == 0) red[t >> 6] = ss;
  __syncthreads();
  float tot = red[0] + red[1] + red[2] + red[3];
  float scale = rsqrtf(tot * (1.f / HDIM) + 1e-6f);
  float4 nv = *(const float4*)(nw + t * 4);
  ushort4 o;
  o.x = f2bf(xv.x * scale * nv.x); o.y = f2bf(xv.y * scale * nv.y);
  o.z = f2bf(xv.z * scale * nv.z); o.w = f2bf(xv.w * scale * nv.w);
  ((ushort4*)xnb)[row * 256 + t] = o;
}

// ---------------- K1: in_proj GEMM, 128x128 tile, pure bf16 ----------------
__global__ __launch_bounds__(256) void k_gemm1b(const u16* __restrict__ A,
                                                const u16* __restrict__ W,
                                                const float* __restrict__ bias,
                                                u16* __restrict__ xgb) {
  __shared__ u16 Asm[128 * 40];
  __shared__ u16 Wsm[128 * 40];
  int t = threadIdx.x;
  int m0 = blockIdx.y * 128, n0 = blockIdx.x * 128;
  int srow = t >> 1, koff = (t & 1) * 16;
  const u16* Ag = A + (size_t)(m0 + srow) * HDIM + koff;
  const u16* Wg = W + (size_t)(n0 + srow) * HDIM + koff;
  int w = t >> 6, lane = t & 63;
  int wr = w >> 1, wc = w & 1;
  int quad = lane >> 4, mr = lane & 15;
  f32x4 z = {0.f, 0.f, 0.f, 0.f};
  f32x4 acc[4][4] = {{z, z, z, z}, {z, z, z, z}, {z, z, z, z}, {z, z, z, z}};
  const u16* arp = &Asm[(wr * 64 + mr) * 40 + quad * 8];
  const u16* brp = &Wsm[(wc * 64 + mr) * 40 + quad * 8];
  for (int k0 = 0; k0 < HDIM; k0 += 32) {
    uint4 a0 = *(const uint4*)(Ag + k0);
    uint4 a1 = *(const uint4*)(Ag + k0 + 8);
    uint4 w0 = *(const uint4*)(Wg + k0);
    uint4 w1 = *(const uint4*)(Wg + k0 + 8);
    __syncthreads();
    *(uint4*)(&Asm[srow * 40 + koff]) = a0;
    *(uint4*)(&Asm[srow * 40 + koff + 8]) = a1;
    *(uint4*)(&Wsm[srow * 40 + koff]) = w0;
    *(uint4*)(&Wsm[srow * 40 + koff + 8]) = w1;
    __syncthreads();
    bf16x8 af[4], bf[4];
#pragma unroll
    for (int i = 0; i < 4; i++) {
      af[i] = *(const bf16x8*)(arp + i * 16 * 40);
      bf[i] = *(const bf16x8*)(brp + i * 16 * 40);
    }
#pragma unroll
    for (int mi = 0; mi < 4; mi++)
#pragma unroll
      for (int ni = 0; ni < 4; ni++)
        acc[mi][ni] = __builtin_amdgcn_mfma_f32_16x16x32_bf16(af[mi], bf[ni],
                                                              acc[mi][ni], 0, 0, 0);
  }
#pragma unroll
  for (int ni = 0; ni < 4; ni++) {
    int col = n0 + wc * 64 + ni * 16 + mr;
    float bv = bias[col];
#pragma unroll
    for (int mi = 0; mi < 4; mi++) {
#pragma unroll
      for (int rr2 = 0; rr2 < 4; rr2++) {
        int rr = m0 + wr * 64 + mi * 16 + quad * 4 + rr2;
        int row = (rr >> 10) * XR + 3 + (rr & 1023);
        xgb[(size_t)row * 4096 + col] = f2bf(acc[mi][ni][rr2] + bv);
      }
    }
  }
}

// ---------------- K4: out_proj GEMM, 128x64 tile + bias + residual ----------------
__global__ __launch_bounds__(256) void k_gemm2b(const u16* __restrict__ A,
                                                const u16* __restrict__ W,
                                                const float* __restrict__ bias,
                                                const float* __restrict__ resid,
                                                float* __restrict__ out) {
  __shared__ u16 Asm[128 * 40];
  __shared__ u16 Wsm[64 * 40];
  int t = threadIdx.x;
  int m0 = blockIdx.y * 128, n0 = blockIdx.x * 64;
  int srow = t >> 1, koff = (t & 1) * 16;
  const u16* Ag = A + (size_t)(m0 + srow) * DDIM + koff;
  const u16* Wg = W + (size_t)(n0 + (srow & 63)) * DDIM + koff;
  int w = t >> 6, lane = t & 63;
  int wr = w >> 1, wc = w & 1;
  int quad = lane >> 4, mr = lane & 15;
  f32x4 z = {0.f, 0.f, 0.f, 0.f};
  f32x4 acc[4][2] = {{z, z}, {z, z}, {z, z}, {z, z}};
  const u16* arp = &Asm[(wr * 64 + mr) * 40 + quad * 8];
  const u16* brp = &Wsm[(wc * 32 + mr) * 40 + quad * 8];
  for (int k0 = 0; k0 < DDIM; k0 += 32) {
    uint4 a0 = *(const uint4*)(Ag + k0);
    uint4 a1 = *(const uint4*)(Ag + k0 + 8);
    uint4 w0, w1;
    if (t < 128) {
      w0 = *(const uint4*)(Wg + k0);
      w1 = *(const uint4*)(Wg + k0 + 8);
    }
    __syncthreads();
    *(uint4*)(&Asm[srow * 40 + koff]) = a0;
    *(uint4*)(&Asm[srow * 40 + koff + 8]) = a1;
    if (t < 128) {
      *(uint4*)(&Wsm[srow * 40 + koff]) = w0;
      *(uint4*)(&Wsm[srow * 40 + koff + 8]) = w1;
    }
    __syncthreads();
    bf16x8 af[4], bf[2];
#pragma unroll
    for (int i = 0; i < 4; i++) af[i] = *(const bf16x8*)(arp + i * 16 * 40);
#pragma unroll
    for (int i = 0; i < 2; i++) bf[i] = *(const bf16x8*)(brp + i * 16 * 40);
#pragma unroll
    for (int mi = 0; mi < 4; mi++)
#pragma unroll
      for (int ni = 0; ni < 2; ni++)
        acc[mi][ni] = __builtin_amdgcn_mfma_f32_16x16x32_bf16(af[mi], bf[ni],
                                                              acc[mi][ni], 0, 0, 0);
  }
#pragma unroll
  for (int ni = 0; ni < 2; ni++) {
    int col = n0 + wc * 32 + ni * 16 + mr;
    float bv = bias[col];
#pragma unroll
    for (int mi = 0; mi < 4; mi++) {
#pragma unroll
      for (int rr2 = 0; rr2 < 4; rr2++) {
        int row = m0 + wr * 64 + mi * 16 + quad * 4 + rr2;
        out[(size_t)row * HDIM + col] =
            acc[mi][ni][rr2] + bv + resid[(size_t)row * HDIM + col];
      }
    }
  }
}

// ---------------- K2 v3: fused conv+silu + x_proj GEMM -> projT, 16 K-partitions ----
// R9's 64-block version was a latency chain (32 serial iters, 4 waves, 200 CUs
// idle) ~80us.  Now 32 token-tiles x 16 K-partitions (K=128, 4 iters) = 512
// blocks (2/CU).  Partition 0 -> projT, 1..15 -> scratch; k_xcomb sums + bias.
__global__ __launch_bounds__(256) void k_xprojT(const u16* __restrict__ xgb,
                                                const u16* __restrict__ whb,
                                                const u16* __restrict__ wlb,
                                                const float* __restrict__ cw,
                                                const float* __restrict__ cb,
                                                float* __restrict__ projT,
                                                float* __restrict__ pscr) {
  __shared__ u16 Xst[67 * 40];     // raw x rows tok-3 .. tok+63
  __shared__ u16 XH[64 * 40];      // xc hi
  __shared__ u16 XL[64 * 40];      // xc lo
  __shared__ u16 WH[96 * 40];      // w hi
  __shared__ u16 WL[96 * 40];      // w lo
  int t = threadIdx.x;
  int tt = blockIdx.x & 31, ks = blockIdx.x >> 5;          // 32 tok-tiles x 16 K-parts
  int tokbase = tt << 6;
  int b = tokbase >> 10, l0 = tokbase & 1023;
  int kbase = ks << 7;                                     // 128 K per partition
  const u16* xbase = xgb + (size_t)(b * XR + l0) * 4096;   // raw row i <-> tok tokbase-3+i
  float* outp = (ks == 0) ? projT : (pscr + (size_t)(ks - 1) * 196608);
  int dlane = t & 31, tokg = t >> 5;                       // conv mapping: 8 tok x 32 d
  int wvq = t >> 6, lane = t & 63;
  int quad = lane >> 4, mr = lane & 15;
  f32x4 z = {0.f, 0.f, 0.f, 0.f};
  f32x4 acc[6] = {z, z, z, z, z, z};

  for (int it = 0; it < 4; it++) {
    int kc = kbase + (it << 5);
    // stage raw x tile [67][32]
    for (int idx = t; idx < 268; idx += 256) {
      int r = idx >> 2, p = idx & 3;
      uint4 v = *(const uint4*)(xbase + (size_t)r * 4096 + kc + p * 8);
      *(uint4*)(&Xst[r * 40 + p * 8]) = v;
    }
    // stage w hi/lo tiles [96][32]
    for (int idx = t; idx < 384; idx += 256) {
      int r = idx >> 2, p = idx & 3;
      *(uint4*)(&WH[r * 40 + p * 8]) = *(const uint4*)(whb + (size_t)r * 2048 + kc + p * 8);
      *(uint4*)(&WL[r * 40 + p * 8]) = *(const uint4*)(wlb + (size_t)r * 2048 + kc + p * 8);
    }
    __syncthreads();
    // conv + silu + bf16-split; thread owns 8 consecutive tokens at one d
    {
      int d = kc + dlane;
      float4 cwv = *(const float4*)(cw + d * 4);
      float cbv = cb[d];
      float xr[11];
#pragma unroll
      for (int j = 0; j < 11; j++) xr[j] = bf2f(Xst[(tokg * 8 + j) * 40 + dlane]);
#pragma unroll
      for (int jj = 0; jj < 8; jj++) {
        float xc = silu_f(cbv + cwv.x * xr[jj] + cwv.y * xr[jj + 1] +
                          cwv.z * xr[jj + 2] + cwv.w * xr[jj + 3]);
        u16 h = f2bf(xc);
        u16 l = f2bf(xc - bf2f(h));
        XH[(tokg * 8 + jj) * 40 + dlane] = h;
        XL[(tokg * 8 + jj) * 40 + dlane] = l;
      }
    }
    __syncthreads();
    // MFMA: C[o][tok], af = w rows, bf = xc rows; wave wvq owns 16 tokens
    bf16x8 xh = *(const bf16x8*)(&XH[(wvq * 16 + mr) * 40 + quad * 8]);
    bf16x8 xl = *(const bf16x8*)(&XL[(wvq * 16 + mr) * 40 + quad * 8]);
#pragma unroll
    for (int mi = 0; mi < 6; mi++) {
      bf16x8 wh = *(const bf16x8*)(&WH[(mi * 16 + mr) * 40 + quad * 8]);
      bf16x8 wl = *(const bf16x8*)(&WL[(mi * 16 + mr) * 40 + quad * 8]);
      acc[mi] = __builtin_amdgcn_mfma_f32_16x16x32_bf16(wh, xh, acc[mi], 0, 0, 0);
      acc[mi] = __builtin_amdgcn_mfma_f32_16x16x32_bf16(wh, xl, acc[mi], 0, 0, 0);
      acc[mi] = __builtin_amdgcn_mfma_f32_16x16x32_bf16(wl, xh, acc[mi], 0, 0, 0);
    }
    __syncthreads();
  }
  // epilogue: row = o, col = tok
#pragma unroll
  for (int mi = 0; mi < 6; mi++) {
#pragma unroll
    for (int rr = 0; rr < 4; rr++) {
      int o = mi * 16 + quad * 4 + rr;
      outp[(size_t)o * BL + tokbase + wvq * 16 + mr] = acc[mi][rr];
    }
  }
}

// ---------------- K2d: combine 16 K-partials + bias into projT ----------------
__global__ __launch_bounds__(256) void k_xcomb(float* __restrict__ projT,
                                               const float* __restrict__ scr,
                                               const float* __restrict__ xpb) {
  int idx = blockIdx.x * 256 + threadIdx.x;   // float4 over [96][2048]
  int o = idx >> 9;
  float4 a = ((const float4*)projT)[idx];
  float bv = xpb[o];
  float sx = bv, sy = bv, sz = bv, sw = bv;
#pragma unroll
  for (int p = 0; p < 15; p++) {
    float4 s = ((const float4*)(scr + (size_t)p * 196608))[idx];
    sx += s.x; sy += s.y; sz += s.z; sw += s.w;
  }
  a.x += sx; a.y += sy; a.z += sz; a.w += sw;
  ((float4*)projT)[idx] = a;
}

// ---------------- K2c: delta GEMM: deltaT[2048 d][2048 tok] = softplus(dtw.projT + dtb) ----
__global__ __launch_bounds__(256) void k_delta(const float* __restrict__ projT,
                                               const float* __restrict__ dtw,
                                               const float* __restrict__ dtb,
                                               float* __restrict__ deltaT) {
  __shared__ float dw_s[16][64];
  int t = threadIdx.x;
  int d0 = (blockIdx.x >> 3) * 16;
  int tokbase = (blockIdx.x & 7) * 256;
  {
    const float* src = dtw + (size_t)d0 * 64;
#pragma unroll
    for (int i = 0; i < 4; i++) {
      int idx = t + i * 256;
      dw_s[idx >> 6][idx & 63] = src[idx];
    }
  }
  __syncthreads();
  int tq = t & 63, dq = t >> 6;
  const float* pr = projT + tokbase + tq * 4;
  int dbase = d0 + dq * 4;
  float acc[4][4];
#pragma unroll
  for (int di = 0; di < 4; di++) {
    float bv = dtb[dbase + di];
    acc[di][0] = bv; acc[di][1] = bv; acc[di][2] = bv; acc[di][3] = bv;
  }
#pragma unroll 8
  for (int r = 0; r < 64; r++) {
    float4 pv = *(const float4*)(pr + (size_t)r * BL);
#pragma unroll
    for (int di = 0; di < 4; di++) {
      float wk = dw_s[dq * 4 + di][r];
      acc[di][0] += pv.x * wk; acc[di][1] += pv.y * wk;
      acc[di][2] += pv.z * wk; acc[di][3] += pv.w * wk;
    }
  }
#pragma unroll
  for (int di = 0; di < 4; di++) {
    float4 o;
    o.x = softplus_f(acc[di][0]); o.y = softplus_f(acc[di][1]);
    o.z = softplus_f(acc[di][2]); o.w = softplus_f(acc[di][3]);
    *(float4*)(deltaT + (size_t)(dbase + di) * BL + tokbase + tq * 4) = o;
  }
}

// ---------------- K3 v2: selective scan, delta precomputed by k_delta ----------------
__global__ __launch_bounds__(256) void k_scan2(const float* __restrict__ projT,
                                               const float* __restrict__ deltaT,
                                               const u16* __restrict__ xgb,
                                               const float* __restrict__ cw,
                                               const float* __restrict__ cb,
                                               const float* __restrict__ alog,
                                               const float* __restrict__ dparam,
                                               const float* __restrict__ cs,
                                               u16* __restrict__ yb) {
  __shared__ float wtot[4];
  __shared__ float xcp[1088];
  __shared__ float uvl[1088];
  __shared__ float dlp[1088];

  int t = threadIdx.x;
  int cidx = ((blockIdx.x & 7) << 9) | (blockIdx.x >> 3);   // (b,d)
  int b = cidx >> 11;
  int d = cidx & (DDIM - 1);
  int wv = t >> 6, lane = t & 63;

  float4 cwv = *(const float4*)(cw + d * 4);
  float cbv = cb[d];
  float Dp = dparam[d];
  const u16* xcol = xgb + (size_t)(b * XR + 3) * 4096 + d;
  const u16* gcol = xcol + DDIM;
  u16* ycol = yb + ((size_t)(b << 10)) * DDIM + d;
  int colbase = b << 10;
  int tok0 = t << 2;

  float4 dv = *(const float4*)(deltaT + (size_t)d * BL + colbase + tok0);

  float* xls = dlp;
  if (t < 3) xls[t] = 0.f;
#pragma unroll
  for (int k = 0; k < 4; k++) {
    int tok = t + (k << 8);
    xls[3 + tok] = bf2f(xcol[(size_t)tok * 4096]);
  }
  __syncthreads();                       // B1

#pragma unroll
  for (int i = 0; i < 4; i++) {
    int tok = tok0 + i;
    float xc = silu_f(cbv + cwv.x * xls[tok] + cwv.y * xls[tok + 1] +
                      cwv.z * xls[tok + 2] + cwv.w * xls[tok + 3]);
    xcp[((tok >> 4) * 17) + (tok & 15)] = xc;
  }
  float d0 = dv.x, d1 = dv.y, d2 = dv.z, d3 = dv.w;
  uvl[((tok0 >> 4) * 17) + (tok0 & 15)]             = d0;
  uvl[(((tok0 + 1) >> 4) * 17) + ((tok0 + 1) & 15)] = d1;
  uvl[(((tok0 + 2) >> 4) * 17) + ((tok0 + 2) & 15)] = d2;
  uvl[(((tok0 + 3) >> 4) * 17) + ((tok0 + 3) & 15)] = d3;
  float c0 = d0, c1 = c0 + d1, c2 = c1 + d2, c3 = c2 + d3;
  float sc = c3;
#pragma unroll
  for (int off = 1; off < 64; off <<= 1) {
    float u = __shfl_up(sc, off);
    if (lane >= off) sc += u;
  }
  if (lane == 63) wtot[wv] = sc;
  __syncthreads();                       // B2
  {
    float base = sc - c3;
#pragma unroll
    for (int i = 0; i < 3; i++) if (i < wv) base += wtot[i];
    dlp[((tok0 >> 4) * 17) + (tok0 & 15)]             = base + c0;
    dlp[(((tok0 + 1) >> 4) * 17) + ((tok0 + 1) & 15)] = base + c1;
    dlp[(((tok0 + 2) >> 4) * 17) + ((tok0 + 2) & 15)] = base + c2;
    dlp[(((tok0 + 3) >> 4) * 17) + ((tok0 + 3) & 15)] = base + c3;
  }
#pragma unroll
  for (int i = 0; i < 4; i++) {
    int tok = tok0 + i;
    int p = ((tok >> 4) * 17) + (tok & 15);
    uvl[p] = uvl[p] * xcp[p];
  }
  __syncthreads();                       // B3

  int pb = lane * 17;
  float y[16];
#pragma unroll
  for (int i = 0; i < 16; i++) y[i] = 0.f;
  float Dprev = (lane == 0) ? 0.f : dlp[pb - 2];

#pragma unroll 1
  for (int r = 0; r < 4; r++) {
    int n = (wv << 2) + r;
    float An = -__expf(alog[d * NST + n]);
    float st = cs[(size_t)(b * DDIM + d) * NST + n];
    const float* pB = projT + (size_t)(64 + n) * BL + colbase + (lane << 4);
    const float* pC = pB + (size_t)16 * BL;
    float Pp = __expf(An * Dprev);
    float sl = 0.f;
#pragma unroll
    for (int c = 0; c < 4; c++) {
      float4 bv = *(const float4*)(pB + c * 4);
      float4 cv = *(const float4*)(pC + c * 4);
      float bvs[4] = {bv.x, bv.y, bv.z, bv.w};
      float cvs[4] = {cv.x, cv.y, cv.z, cv.w};
#pragma unroll
      for (int j = 0; j < 4; j++) {
        int i = c * 4 + j;
        float P = __expf(An * dlp[pb + i]);
        float w = uvl[pb + i] * bvs[j] * __builtin_amdgcn_rcpf(fmaxf(Pp, 1e-10f));
        sl += w;
        y[i] += (sl * Pp + st * P) * cvs[j];
        Pp = P;
      }
    }
    float s2 = sl;
#pragma unroll
    for (int off = 1; off < 64; off <<= 1) {
      float u = __shfl_up(s2, off);
      if (lane >= off) s2 += u;
    }
    float Soff = s2 - sl;
#pragma unroll
    for (int c = 0; c < 4; c++) {
      float4 cv = *(const float4*)(pC + c * 4);
      float cvs[4] = {cv.x, cv.y, cv.z, cv.w};
#pragma unroll
      for (int j = 0; j < 4; j++) {
        int i = c * 4 + j;
        float dlm = (i == 0) ? Dprev : dlp[pb + i - 1];
        y[i] += Soff * __expf(An * dlm) * cvs[j];
      }
    }
  }
  __syncthreads();                       // B4
  if (wv == 2) {
#pragma unroll
    for (int i = 0; i < 16; i++) uvl[pb + i] = y[i];
  } else if (wv == 3) {
#pragma unroll
    for (int i = 0; i < 16; i++) dlp[pb + i] = y[i];
  }
  __syncthreads();                       // B5
  if (wv == 0) {
#pragma unroll
    for (int i = 0; i < 16; i++) uvl[pb + i] += y[i];
  } else if (wv == 1) {
#pragma unroll
    for (int i = 0; i < 16; i++) dlp[pb + i] += y[i];
  }
  __syncthreads();                       // B6
#pragma unroll
  for (int i = 0; i < 4; i++) {
    int tok = tok0 + i;
    int p = ((tok >> 4) * 17) + (tok & 15);
    float yv = uvl[p] + dlp[p] + xcp[p] * Dp;
    float g = bf2f(gcol[(size_t)tok * 4096]);
    ycol[(size_t)tok * DDIM] = f2bf(yv * silu_f(g));
  }
}

extern "C" void kernel_launch(void* const* d_in, const int* in_sizes, int n_in,
                              void* d_out, int out_size, void* d_ws, size_t ws_size,
                              hipStream_t stream) {
  const float* inp    = (const float*)d_in[0];
  const float* cstate = (const float*)d_in[1];
  const float* norm_w = (const float*)d_in[2];
  const float* w1     = (const float*)d_in[3];
  const float* b1     = (const float*)d_in[4];
  const float* convw  = (const float*)d_in[5];
  const float* convb  = (const float*)d_in[6];
  const float* xpw    = (const float*)d_in[7];
  const float* xpb    = (const float*)d_in[8];
  const float* dtw    = (const float*)d_in[9];
  const float* dtb    = (const float*)d_in[10];
  const float* alog   = (const float*)d_in[11];
  const float* dparam = (const float*)d_in[12];
  const float* wo     = (const float*)d_in[13];
  const float* bo     = (const float*)d_in[14];
  float* out = (float*)d_out;

  // workspace layout (ws >= 56,156,160 B confirmed)
  char* wsb = (char*)d_ws;
  u16*   w1b    = (u16*)(wsb + 0);            //  8,388,608 B  [4096][1024] bf16
  u16*   wob    = (u16*)(wsb + 8388608);      //  4,194,304 B  [1024][2048] bf16
  u16*   whb    = (u16*)(wsb + 12591104);     //    393,216 B  xpw hi bf16 [96][2048]
  u16*   wlb    = (u16*)(wsb + 12984320);     //    393,216 B  xpw lo bf16 [96][2048]
  float* projT  = (float*)(wsb + 13377536);   //    786,432 B  [96][2048] f32
  u16*   xgb    = (u16*)(wsb + 14163968);     // 16,826,368 B  [2][1027][4096] bf16
  u16*   yb     = (u16*)(wsb + 30990336);     //  8,388,608 B  [2][1024][2048] bf16
  u16*   xnb    = yb;                         //  aliases yb (consumed before scan writes)
  float* deltaT = (float*)(wsb + 39378944);   // 16,777,216 B  [2048 d][2048 tok] f32
  float* pscr   = deltaT;                     //  first 15*786,432 B = 11.8 MB reused as
                                              //  K-partial scratch (read by k_xcomb
                                              //  BEFORE k_delta writes deltaT)

  k_castw<<<4096, 256, 0, stream>>>(w1, w1b);
  k_castw<<<2048, 256, 0, stream>>>(wo, wob);
  k_castsplit<<<192, 256, 0, stream>>>(xpw, whb, wlb);
  k_rowscale2<<<BL, 256, 0, stream>>>(inp, norm_w, xnb);
  k_gemm1b<<<dim3(32, 16), 256, 0, stream>>>(xnb, w1b, b1, xgb);
  k_zerohalo<<<24, 256, 0, stream>>>(xgb);
  k_xprojT<<<512, 256, 0, stream>>>(xgb, whb, wlb, convw, convb, projT, pscr);
  k_xcomb<<<192, 256, 0, stream>>>(projT, pscr, xpb);
  k_delta<<<1024, 256, 0, stream>>>(projT, dtw, dtb, deltaT);
  k_scan2<<<2 * DDIM, 256, 0, stream>>>(projT, deltaT, xgb, convw, convb,
                                        alog, dparam, cstate, yb);
  k_gemm2b<<<dim3(16, 16), 256, 0, stream>>>(yb, wob, bo, inp, out);
}

// Round 12
// 274.194 us; speedup vs baseline: 2.1653x; 1.0598x over previous
//
#include <hip/hip_runtime.h>
#include <stdint.h>

#define LSEQ 1024
#define HDIM 1024
#define DDIM 2048
#define BL 2048
#define NST 16
#define XR 1027          // 3 halo rows (zeroed in k_prep) + 1024 tokens

typedef unsigned short u16;
typedef __attribute__((ext_vector_type(8))) short bf16x8;
typedef __attribute__((ext_vector_type(4))) float f32x4;

// silu via v_rcp (1-ulp rcp; output tolerance is bf16-dominated)
static __device__ __forceinline__ float silu_f(float v) {
  return v * __builtin_amdgcn_rcpf(1.f + __expf(-v));
}
static __device__ __forceinline__ float bf2f(u16 u) {
  union { float f; unsigned int i; } c; c.i = ((unsigned int)u) << 16; return c.f;
}
static __device__ __forceinline__ u16 f2bf(float f) {
  union { float f; unsigned int i; } c; c.f = f;
  unsigned int r = c.i + 0x7fffu + ((c.i >> 16) & 1u);
  return (u16)(r >> 16);
}
static __device__ __forceinline__ float softplus_f(float v) {
  return (v > 20.f) ? v : __logf(1.f + __expf(v));
}

// ---------------- fused prep: castw(w1), castw(wo), castsplit(xpw), zerohalo ----------------
__global__ __launch_bounds__(256) void k_prep(const float* __restrict__ w1,
                                              u16* __restrict__ w1b,
                                              const float* __restrict__ wo,
                                              u16* __restrict__ wob,
                                              const float* __restrict__ xpw,
                                              u16* __restrict__ whb,
                                              u16* __restrict__ wlb,
                                              u16* __restrict__ xgb) {
  int bidx = blockIdx.x;
  int t = threadIdx.x;
  if (bidx < 4096) {
    int idx = bidx * 256 + t;
    float4 v = ((const float4*)w1)[idx];
    ushort4 o;
    o.x = f2bf(v.x); o.y = f2bf(v.y); o.z = f2bf(v.z); o.w = f2bf(v.w);
    ((ushort4*)w1b)[idx] = o;
  } else if (bidx < 6144) {
    int idx = (bidx - 4096) * 256 + t;
    float4 v = ((const float4*)wo)[idx];
    ushort4 o;
    o.x = f2bf(v.x); o.y = f2bf(v.y); o.z = f2bf(v.z); o.w = f2bf(v.w);
    ((ushort4*)wob)[idx] = o;
  } else if (bidx < 6336) {
    int idx = (bidx - 6144) * 256 + t;
    float4 v = ((const float4*)xpw)[idx];
    ushort4 h, l;
    h.x = f2bf(v.x); l.x = f2bf(v.x - bf2f(h.x));
    h.y = f2bf(v.y); l.y = f2bf(v.y - bf2f(h.y));
    h.z = f2bf(v.z); l.z = f2bf(v.z - bf2f(h.z));
    h.w = f2bf(v.w); l.w = f2bf(v.w - bf2f(h.w));
    ((ushort4*)whb)[idx] = h;
    ((ushort4*)wlb)[idx] = l;
  } else {
    int idx = (bidx - 6336) * 256 + t;      // 6144 ushort4: 2 b x 3 rows x 1024
    int b = idx / 3072;
    int r = idx - b * 3072;
    ushort4 z4 = {0, 0, 0, 0};
    ((ushort4*)(xgb + (size_t)b * XR * 4096))[r] = z4;
  }
}

// ---------------- per-row rmsnorm + normalize -> xnb bf16 [2048][1024] ----------------
__global__ __launch_bounds__(256) void k_rowscale2(const float* __restrict__ inp,
                                                   const float* __restrict__ nw,
                                                   u16* __restrict__ xnb) {
  int row = blockIdx.x;
  int t = threadIdx.x;
  float4 xv = *(const float4*)(inp + (size_t)row * HDIM + t * 4);
  float ss = xv.x * xv.x + xv.y * xv.y + xv.z * xv.z + xv.w * xv.w;
  for (int off = 32; off > 0; off >>= 1) ss += __shfl_down(ss, off);
  __shared__ float red[4];
  if ((t & 63) == 0) red[t >> 6] = ss;
  __syncthreads();
  float tot = red[0] + red[1] + red[2] + red[3];
  float scale = rsqrtf(tot * (1.f / HDIM) + 1e-6f);
  float4 nv = *(const float4*)(nw + t * 4);
  ushort4 o;
  o.x = f2bf(xv.x * scale * nv.x); o.y = f2bf(xv.y * scale * nv.y);
  o.z = f2bf(xv.z * scale * nv.z); o.w = f2bf(xv.w * scale * nv.w);
  ((ushort4*)xnb)[row * 256 + t] = o;
}

// ---------------- K1: in_proj GEMM, 128x128 tile, pure bf16 ----------------
__global__ __launch_bounds__(256) void k_gemm1b(const u16* __restrict__ A,
                                                const u16* __restrict__ W,
                                                const float* __restrict__ bias,
                                                u16* __restrict__ xgb) {
  __shared__ u16 Asm[128 * 40];
  __shared__ u16 Wsm[128 * 40];
  int t = threadIdx.x;
  int m0 = blockIdx.y * 128, n0 = blockIdx.x * 128;
  int srow = t >> 1, koff = (t & 1) * 16;
  const u16* Ag = A + (size_t)(m0 + srow) * HDIM + koff;
  const u16* Wg = W + (size_t)(n0 + srow) * HDIM + koff;
  int w = t >> 6, lane = t & 63;
  int wr = w >> 1, wc = w & 1;
  int quad = lane >> 4, mr = lane & 15;
  f32x4 z = {0.f, 0.f, 0.f, 0.f};
  f32x4 acc[4][4] = {{z, z, z, z}, {z, z, z, z}, {z, z, z, z}, {z, z, z, z}};
  const u16* arp = &Asm[(wr * 64 + mr) * 40 + quad * 8];
  const u16* brp = &Wsm[(wc * 64 + mr) * 40 + quad * 8];
  for (int k0 = 0; k0 < HDIM; k0 += 32) {
    uint4 a0 = *(const uint4*)(Ag + k0);
    uint4 a1 = *(const uint4*)(Ag + k0 + 8);
    uint4 w0 = *(const uint4*)(Wg + k0);
    uint4 w1 = *(const uint4*)(Wg + k0 + 8);
    __syncthreads();
    *(uint4*)(&Asm[srow * 40 + koff]) = a0;
    *(uint4*)(&Asm[srow * 40 + koff + 8]) = a1;
    *(uint4*)(&Wsm[srow * 40 + koff]) = w0;
    *(uint4*)(&Wsm[srow * 40 + koff + 8]) = w1;
    __syncthreads();
    bf16x8 af[4], bf[4];
#pragma unroll
    for (int i = 0; i < 4; i++) {
      af[i] = *(const bf16x8*)(arp + i * 16 * 40);
      bf[i] = *(const bf16x8*)(brp + i * 16 * 40);
    }
#pragma unroll
    for (int mi = 0; mi < 4; mi++)
#pragma unroll
      for (int ni = 0; ni < 4; ni++)
        acc[mi][ni] = __builtin_amdgcn_mfma_f32_16x16x32_bf16(af[mi], bf[ni],
                                                              acc[mi][ni], 0, 0, 0);
  }
#pragma unroll
  for (int ni = 0; ni < 4; ni++) {
    int col = n0 + wc * 64 + ni * 16 + mr;
    float bv = bias[col];
#pragma unroll
    for (int mi = 0; mi < 4; mi++) {
#pragma unroll
      for (int rr2 = 0; rr2 < 4; rr2++) {
        int rr = m0 + wr * 64 + mi * 16 + quad * 4 + rr2;
        int row = (rr >> 10) * XR + 3 + (rr & 1023);
        xgb[(size_t)row * 4096 + col] = f2bf(acc[mi][ni][rr2] + bv);
      }
    }
  }
}

// ---------------- K1b: transpose x-half of xgb -> xT[2048 d][2048 tok] (bf16) ----------------
// Makes scan2's x staging a coalesced row read (was a stride-8KB column gather).
// Same bf16 values -> scan2's conv output is bitwise identical.
__global__ __launch_bounds__(256) void k_xT(const u16* __restrict__ xgb,
                                            u16* __restrict__ xT) {
  __shared__ u16 tile[64][66];      // row stride 66 u16 = 33 dwords (odd -> conflict-free cols)
  int dt = blockIdx.x & 31;         // d-tile (64 d)
  int tt = blockIdx.x >> 5;         // tok-tile (64 tok)
  int gtok0 = tt << 6;
  int b = gtok0 >> 10, l0 = gtok0 & 1023;
  int d0 = dt << 6;
  int t = threadIdx.x;
  const u16* src = xgb + (size_t)(b * XR + 3 + l0) * 4096 + d0;
  // load 64 token-rows x 32 uints (4B) each
#pragma unroll
  for (int i = 0; i < 8; i++) {
    int idx = t + i * 256;          // 0..2047
    int row = idx >> 5, uc = idx & 31;
    unsigned int v = *(const unsigned int*)(src + (size_t)row * 4096 + uc * 2);
    tile[row][uc * 2]     = (u16)(v & 0xffffu);
    tile[row][uc * 2 + 1] = (u16)(v >> 16);
  }
  __syncthreads();
  // store 64 d-rows x 32 uints (pairs of consecutive tokens)
#pragma unroll
  for (int i = 0; i < 8; i++) {
    int idx = t + i * 256;
    int r = idx >> 5, c2 = idx & 31;          // d-row r, token pair c2
    unsigned int lo = tile[c2 * 2][r];
    unsigned int hi = tile[c2 * 2 + 1][r];
    *(unsigned int*)(xT + (size_t)(d0 + r) * 2048 + gtok0 + c2 * 2) = lo | (hi << 16);
  }
}

// ---------------- K4: out_proj GEMM, 128x64 tile, split-K x2 -> f32 partials ----------------
__global__ __launch_bounds__(256) void k_gemm2b(const u16* __restrict__ A,
                                                const u16* __restrict__ W,
                                                float* __restrict__ psplit) {
  __shared__ u16 Asm[128 * 40];
  __shared__ u16 Wsm[64 * 40];
  int t = threadIdx.x;
  int m0 = blockIdx.y * 128, n0 = blockIdx.x * 64;
  int kstart = blockIdx.z << 10;
  float* outp = psplit + (size_t)blockIdx.z * 2048 * 1024;
  int srow = t >> 1, koff = (t & 1) * 16;
  const u16* Ag = A + (size_t)(m0 + srow) * DDIM + kstart + koff;
  const u16* Wg = W + (size_t)(n0 + (srow & 63)) * DDIM + kstart + koff;
  int w = t >> 6, lane = t & 63;
  int wr = w >> 1, wc = w & 1;
  int quad = lane >> 4, mr = lane & 15;
  f32x4 z = {0.f, 0.f, 0.f, 0.f};
  f32x4 acc[4][2] = {{z, z}, {z, z}, {z, z}, {z, z}};
  const u16* arp = &Asm[(wr * 64 + mr) * 40 + quad * 8];
  const u16* brp = &Wsm[(wc * 32 + mr) * 40 + quad * 8];
  for (int k0 = 0; k0 < 1024; k0 += 32) {
    uint4 a0 = *(const uint4*)(Ag + k0);
    uint4 a1 = *(const uint4*)(Ag + k0 + 8);
    uint4 w0, w1;
    if (t < 128) {
      w0 = *(const uint4*)(Wg + k0);
      w1 = *(const uint4*)(Wg + k0 + 8);
    }
    __syncthreads();
    *(uint4*)(&Asm[srow * 40 + koff]) = a0;
    *(uint4*)(&Asm[srow * 40 + koff + 8]) = a1;
    if (t < 128) {
      *(uint4*)(&Wsm[srow * 40 + koff]) = w0;
      *(uint4*)(&Wsm[srow * 40 + koff + 8]) = w1;
    }
    __syncthreads();
    bf16x8 af[4], bf[2];
#pragma unroll
    for (int i = 0; i < 4; i++) af[i] = *(const bf16x8*)(arp + i * 16 * 40);
#pragma unroll
    for (int i = 0; i < 2; i++) bf[i] = *(const bf16x8*)(brp + i * 16 * 40);
#pragma unroll
    for (int mi = 0; mi < 4; mi++)
#pragma unroll
      for (int ni = 0; ni < 2; ni++)
        acc[mi][ni] = __builtin_amdgcn_mfma_f32_16x16x32_bf16(af[mi], bf[ni],
                                                              acc[mi][ni], 0, 0, 0);
  }
#pragma unroll
  for (int ni = 0; ni < 2; ni++) {
    int col = n0 + wc * 32 + ni * 16 + mr;
#pragma unroll
    for (int mi = 0; mi < 4; mi++) {
#pragma unroll
      for (int rr2 = 0; rr2 < 4; rr2++) {
        int row = m0 + wr * 64 + mi * 16 + quad * 4 + rr2;
        outp[(size_t)row * 1024 + col] = acc[mi][ni][rr2];
      }
    }
  }
}

// ---------------- K4b: combine split-K partials + bias + residual -> out ----------------
__global__ __launch_bounds__(256) void k_ocomb(const float* __restrict__ psplit,
                                               const float* __restrict__ bias,
                                               const float* __restrict__ resid,
                                               float* __restrict__ out) {
  int idx = blockIdx.x * 256 + threadIdx.x;   // float4 over [2048][1024]
  int colf = idx & 255;
  float4 a = ((const float4*)psplit)[idx];
  float4 b2 = ((const float4*)(psplit + 2048 * 1024))[idx];
  float4 rv = ((const float4*)resid)[idx];
  float4 bv = *(const float4*)(bias + colf * 4);
  float4 o;
  o.x = a.x + b2.x + bv.x + rv.x;
  o.y = a.y + b2.y + bv.y + rv.y;
  o.z = a.z + b2.z + bv.z + rv.z;
  o.w = a.w + b2.w + bv.w + rv.w;
  ((float4*)out)[idx] = o;
}

// ---------------- K2 v3: fused conv+silu + x_proj GEMM -> projT, 16 K-partitions ----
__global__ __launch_bounds__(256) void k_xprojT(const u16* __restrict__ xgb,
                                                const u16* __restrict__ whb,
                                                const u16* __restrict__ wlb,
                                                const float* __restrict__ cw,
                                                const float* __restrict__ cb,
                                                float* __restrict__ projT,
                                                float* __restrict__ pscr) {
  __shared__ u16 Xst[67 * 40];
  __shared__ u16 XH[64 * 40];
  __shared__ u16 XL[64 * 40];
  __shared__ u16 WH[96 * 40];
  __shared__ u16 WL[96 * 40];
  int t = threadIdx.x;
  int tt = blockIdx.x & 31, ks = blockIdx.x >> 5;
  int tokbase = tt << 6;
  int b = tokbase >> 10, l0 = tokbase & 1023;
  int kbase = ks << 7;
  const u16* xbase = xgb + (size_t)(b * XR + l0) * 4096;
  float* outp = (ks == 0) ? projT : (pscr + (size_t)(ks - 1) * 196608);
  int dlane = t & 31, tokg = t >> 5;
  int wvq = t >> 6, lane = t & 63;
  int quad = lane >> 4, mr = lane & 15;
  f32x4 z = {0.f, 0.f, 0.f, 0.f};
  f32x4 acc[6] = {z, z, z, z, z, z};

  for (int it = 0; it < 4; it++) {
    int kc = kbase + (it << 5);
    for (int idx = t; idx < 268; idx += 256) {
      int r = idx >> 2, p = idx & 3;
      uint4 v = *(const uint4*)(xbase + (size_t)r * 4096 + kc + p * 8);
      *(uint4*)(&Xst[r * 40 + p * 8]) = v;
    }
    for (int idx = t; idx < 384; idx += 256) {
      int r = idx >> 2, p = idx & 3;
      *(uint4*)(&WH[r * 40 + p * 8]) = *(const uint4*)(whb + (size_t)r * 2048 + kc + p * 8);
      *(uint4*)(&WL[r * 40 + p * 8]) = *(const uint4*)(wlb + (size_t)r * 2048 + kc + p * 8);
    }
    __syncthreads();
    {
      int d = kc + dlane;
      float4 cwv = *(const float4*)(cw + d * 4);
      float cbv = cb[d];
      float xr[11];
#pragma unroll
      for (int j = 0; j < 11; j++) xr[j] = bf2f(Xst[(tokg * 8 + j) * 40 + dlane]);
#pragma unroll
      for (int jj = 0; jj < 8; jj++) {
        float xc = silu_f(cbv + cwv.x * xr[jj] + cwv.y * xr[jj + 1] +
                          cwv.z * xr[jj + 2] + cwv.w * xr[jj + 3]);
        u16 h = f2bf(xc);
        u16 l = f2bf(xc - bf2f(h));
        XH[(tokg * 8 + jj) * 40 + dlane] = h;
        XL[(tokg * 8 + jj) * 40 + dlane] = l;
      }
    }
    __syncthreads();
    bf16x8 xh = *(const bf16x8*)(&XH[(wvq * 16 + mr) * 40 + quad * 8]);
    bf16x8 xl = *(const bf16x8*)(&XL[(wvq * 16 + mr) * 40 + quad * 8]);
#pragma unroll
    for (int mi = 0; mi < 6; mi++) {
      bf16x8 wh = *(const bf16x8*)(&WH[(mi * 16 + mr) * 40 + quad * 8]);
      bf16x8 wl = *(const bf16x8*)(&WL[(mi * 16 + mr) * 40 + quad * 8]);
      acc[mi] = __builtin_amdgcn_mfma_f32_16x16x32_bf16(wh, xh, acc[mi], 0, 0, 0);
      acc[mi] = __builtin_amdgcn_mfma_f32_16x16x32_bf16(wh, xl, acc[mi], 0, 0, 0);
      acc[mi] = __builtin_amdgcn_mfma_f32_16x16x32_bf16(wl, xh, acc[mi], 0, 0, 0);
    }
    __syncthreads();
  }
#pragma unroll
  for (int mi = 0; mi < 6; mi++) {
#pragma unroll
    for (int rr = 0; rr < 4; rr++) {
      int o = mi * 16 + quad * 4 + rr;
      outp[(size_t)o * BL + tokbase + wvq * 16 + mr] = acc[mi][rr];
    }
  }
}

// ---------------- K2d: combine 16 K-partials + bias into projT ----------------
__global__ __launch_bounds__(256) void k_xcomb(float* __restrict__ projT,
                                               const float* __restrict__ scr,
                                               const float* __restrict__ xpb) {
  int idx = blockIdx.x * 256 + threadIdx.x;
  int o = idx >> 9;
  float4 a = ((const float4*)projT)[idx];
  float bv = xpb[o];
  float sx = bv, sy = bv, sz = bv, sw = bv;
#pragma unroll
  for (int p = 0; p < 15; p++) {
    float4 s = ((const float4*)(scr + (size_t)p * 196608))[idx];
    sx += s.x; sy += s.y; sz += s.z; sw += s.w;
  }
  a.x += sx; a.y += sy; a.z += sz; a.w += sw;
  ((float4*)projT)[idx] = a;
}

// ---------------- K2c: delta GEMM: deltaT[2048 d][2048 tok] = softplus(dtw.projT + dtb) ----
__global__ __launch_bounds__(256) void k_delta(const float* __restrict__ projT,
                                               const float* __restrict__ dtw,
                                               const float* __restrict__ dtb,
                                               float* __restrict__ deltaT) {
  __shared__ float dw_s[16][64];
  int t = threadIdx.x;
  int d0 = (blockIdx.x >> 3) * 16;
  int tokbase = (blockIdx.x & 7) * 256;
  {
    const float* src = dtw + (size_t)d0 * 64;
#pragma unroll
    for (int i = 0; i < 4; i++) {
      int idx = t + i * 256;
      dw_s[idx >> 6][idx & 63] = src[idx];
    }
  }
  __syncthreads();
  int tq = t & 63, dq = t >> 6;
  const float* pr = projT + tokbase + tq * 4;
  int dbase = d0 + dq * 4;
  float acc[4][4];
#pragma unroll
  for (int di = 0; di < 4; di++) {
    float bv = dtb[dbase + di];
    acc[di][0] = bv; acc[di][1] = bv; acc[di][2] = bv; acc[di][3] = bv;
  }
#pragma unroll 8
  for (int r = 0; r < 64; r++) {
    float4 pv = *(const float4*)(pr + (size_t)r * BL);
#pragma unroll
    for (int di = 0; di < 4; di++) {
      float wk = dw_s[dq * 4 + di][r];
      acc[di][0] += pv.x * wk; acc[di][1] += pv.y * wk;
      acc[di][2] += pv.z * wk; acc[di][3] += pv.w * wk;
    }
  }
#pragma unroll
  for (int di = 0; di < 4; di++) {
    float4 o;
    o.x = softplus_f(acc[di][0]); o.y = softplus_f(acc[di][1]);
    o.z = softplus_f(acc[di][2]); o.w = softplus_f(acc[di][3]);
    *(float4*)(deltaT + (size_t)(dbase + di) * BL + tokbase + tq * 4) = o;
  }
}

// ---------------- K3 v3: selective scan; x from d-major xT (coalesced) ----------------
__global__ __launch_bounds__(256) void k_scan2(const float* __restrict__ projT,
                                               const float* __restrict__ deltaT,
                                               const u16* __restrict__ xT,
                                               const u16* __restrict__ xgb,
                                               const float* __restrict__ cw,
                                               const float* __restrict__ cb,
                                               const float* __restrict__ alog,
                                               const float* __restrict__ dparam,
                                               const float* __restrict__ cs,
                                               u16* __restrict__ yb) {
  __shared__ float wtot[4];
  __shared__ float xcp[1088];
  __shared__ float uvl[1088];
  __shared__ float dlp[1088];

  int t = threadIdx.x;
  int cidx = ((blockIdx.x & 7) << 9) | (blockIdx.x >> 3);   // (b,d)
  int b = cidx >> 11;
  int d = cidx & (DDIM - 1);
  int wv = t >> 6, lane = t & 63;

  float4 cwv = *(const float4*)(cw + d * 4);
  float cbv = cb[d];
  float Dp = dparam[d];
  const u16* gcol = xgb + (size_t)(b * XR + 3) * 4096 + d + DDIM;   // gate column
  u16* ycol = yb + ((size_t)(b << 10)) * DDIM + d;
  int colbase = b << 10;
  int tok0 = t << 2;

  float4 dv = *(const float4*)(deltaT + (size_t)d * BL + colbase + tok0);

  // ---- stage x row (coalesced from xT) into dlp-aliased xls ----
  float* xls = dlp;
  if (t < 3) xls[t] = 0.f;
  {
    ushort4 xv = ((const ushort4*)(xT + (size_t)d * 2048 + colbase))[t];
    xls[3 + tok0 + 0] = bf2f(xv.x);
    xls[3 + tok0 + 1] = bf2f(xv.y);
    xls[3 + tok0 + 2] = bf2f(xv.z);
    xls[3 + tok0 + 3] = bf2f(xv.w);
  }
  __syncthreads();                       // B1

#pragma unroll
  for (int i = 0; i < 4; i++) {
    int tok = tok0 + i;
    float xc = silu_f(cbv + cwv.x * xls[tok] + cwv.y * xls[tok + 1] +
                      cwv.z * xls[tok + 2] + cwv.w * xls[tok + 3]);
    xcp[((tok >> 4) * 17) + (tok & 15)] = xc;
  }
  float d0 = dv.x, d1 = dv.y, d2 = dv.z, d3 = dv.w;
  uvl[((tok0 >> 4) * 17) + (tok0 & 15)]             = d0;
  uvl[(((tok0 + 1) >> 4) * 17) + ((tok0 + 1) & 15)] = d1;
  uvl[(((tok0 + 2) >> 4) * 17) + ((tok0 + 2) & 15)] = d2;
  uvl[(((tok0 + 3) >> 4) * 17) + ((tok0 + 3) & 15)] = d3;
  float c0 = d0, c1 = c0 + d1, c2 = c1 + d2, c3 = c2 + d3;
  float sc = c3;
#pragma unroll
  for (int off = 1; off < 64; off <<= 1) {
    float u = __shfl_up(sc, off);
    if (lane >= off) sc += u;
  }
  if (lane == 63) wtot[wv] = sc;
  __syncthreads();                       // B2
  {
    float base = sc - c3;
#pragma unroll
    for (int i = 0; i < 3; i++) if (i < wv) base += wtot[i];
    dlp[((tok0 >> 4) * 17) + (tok0 & 15)]             = base + c0;
    dlp[(((tok0 + 1) >> 4) * 17) + ((tok0 + 1) & 15)] = base + c1;
    dlp[(((tok0 + 2) >> 4) * 17) + ((tok0 + 2) & 15)] = base + c2;
    dlp[(((tok0 + 3) >> 4) * 17) + ((tok0 + 3) & 15)] = base + c3;
  }
#pragma unroll
  for (int i = 0; i < 4; i++) {
    int tok = tok0 + i;
    int p = ((tok >> 4) * 17) + (tok & 15);
    uvl[p] = uvl[p] * xcp[p];
  }
  __syncthreads();                       // B3

  int pb = lane * 17;
  float y[16];
#pragma unroll
  for (int i = 0; i < 16; i++) y[i] = 0.f;
  float Dprev = (lane == 0) ? 0.f : dlp[pb - 2];

#pragma unroll 1
  for (int r = 0; r < 4; r++) {
    int n = (wv << 2) + r;
    float An = -__expf(alog[d * NST + n]);
    float st = cs[(size_t)(b * DDIM + d) * NST + n];
    const float* pB = projT + (size_t)(64 + n) * BL + colbase + (lane << 4);
    const float* pC = pB + (size_t)16 * BL;
    float Pp = __expf(An * Dprev);
    float sl = 0.f;
#pragma unroll
    for (int c = 0; c < 4; c++) {
      float4 bv = *(const float4*)(pB + c * 4);
      float4 cv = *(const float4*)(pC + c * 4);
      float bvs[4] = {bv.x, bv.y, bv.z, bv.w};
      float cvs[4] = {cv.x, cv.y, cv.z, cv.w};
#pragma unroll
      for (int j = 0; j < 4; j++) {
        int i = c * 4 + j;
        float P = __expf(An * dlp[pb + i]);
        float w = uvl[pb + i] * bvs[j] * __builtin_amdgcn_rcpf(fmaxf(Pp, 1e-10f));
        sl += w;
        y[i] += (sl * Pp + st * P) * cvs[j];
        Pp = P;
      }
    }
    float s2 = sl;
#pragma unroll
    for (int off = 1; off < 64; off <<= 1) {
      float u = __shfl_up(s2, off);
      if (lane >= off) s2 += u;
    }
    float Soff = s2 - sl;
#pragma unroll
    for (int c = 0; c < 4; c++) {
      float4 cv = *(const float4*)(pC + c * 4);
      float cvs[4] = {cv.x, cv.y, cv.z, cv.w};
#pragma unroll
      for (int j = 0; j < 4; j++) {
        int i = c * 4 + j;
        float dlm = (i == 0) ? Dprev : dlp[pb + i - 1];
        y[i] += Soff * __expf(An * dlm) * cvs[j];
      }
    }
  }
  __syncthreads();                       // B4
  if (wv == 2) {
#pragma unroll
    for (int i = 0; i < 16; i++) uvl[pb + i] = y[i];
  } else if (wv == 3) {
#pragma unroll
    for (int i = 0; i < 16; i++) dlp[pb + i] = y[i];
  }
  __syncthreads();                       // B5
  if (wv == 0) {
#pragma unroll
    for (int i = 0; i < 16; i++) uvl[pb + i] += y[i];
  } else if (wv == 1) {
#pragma unroll
    for (int i = 0; i < 16; i++) dlp[pb + i] += y[i];
  }
  __syncthreads();                       // B6
#pragma unroll
  for (int i = 0; i < 4; i++) {
    int tok = tok0 + i;
    int p = ((tok >> 4) * 17) + (tok & 15);
    float yv = uvl[p] + dlp[p] + xcp[p] * Dp;
    float g = bf2f(gcol[(size_t)tok * 4096]);
    ycol[(size_t)tok * DDIM] = f2bf(yv * silu_f(g));
  }
}

extern "C" void kernel_launch(void* const* d_in, const int* in_sizes, int n_in,
                              void* d_out, int out_size, void* d_ws, size_t ws_size,
                              hipStream_t stream) {
  const float* inp    = (const float*)d_in[0];
  const float* cstate = (const float*)d_in[1];
  const float* norm_w = (const float*)d_in[2];
  const float* w1     = (const float*)d_in[3];
  const float* b1     = (const float*)d_in[4];
  const float* convw  = (const float*)d_in[5];
  const float* convb  = (const float*)d_in[6];
  const float* xpw    = (const float*)d_in[7];
  const float* xpb    = (const float*)d_in[8];
  const float* dtw    = (const float*)d_in[9];
  const float* dtb    = (const float*)d_in[10];
  const float* alog   = (const float*)d_in[11];
  const float* dparam = (const float*)d_in[12];
  const float* wo     = (const float*)d_in[13];
  const float* bo     = (const float*)d_in[14];
  float* out = (float*)d_out;

  // workspace layout (ws >= 56,156,160 B confirmed R6/R8/R10)
  char* wsb = (char*)d_ws;
  u16*   w1b    = (u16*)(wsb + 0);            //  8,388,608 B  [4096][1024] bf16 (dead after gemm1b)
  u16*   xTbuf  = w1b;                        //  8,388,608 B  xT [2048 d][2048 tok] bf16 (after gemm1b)
  u16*   wob    = (u16*)(wsb + 8388608);      //  4,194,304 B  [1024][2048] bf16
  u16*   whb    = (u16*)(wsb + 12591104);     //    393,216 B  xpw hi bf16 [96][2048]
  u16*   wlb    = (u16*)(wsb + 12984320);     //    393,216 B  xpw lo bf16 [96][2048]
  float* projT  = (float*)(wsb + 13377536);   //    786,432 B  [96][2048] f32
  u16*   xgb    = (u16*)(wsb + 14163968);     // 16,826,368 B  [2][1027][4096] bf16
  u16*   yb     = (u16*)(wsb + 30990336);     //  8,388,608 B  [2][1024][2048] bf16
  u16*   xnb    = yb;                         //  aliases yb (consumed before scan writes)
  float* deltaT = (float*)(wsb + 39378944);   // 16,777,216 B  [2048 d][2048 tok] f32
  float* pscr   = deltaT;                     //  first 11.8 MB: xproj K-partials (pre-k_delta)
  float* psplit = deltaT;                     //  16 MB: gemm2 split-K partials (post-scan2)

  k_prep<<<6360, 256, 0, stream>>>(w1, w1b, wo, wob, xpw, whb, wlb, xgb);
  k_rowscale2<<<BL, 256, 0, stream>>>(inp, norm_w, xnb);
  k_gemm1b<<<dim3(32, 16), 256, 0, stream>>>(xnb, w1b, b1, xgb);
  k_xT<<<1024, 256, 0, stream>>>(xgb, xTbuf);
  k_xprojT<<<512, 256, 0, stream>>>(xgb, whb, wlb, convw, convb, projT, pscr);
  k_xcomb<<<192, 256, 0, stream>>>(projT, pscr, xpb);
  k_delta<<<1024, 256, 0, stream>>>(projT, dtw, dtb, deltaT);
  k_scan2<<<2 * DDIM, 256, 0, stream>>>(projT, deltaT, xTbuf, xgb, convw, convb,
                                        alog, dparam, cstate, yb);
  k_gemm2b<<<dim3(16, 16, 2), 256, 0, stream>>>(yb, wob, psplit);
  k_ocomb<<<2048, 256, 0, stream>>>(psplit, bo, inp, out);
}

// Round 13
// 261.833 us; speedup vs baseline: 2.2676x; 1.0472x over previous
//
#include <hip/hip_runtime.h>
#include <stdint.h>

#define LSEQ 1024
#define HDIM 1024
#define DDIM 2048
#define BL 2048
#define NST 16
#define XR 1027          // 3 halo rows (zeroed in k_prep) + 1024 tokens

typedef unsigned short u16;
typedef __attribute__((ext_vector_type(8))) short bf16x8;
typedef __attribute__((ext_vector_type(4))) float f32x4;

// silu via v_rcp (1-ulp rcp; output tolerance is bf16-dominated)
static __device__ __forceinline__ float silu_f(float v) {
  return v * __builtin_amdgcn_rcpf(1.f + __expf(-v));
}
static __device__ __forceinline__ float bf2f(u16 u) {
  union { float f; unsigned int i; } c; c.i = ((unsigned int)u) << 16; return c.f;
}
static __device__ __forceinline__ u16 f2bf(float f) {
  union { float f; unsigned int i; } c; c.f = f;
  unsigned int r = c.i + 0x7fffu + ((c.i >> 16) & 1u);
  return (u16)(r >> 16);
}
static __device__ __forceinline__ float softplus_f(float v) {
  return (v > 20.f) ? v : __logf(1.f + __expf(v));
}

// ---------------- fused prep: castw(w1), castw(wo), castsplit(xpw), zerohalo, rmsnorm ----
__global__ __launch_bounds__(256) void k_prep(const float* __restrict__ w1,
                                              u16* __restrict__ w1b,
                                              const float* __restrict__ wo,
                                              u16* __restrict__ wob,
                                              const float* __restrict__ xpw,
                                              u16* __restrict__ whb,
                                              u16* __restrict__ wlb,
                                              u16* __restrict__ xgb,
                                              const float* __restrict__ inp,
                                              const float* __restrict__ nw,
                                              u16* __restrict__ xnb) {
  int bidx = blockIdx.x;
  int t = threadIdx.x;
  if (bidx < 4096) {
    int idx = bidx * 256 + t;
    float4 v = ((const float4*)w1)[idx];
    ushort4 o;
    o.x = f2bf(v.x); o.y = f2bf(v.y); o.z = f2bf(v.z); o.w = f2bf(v.w);
    ((ushort4*)w1b)[idx] = o;
  } else if (bidx < 6144) {
    int idx = (bidx - 4096) * 256 + t;
    float4 v = ((const float4*)wo)[idx];
    ushort4 o;
    o.x = f2bf(v.x); o.y = f2bf(v.y); o.z = f2bf(v.z); o.w = f2bf(v.w);
    ((ushort4*)wob)[idx] = o;
  } else if (bidx < 6336) {
    int idx = (bidx - 6144) * 256 + t;
    float4 v = ((const float4*)xpw)[idx];
    ushort4 h, l;
    h.x = f2bf(v.x); l.x = f2bf(v.x - bf2f(h.x));
    h.y = f2bf(v.y); l.y = f2bf(v.y - bf2f(h.y));
    h.z = f2bf(v.z); l.z = f2bf(v.z - bf2f(h.z));
    h.w = f2bf(v.w); l.w = f2bf(v.w - bf2f(h.w));
    ((ushort4*)whb)[idx] = h;
    ((ushort4*)wlb)[idx] = l;
  } else if (bidx < 6360) {
    int idx = (bidx - 6336) * 256 + t;      // 6144 ushort4: 2 b x 3 rows x 1024
    int b = idx / 3072;
    int r = idx - b * 3072;
    ushort4 z4 = {0, 0, 0, 0};
    ((ushort4*)(xgb + (size_t)b * XR * 4096))[r] = z4;
  } else {
    // rmsnorm + normalize -> xnb bf16 [2048][1024]
    int row = bidx - 6360;
    float4 xv = *(const float4*)(inp + (size_t)row * HDIM + t * 4);
    float ss = xv.x * xv.x + xv.y * xv.y + xv.z * xv.z + xv.w * xv.w;
    for (int off = 32; off > 0; off >>= 1) ss += __shfl_down(ss, off);
    __shared__ float red[4];
    if ((t & 63) == 0) red[t >> 6] = ss;
    __syncthreads();
    float tot = red[0] + red[1] + red[2] + red[3];
    float scale = rsqrtf(tot * (1.f / HDIM) + 1e-6f);
    float4 nv = *(const float4*)(nw + t * 4);
    ushort4 o;
    o.x = f2bf(xv.x * scale * nv.x); o.y = f2bf(xv.y * scale * nv.y);
    o.z = f2bf(xv.z * scale * nv.z); o.w = f2bf(xv.w * scale * nv.w);
    ((ushort4*)xnb)[row * 256 + t] = o;
  }
}

// ---------------- K1: in_proj GEMM, 128x128 tile, pure bf16 ----------------
__global__ __launch_bounds__(256) void k_gemm1b(const u16* __restrict__ A,
                                                const u16* __restrict__ W,
                                                const float* __restrict__ bias,
                                                u16* __restrict__ xgb) {
  __shared__ u16 Asm[128 * 40];
  __shared__ u16 Wsm[128 * 40];
  int t = threadIdx.x;
  int m0 = blockIdx.y * 128, n0 = blockIdx.x * 128;
  int srow = t >> 1, koff = (t & 1) * 16;
  const u16* Ag = A + (size_t)(m0 + srow) * HDIM + koff;
  const u16* Wg = W + (size_t)(n0 + srow) * HDIM + koff;
  int w = t >> 6, lane = t & 63;
  int wr = w >> 1, wc = w & 1;
  int quad = lane >> 4, mr = lane & 15;
  f32x4 z = {0.f, 0.f, 0.f, 0.f};
  f32x4 acc[4][4] = {{z, z, z, z}, {z, z, z, z}, {z, z, z, z}, {z, z, z, z}};
  const u16* arp = &Asm[(wr * 64 + mr) * 40 + quad * 8];
  const u16* brp = &Wsm[(wc * 64 + mr) * 40 + quad * 8];
  for (int k0 = 0; k0 < HDIM; k0 += 32) {
    uint4 a0 = *(const uint4*)(Ag + k0);
    uint4 a1 = *(const uint4*)(Ag + k0 + 8);
    uint4 w0 = *(const uint4*)(Wg + k0);
    uint4 w1 = *(const uint4*)(Wg + k0 + 8);
    __syncthreads();
    *(uint4*)(&Asm[srow * 40 + koff]) = a0;
    *(uint4*)(&Asm[srow * 40 + koff + 8]) = a1;
    *(uint4*)(&Wsm[srow * 40 + koff]) = w0;
    *(uint4*)(&Wsm[srow * 40 + koff + 8]) = w1;
    __syncthreads();
    bf16x8 af[4], bf[4];
#pragma unroll
    for (int i = 0; i < 4; i++) {
      af[i] = *(const bf16x8*)(arp + i * 16 * 40);
      bf[i] = *(const bf16x8*)(brp + i * 16 * 40);
    }
#pragma unroll
    for (int mi = 0; mi < 4; mi++)
#pragma unroll
      for (int ni = 0; ni < 4; ni++)
        acc[mi][ni] = __builtin_amdgcn_mfma_f32_16x16x32_bf16(af[mi], bf[ni],
                                                              acc[mi][ni], 0, 0, 0);
  }
#pragma unroll
  for (int ni = 0; ni < 4; ni++) {
    int col = n0 + wc * 64 + ni * 16 + mr;
    float bv = bias[col];
#pragma unroll
    for (int mi = 0; mi < 4; mi++) {
#pragma unroll
      for (int rr2 = 0; rr2 < 4; rr2++) {
        int rr = m0 + wr * 64 + mi * 16 + quad * 4 + rr2;
        int row = (rr >> 10) * XR + 3 + (rr & 1023);
        xgb[(size_t)row * 4096 + col] = f2bf(acc[mi][ni][rr2] + bv);
      }
    }
  }
}

// ---------------- K1b: transpose x-half of xgb -> xT[2048 d][2048 tok] (bf16) ----------------
__global__ __launch_bounds__(256) void k_xT(const u16* __restrict__ xgb,
                                            u16* __restrict__ xT) {
  __shared__ u16 tile[64][66];      // row stride 66 u16 = 33 dwords (odd -> conflict-free cols)
  int dt = blockIdx.x & 31;         // d-tile (64 d)
  int tt = blockIdx.x >> 5;         // tok-tile (64 tok)
  int gtok0 = tt << 6;
  int b = gtok0 >> 10, l0 = gtok0 & 1023;
  int d0 = dt << 6;
  int t = threadIdx.x;
  const u16* src = xgb + (size_t)(b * XR + 3 + l0) * 4096 + d0;
#pragma unroll
  for (int i = 0; i < 8; i++) {
    int idx = t + i * 256;          // 0..2047
    int row = idx >> 5, uc = idx & 31;
    unsigned int v = *(const unsigned int*)(src + (size_t)row * 4096 + uc * 2);
    tile[row][uc * 2]     = (u16)(v & 0xffffu);
    tile[row][uc * 2 + 1] = (u16)(v >> 16);
  }
  __syncthreads();
#pragma unroll
  for (int i = 0; i < 8; i++) {
    int idx = t + i * 256;
    int r = idx >> 5, c2 = idx & 31;          // d-row r, token pair c2
    unsigned int lo = tile[c2 * 2][r];
    unsigned int hi = tile[c2 * 2 + 1][r];
    *(unsigned int*)(xT + (size_t)(d0 + r) * 2048 + gtok0 + c2 * 2) = lo | (hi << 16);
  }
}

// ---------------- K4: out_proj GEMM, 128x64 tile, split-K x2 -> f32 partials ----------------
__global__ __launch_bounds__(256) void k_gemm2b(const u16* __restrict__ A,
                                                const u16* __restrict__ W,
                                                float* __restrict__ psplit) {
  __shared__ u16 Asm[128 * 40];
  __shared__ u16 Wsm[64 * 40];
  int t = threadIdx.x;
  int m0 = blockIdx.y * 128, n0 = blockIdx.x * 64;
  int kstart = blockIdx.z << 10;
  float* outp = psplit + (size_t)blockIdx.z * 2048 * 1024;
  int srow = t >> 1, koff = (t & 1) * 16;
  const u16* Ag = A + (size_t)(m0 + srow) * DDIM + kstart + koff;
  const u16* Wg = W + (size_t)(n0 + (srow & 63)) * DDIM + kstart + koff;
  int w = t >> 6, lane = t & 63;
  int wr = w >> 1, wc = w & 1;
  int quad = lane >> 4, mr = lane & 15;
  f32x4 z = {0.f, 0.f, 0.f, 0.f};
  f32x4 acc[4][2] = {{z, z}, {z, z}, {z, z}, {z, z}};
  const u16* arp = &Asm[(wr * 64 + mr) * 40 + quad * 8];
  const u16* brp = &Wsm[(wc * 32 + mr) * 40 + quad * 8];
  for (int k0 = 0; k0 < 1024; k0 += 32) {
    uint4 a0 = *(const uint4*)(Ag + k0);
    uint4 a1 = *(const uint4*)(Ag + k0 + 8);
    uint4 w0, w1;
    if (t < 128) {
      w0 = *(const uint4*)(Wg + k0);
      w1 = *(const uint4*)(Wg + k0 + 8);
    }
    __syncthreads();
    *(uint4*)(&Asm[srow * 40 + koff]) = a0;
    *(uint4*)(&Asm[srow * 40 + koff + 8]) = a1;
    if (t < 128) {
      *(uint4*)(&Wsm[srow * 40 + koff]) = w0;
      *(uint4*)(&Wsm[srow * 40 + koff + 8]) = w1;
    }
    __syncthreads();
    bf16x8 af[4], bf[2];
#pragma unroll
    for (int i = 0; i < 4; i++) af[i] = *(const bf16x8*)(arp + i * 16 * 40);
#pragma unroll
    for (int i = 0; i < 2; i++) bf[i] = *(const bf16x8*)(brp + i * 16 * 40);
#pragma unroll
    for (int mi = 0; mi < 4; mi++)
#pragma unroll
      for (int ni = 0; ni < 2; ni++)
        acc[mi][ni] = __builtin_amdgcn_mfma_f32_16x16x32_bf16(af[mi], bf[ni],
                                                              acc[mi][ni], 0, 0, 0);
  }
#pragma unroll
  for (int ni = 0; ni < 2; ni++) {
    int col = n0 + wc * 32 + ni * 16 + mr;
#pragma unroll
    for (int mi = 0; mi < 4; mi++) {
#pragma unroll
      for (int rr2 = 0; rr2 < 4; rr2++) {
        int row = m0 + wr * 64 + mi * 16 + quad * 4 + rr2;
        outp[(size_t)row * 1024 + col] = acc[mi][ni][rr2];
      }
    }
  }
}

// ---------------- K4b: combine split-K partials + bias + residual -> out ----------------
__global__ __launch_bounds__(256) void k_ocomb(const float* __restrict__ psplit,
                                               const float* __restrict__ bias,
                                               const float* __restrict__ resid,
                                               float* __restrict__ out) {
  int idx = blockIdx.x * 256 + threadIdx.x;   // float4 over [2048][1024]
  int colf = idx & 255;
  float4 a = ((const float4*)psplit)[idx];
  float4 b2 = ((const float4*)(psplit + 2048 * 1024))[idx];
  float4 rv = ((const float4*)resid)[idx];
  float4 bv = *(const float4*)(bias + colf * 4);
  float4 o;
  o.x = a.x + b2.x + bv.x + rv.x;
  o.y = a.y + b2.y + bv.y + rv.y;
  o.z = a.z + b2.z + bv.z + rv.z;
  o.w = a.w + b2.w + bv.w + rv.w;
  ((float4*)out)[idx] = o;
}

// ---------------- K2 v3: fused conv+silu + x_proj GEMM -> projT, 16 K-partitions ----
__global__ __launch_bounds__(256) void k_xprojT(const u16* __restrict__ xgb,
                                                const u16* __restrict__ whb,
                                                const u16* __restrict__ wlb,
                                                const float* __restrict__ cw,
                                                const float* __restrict__ cb,
                                                float* __restrict__ projT,
                                                float* __restrict__ pscr) {
  __shared__ u16 Xst[67 * 40];
  __shared__ u16 XH[64 * 40];
  __shared__ u16 XL[64 * 40];
  __shared__ u16 WH[96 * 40];
  __shared__ u16 WL[96 * 40];
  int t = threadIdx.x;
  int tt = blockIdx.x & 31, ks = blockIdx.x >> 5;
  int tokbase = tt << 6;
  int b = tokbase >> 10, l0 = tokbase & 1023;
  int kbase = ks << 7;
  const u16* xbase = xgb + (size_t)(b * XR + l0) * 4096;
  float* outp = (ks == 0) ? projT : (pscr + (size_t)(ks - 1) * 196608);
  int dlane = t & 31, tokg = t >> 5;
  int wvq = t >> 6, lane = t & 63;
  int quad = lane >> 4, mr = lane & 15;
  f32x4 z = {0.f, 0.f, 0.f, 0.f};
  f32x4 acc[6] = {z, z, z, z, z, z};

  for (int it = 0; it < 4; it++) {
    int kc = kbase + (it << 5);
    for (int idx = t; idx < 268; idx += 256) {
      int r = idx >> 2, p = idx & 3;
      uint4 v = *(const uint4*)(xbase + (size_t)r * 4096 + kc + p * 8);
      *(uint4*)(&Xst[r * 40 + p * 8]) = v;
    }
    for (int idx = t; idx < 384; idx += 256) {
      int r = idx >> 2, p = idx & 3;
      *(uint4*)(&WH[r * 40 + p * 8]) = *(const uint4*)(whb + (size_t)r * 2048 + kc + p * 8);
      *(uint4*)(&WL[r * 40 + p * 8]) = *(const uint4*)(wlb + (size_t)r * 2048 + kc + p * 8);
    }
    __syncthreads();
    {
      int d = kc + dlane;
      float4 cwv = *(const float4*)(cw + d * 4);
      float cbv = cb[d];
      float xr[11];
#pragma unroll
      for (int j = 0; j < 11; j++) xr[j] = bf2f(Xst[(tokg * 8 + j) * 40 + dlane]);
#pragma unroll
      for (int jj = 0; jj < 8; jj++) {
        float xc = silu_f(cbv + cwv.x * xr[jj] + cwv.y * xr[jj + 1] +
                          cwv.z * xr[jj + 2] + cwv.w * xr[jj + 3]);
        u16 h = f2bf(xc);
        u16 l = f2bf(xc - bf2f(h));
        XH[(tokg * 8 + jj) * 40 + dlane] = h;
        XL[(tokg * 8 + jj) * 40 + dlane] = l;
      }
    }
    __syncthreads();
    bf16x8 xh = *(const bf16x8*)(&XH[(wvq * 16 + mr) * 40 + quad * 8]);
    bf16x8 xl = *(const bf16x8*)(&XL[(wvq * 16 + mr) * 40 + quad * 8]);
#pragma unroll
    for (int mi = 0; mi < 6; mi++) {
      bf16x8 wh = *(const bf16x8*)(&WH[(mi * 16 + mr) * 40 + quad * 8]);
      bf16x8 wl = *(const bf16x8*)(&WL[(mi * 16 + mr) * 40 + quad * 8]);
      acc[mi] = __builtin_amdgcn_mfma_f32_16x16x32_bf16(wh, xh, acc[mi], 0, 0, 0);
      acc[mi] = __builtin_amdgcn_mfma_f32_16x16x32_bf16(wh, xl, acc[mi], 0, 0, 0);
      acc[mi] = __builtin_amdgcn_mfma_f32_16x16x32_bf16(wl, xh, acc[mi], 0, 0, 0);
    }
    __syncthreads();
  }
#pragma unroll
  for (int mi = 0; mi < 6; mi++) {
#pragma unroll
    for (int rr = 0; rr < 4; rr++) {
      int o = mi * 16 + quad * 4 + rr;
      outp[(size_t)o * BL + tokbase + wvq * 16 + mr] = acc[mi][rr];
    }
  }
}

// ---------------- K2d: combine 16 K-partials + bias into projT ----------------
__global__ __launch_bounds__(256) void k_xcomb(float* __restrict__ projT,
                                               const float* __restrict__ scr,
                                               const float* __restrict__ xpb) {
  int idx = blockIdx.x * 256 + threadIdx.x;
  int o = idx >> 9;
  float4 a = ((const float4*)projT)[idx];
  float bv = xpb[o];
  float sx = bv, sy = bv, sz = bv, sw = bv;
#pragma unroll
  for (int p = 0; p < 15; p++) {
    float4 s = ((const float4*)(scr + (size_t)p * 196608))[idx];
    sx += s.x; sy += s.y; sz += s.z; sw += s.w;
  }
  a.x += sx; a.y += sy; a.z += sz; a.w += sw;
  ((float4*)projT)[idx] = a;
}

// ---------------- K2c: delta GEMM: deltaT[2048 d][2048 tok] = softplus(dtw.projT + dtb) ----
__global__ __launch_bounds__(256) void k_delta(const float* __restrict__ projT,
                                               const float* __restrict__ dtw,
                                               const float* __restrict__ dtb,
                                               float* __restrict__ deltaT) {
  __shared__ float dw_s[16][64];
  int t = threadIdx.x;
  int d0 = (blockIdx.x >> 3) * 16;
  int tokbase = (blockIdx.x & 7) * 256;
  {
    const float* src = dtw + (size_t)d0 * 64;
#pragma unroll
    for (int i = 0; i < 4; i++) {
      int idx = t + i * 256;
      dw_s[idx >> 6][idx & 63] = src[idx];
    }
  }
  __syncthreads();
  int tq = t & 63, dq = t >> 6;
  const float* pr = projT + tokbase + tq * 4;
  int dbase = d0 + dq * 4;
  float acc[4][4];
#pragma unroll
  for (int di = 0; di < 4; di++) {
    float bv = dtb[dbase + di];
    acc[di][0] = bv; acc[di][1] = bv; acc[di][2] = bv; acc[di][3] = bv;
  }
#pragma unroll 8
  for (int r = 0; r < 64; r++) {
    float4 pv = *(const float4*)(pr + (size_t)r * BL);
#pragma unroll
    for (int di = 0; di < 4; di++) {
      float wk = dw_s[dq * 4 + di][r];
      acc[di][0] += pv.x * wk; acc[di][1] += pv.y * wk;
      acc[di][2] += pv.z * wk; acc[di][3] += pv.w * wk;
    }
  }
#pragma unroll
  for (int di = 0; di < 4; di++) {
    float4 o;
    o.x = softplus_f(acc[di][0]); o.y = softplus_f(acc[di][1]);
    o.z = softplus_f(acc[di][2]); o.w = softplus_f(acc[di][3]);
    *(float4*)(deltaT + (size_t)(dbase + di) * BL + tokbase + tq * 4) = o;
  }
}

// ---------------- K3 v4: selective scan, fully coalesced ----------------
// Un-gated y (f32) is written back into this block's own deltaT row slice:
// each thread read exactly deltaT[d][colbase+tok0..3] at kernel start (dv),
// so the slice is dead afterward; per-thread read-then-write, no cross-thread
// overlap.  Gating + transpose to yb happens in k_gate (coalesced both sides,
// y stays f32 until gated -> output bitwise identical to the fused path).
__global__ __launch_bounds__(256) void k_scan2(const float* __restrict__ projT,
                                               float* __restrict__ deltaT,
                                               const u16* __restrict__ xT,
                                               const float* __restrict__ cw,
                                               const float* __restrict__ cb,
                                               const float* __restrict__ alog,
                                               const float* __restrict__ dparam,
                                               const float* __restrict__ cs) {
  __shared__ float wtot[4];
  __shared__ float xcp[1088];
  __shared__ float uvl[1088];
  __shared__ float dlp[1088];

  int t = threadIdx.x;
  int cidx = ((blockIdx.x & 7) << 9) | (blockIdx.x >> 3);   // (b,d)
  int b = cidx >> 11;
  int d = cidx & (DDIM - 1);
  int wv = t >> 6, lane = t & 63;

  float4 cwv = *(const float4*)(cw + d * 4);
  float cbv = cb[d];
  float Dp = dparam[d];
  int colbase = b << 10;
  int tok0 = t << 2;
  float* drow = deltaT + (size_t)d * BL + colbase;

  float4 dv = *(const float4*)(drow + tok0);

  // ---- stage x row (coalesced from xT) into dlp-aliased xls ----
  float* xls = dlp;
  if (t < 3) xls[t] = 0.f;
  {
    ushort4 xv = ((const ushort4*)(xT + (size_t)d * 2048 + colbase))[t];
    xls[3 + tok0 + 0] = bf2f(xv.x);
    xls[3 + tok0 + 1] = bf2f(xv.y);
    xls[3 + tok0 + 2] = bf2f(xv.z);
    xls[3 + tok0 + 3] = bf2f(xv.w);
  }
  __syncthreads();                       // B1

#pragma unroll
  for (int i = 0; i < 4; i++) {
    int tok = tok0 + i;
    float xc = silu_f(cbv + cwv.x * xls[tok] + cwv.y * xls[tok + 1] +
                      cwv.z * xls[tok + 2] + cwv.w * xls[tok + 3]);
    xcp[((tok >> 4) * 17) + (tok & 15)] = xc;
  }
  float d0 = dv.x, d1 = dv.y, d2 = dv.z, d3 = dv.w;
  uvl[((tok0 >> 4) * 17) + (tok0 & 15)]             = d0;
  uvl[(((tok0 + 1) >> 4) * 17) + ((tok0 + 1) & 15)] = d1;
  uvl[(((tok0 + 2) >> 4) * 17) + ((tok0 + 2) & 15)] = d2;
  uvl[(((tok0 + 3) >> 4) * 17) + ((tok0 + 3) & 15)] = d3;
  float c0 = d0, c1 = c0 + d1, c2 = c1 + d2, c3 = c2 + d3;
  float sc = c3;
#pragma unroll
  for (int off = 1; off < 64; off <<= 1) {
    float u = __shfl_up(sc, off);
    if (lane >= off) sc += u;
  }
  if (lane == 63) wtot[wv] = sc;
  __syncthreads();                       // B2
  {
    float base = sc - c3;
#pragma unroll
    for (int i = 0; i < 3; i++) if (i < wv) base += wtot[i];
    dlp[((tok0 >> 4) * 17) + (tok0 & 15)]             = base + c0;
    dlp[(((tok0 + 1) >> 4) * 17) + ((tok0 + 1) & 15)] = base + c1;
    dlp[(((tok0 + 2) >> 4) * 17) + ((tok0 + 2) & 15)] = base + c2;
    dlp[(((tok0 + 3) >> 4) * 17) + ((tok0 + 3) & 15)] = base + c3;
  }
#pragma unroll
  for (int i = 0; i < 4; i++) {
    int tok = tok0 + i;
    int p = ((tok >> 4) * 17) + (tok & 15);
    uvl[p] = uvl[p] * xcp[p];
  }
  __syncthreads();                       // B3

  int pb = lane * 17;
  float y[16];
#pragma unroll
  for (int i = 0; i < 16; i++) y[i] = 0.f;
  float Dprev = (lane == 0) ? 0.f : dlp[pb - 2];

#pragma unroll 1
  for (int r = 0; r < 4; r++) {
    int n = (wv << 2) + r;
    float An = -__expf(alog[d * NST + n]);
    float st = cs[(size_t)(b * DDIM + d) * NST + n];
    const float* pB = projT + (size_t)(64 + n) * BL + colbase + (lane << 4);
    const float* pC = pB + (size_t)16 * BL;
    float Pp = __expf(An * Dprev);
    float sl = 0.f;
#pragma unroll
    for (int c = 0; c < 4; c++) {
      float4 bv = *(const float4*)(pB + c * 4);
      float4 cv = *(const float4*)(pC + c * 4);
      float bvs[4] = {bv.x, bv.y, bv.z, bv.w};
      float cvs[4] = {cv.x, cv.y, cv.z, cv.w};
#pragma unroll
      for (int j = 0; j < 4; j++) {
        int i = c * 4 + j;
        float P = __expf(An * dlp[pb + i]);
        float w = uvl[pb + i] * bvs[j] * __builtin_amdgcn_rcpf(fmaxf(Pp, 1e-10f));
        sl += w;
        y[i] += (sl * Pp + st * P) * cvs[j];
        Pp = P;
      }
    }
    float s2 = sl;
#pragma unroll
    for (int off = 1; off < 64; off <<= 1) {
      float u = __shfl_up(s2, off);
      if (lane >= off) s2 += u;
    }
    float Soff = s2 - sl;
#pragma unroll
    for (int c = 0; c < 4; c++) {
      float4 cv = *(const float4*)(pC + c * 4);
      float cvs[4] = {cv.x, cv.y, cv.z, cv.w};
#pragma unroll
      for (int j = 0; j < 4; j++) {
        int i = c * 4 + j;
        float dlm = (i == 0) ? Dprev : dlp[pb + i - 1];
        y[i] += Soff * __expf(An * dlm) * cvs[j];
      }
    }
  }
  __syncthreads();                       // B4
  if (wv == 2) {
#pragma unroll
    for (int i = 0; i < 16; i++) uvl[pb + i] = y[i];
  } else if (wv == 3) {
#pragma unroll
    for (int i = 0; i < 16; i++) dlp[pb + i] = y[i];
  }
  __syncthreads();                       // B5
  if (wv == 0) {
#pragma unroll
    for (int i = 0; i < 16; i++) uvl[pb + i] += y[i];
  } else if (wv == 1) {
#pragma unroll
    for (int i = 0; i < 16; i++) dlp[pb + i] += y[i];
  }
  __syncthreads();                       // B6
  // ---- un-gated y (f32) -> own deltaT slice, coalesced float4 ----
  {
    float4 yo;
    int p0 = ((tok0 >> 4) * 17) + (tok0 & 15);
    int p1 = (((tok0 + 1) >> 4) * 17) + ((tok0 + 1) & 15);
    int p2 = (((tok0 + 2) >> 4) * 17) + ((tok0 + 2) & 15);
    int p3 = (((tok0 + 3) >> 4) * 17) + ((tok0 + 3) & 15);
    yo.x = uvl[p0] + dlp[p0] + xcp[p0] * Dp;
    yo.y = uvl[p1] + dlp[p1] + xcp[p1] * Dp;
    yo.z = uvl[p2] + dlp[p2] + xcp[p2] * Dp;
    yo.w = uvl[p3] + dlp[p3] + xcp[p3] * Dp;
    *(float4*)(drow + tok0) = yo;
  }
}

// ---------------- K3b: gate + transpose: yb[tok][d] = bf16(yT[d][tok] * silu(g[tok][d])) ----
__global__ __launch_bounds__(256) void k_gate(const float* __restrict__ yT,
                                              const u16* __restrict__ xgb,
                                              u16* __restrict__ yb) {
  __shared__ float tile[64 * 65];
  int dt = blockIdx.x & 31;         // d-tile (64 d)
  int tt = blockIdx.x >> 5;         // tok-tile (64 tok)
  int gtok0 = tt << 6;
  int b = gtok0 >> 10, l0 = gtok0 & 1023;
  int d0 = dt << 6;
  int t = threadIdx.x;
  // load yT tile [64 d][64 tok], coalesced rows
#pragma unroll
  for (int i = 0; i < 16; i++) {
    int idx = t + i * 256;
    int r = idx >> 6, c = idx & 63;
    tile[r * 65 + c] = yT[(size_t)(d0 + r) * BL + gtok0 + c];
  }
  __syncthreads();
  // write token-major with gate: rows = tokens, coalesced gate read + yb write
#pragma unroll
  for (int i = 0; i < 16; i++) {
    int idx = t + i * 256;
    int tr = idx >> 6, dc = idx & 63;
    float g = bf2f(xgb[(size_t)(b * XR + 3 + l0 + tr) * 4096 + 2048 + d0 + dc]);
    float yv = tile[dc * 65 + tr];
    yb[(size_t)(gtok0 + tr) * DDIM + d0 + dc] = f2bf(yv * silu_f(g));
  }
}

extern "C" void kernel_launch(void* const* d_in, const int* in_sizes, int n_in,
                              void* d_out, int out_size, void* d_ws, size_t ws_size,
                              hipStream_t stream) {
  const float* inp    = (const float*)d_in[0];
  const float* cstate = (const float*)d_in[1];
  const float* norm_w = (const float*)d_in[2];
  const float* w1     = (const float*)d_in[3];
  const float* b1     = (const float*)d_in[4];
  const float* convw  = (const float*)d_in[5];
  const float* convb  = (const float*)d_in[6];
  const float* xpw    = (const float*)d_in[7];
  const float* xpb    = (const float*)d_in[8];
  const float* dtw    = (const float*)d_in[9];
  const float* dtb    = (const float*)d_in[10];
  const float* alog   = (const float*)d_in[11];
  const float* dparam = (const float*)d_in[12];
  const float* wo     = (const float*)d_in[13];
  const float* bo     = (const float*)d_in[14];
  float* out = (float*)d_out;

  // workspace layout (ws >= 56,156,160 B confirmed R6/R8/R10/R12)
  char* wsb = (char*)d_ws;
  u16*   w1b    = (u16*)(wsb + 0);            //  8,388,608 B  [4096][1024] bf16 (dead after gemm1b)
  u16*   xTbuf  = w1b;                        //  8,388,608 B  xT [2048 d][2048 tok] bf16 (after gemm1b)
  u16*   wob    = (u16*)(wsb + 8388608);      //  4,194,304 B  [1024][2048] bf16
  u16*   whb    = (u16*)(wsb + 12591104);     //    393,216 B  xpw hi bf16 [96][2048]
  u16*   wlb    = (u16*)(wsb + 12984320);     //    393,216 B  xpw lo bf16 [96][2048]
  float* projT  = (float*)(wsb + 13377536);   //    786,432 B  [96][2048] f32
  u16*   xgb    = (u16*)(wsb + 14163968);     // 16,826,368 B  [2][1027][4096] bf16
  u16*   yb     = (u16*)(wsb + 30990336);     //  8,388,608 B  [2][1024][2048] bf16
  u16*   xnb    = yb;                         //  aliases yb (consumed before k_gate writes)
  float* deltaT = (float*)(wsb + 39378944);   // 16,777,216 B  [2048 d][2048 tok] f32
  float* pscr   = deltaT;                     //  first 11.8 MB: xproj K-partials (pre-k_delta)
  float* psplit = deltaT;                     //  16 MB: gemm2 split-K partials (post-k_gate)

  k_prep<<<8408, 256, 0, stream>>>(w1, w1b, wo, wob, xpw, whb, wlb, xgb,
                                   inp, norm_w, xnb);
  k_gemm1b<<<dim3(32, 16), 256, 0, stream>>>(xnb, w1b, b1, xgb);
  k_xT<<<1024, 256, 0, stream>>>(xgb, xTbuf);
  k_xprojT<<<512, 256, 0, stream>>>(xgb, whb, wlb, convw, convb, projT, pscr);
  k_xcomb<<<192, 256, 0, stream>>>(projT, pscr, xpb);
  k_delta<<<1024, 256, 0, stream>>>(projT, dtw, dtb, deltaT);
  k_scan2<<<2 * DDIM, 256, 0, stream>>>(projT, deltaT, xTbuf, convw, convb,
                                        alog, dparam, cstate);
  k_gate<<<1024, 256, 0, stream>>>(deltaT, xgb, yb);
  k_gemm2b<<<dim3(16, 16, 2), 256, 0, stream>>>(yb, wob, psplit);
  k_ocomb<<<2048, 256, 0, stream>>>(psplit, bo, inp, out);
}